// Round 5
// baseline (499.661 us; speedup 1.0000x reference)
//
#include <hip/hip_runtime.h>
#include <hip/hip_bf16.h>

#define B_   2
#define H_   16
#define LQ_  1024
#define LKV_ 2048
#define D_   64
#define E_   1024

typedef __attribute__((ext_vector_type(8))) _Float16 f16x8;
typedef __attribute__((ext_vector_type(8))) short   short8;
typedef __attribute__((ext_vector_type(4))) float   f32x4;

__device__ __forceinline__ float bf2f(unsigned short u) {
    union { unsigned u; float f; } v; v.u = ((unsigned)u) << 16; return v.f;
}

__device__ __forceinline__ void gload16_lds(const void* g, void* l) {
    __builtin_amdgcn_global_load_lds(
        (const __attribute__((address_space(1))) unsigned int*)g,
        (__attribute__((address_space(3))) unsigned int*)l, 16, 0, 0);
}

// ---- self-contained probe: is this float array packed bf16 (vs f32)? ----
__device__ int probe_is_bf16(const unsigned* __restrict__ w, int strideWords) {
    int hits = 0;
#pragma unroll 8
    for (int i = 0; i < 256; ++i) {
        unsigned e = (w[i * strideWords] >> 7) & 0xFFu;
        hits += (e >= 90u && e <= 142u) ? 1 : 0;
    }
    return hits >= 192 ? 1 : 0;
}

// ---------------- mask canonicalization -> u8 (self-probing) ----------------
__global__ void canon_mask5(const void* __restrict__ m, unsigned char* __restrict__ mu, int n) {
    __shared__ int s_mode;
    if (threadIdx.x == 0) {
        const unsigned* w = (const unsigned*)m;
        int notInt = 0, notF32 = 0, notBF = 0;
        for (int i = 0; i < 256; ++i) {
            unsigned v = w[i * 997];
            if (v > 1u) notInt = 1;
            if (v != 0u && v != 0x3F800000u) notF32 = 1;
            if (v != 0u && v != 0x3F80u && v != 0x3F800000u && v != 0x3F803F80u) notBF = 1;
        }
        s_mode = !notInt ? 0 : (!notF32 ? 1 : (!notBF ? 2 : 3));  // int32/f32/bf16/u8
    }
    __syncthreads();
    const int mode = s_mode;
    const int stride = gridDim.x * blockDim.x;
    for (int i = blockIdx.x * blockDim.x + threadIdx.x; i < n; i += stride) {
        unsigned char v;
        if (mode == 0)      v = (((const int*)m)[i] != 0);
        else if (mode == 1) v = (((const float*)m)[i] != 0.0f);
        else if (mode == 2) v = (((const unsigned short*)m)[i] != 0);
        else                v = (((const unsigned char*)m)[i] != 0);
        mu[i] = v;
    }
}

// ---------------- float-array canonicalization -> f16 (self-probing) --------
template <int SSTRIDE>
__global__ void canon5_f16(const void* __restrict__ src, _Float16* __restrict__ dst, int n8) {
    __shared__ int s_isbf;
    if (threadIdx.x == 0) s_isbf = probe_is_bf16((const unsigned*)src, SSTRIDE);
    __syncthreads();
    const bool isbf = (s_isbf != 0);
    const int stride = gridDim.x * blockDim.x;
    if (isbf) {
        const short8* s = (const short8*)src;
        for (int i = blockIdx.x * blockDim.x + threadIdx.x; i < n8; i += stride) {
            short8 v = s[i];
            f16x8 o;
#pragma unroll
            for (int j = 0; j < 8; j++) o[j] = (_Float16)bf2f((unsigned short)v[j]);
            ((f16x8*)dst)[i] = o;
        }
    } else {
        const f32x4* s = (const f32x4*)src;
        for (int i = blockIdx.x * blockDim.x + threadIdx.x; i < n8; i += stride) {
            f32x4 a = s[2 * i], b = s[2 * i + 1];
            f16x8 o;
            o[0] = (_Float16)a.x; o[1] = (_Float16)a.y; o[2] = (_Float16)a.z; o[3] = (_Float16)a.w;
            o[4] = (_Float16)b.x; o[5] = (_Float16)b.y; o[6] = (_Float16)b.z; o[7] = (_Float16)b.w;
            ((f16x8*)dst)[i] = o;
        }
    }
}

__global__ void canon5_bias(const void* __restrict__ src, float* __restrict__ dst, int n) {
    __shared__ int s_isbf;
    if (threadIdx.x == 0) s_isbf = probe_is_bf16((const unsigned*)src, 1);
    __syncthreads();
    const bool isbf = (s_isbf != 0);
    int i = blockIdx.x * blockDim.x + threadIdx.x;
    if (i < n) dst[i] = isbf ? bf2f(((const unsigned short*)src)[i]) : ((const float*)src)[i];
}

// ---------------- templated NT GEMM: C[M,N] = A[M,K] * W[N,K]^T (f16 in, f32 acc) ----
// MODE 0: Q proj -> Qh[B,H,LQ,D] f16, scaled 0.125
// MODE 1: K proj -> Kh[B,H,LKV,D] f16
// MODE 2: V proj -> Vt[B,H,D,LKV] f16 (transposed)
// MODE 3: FC     -> out FLOAT32, + bias
template <int MODE>
__global__ __launch_bounds__(256) void gemm5_nt(
    const _Float16* __restrict__ A,
    const _Float16* __restrict__ W,
    const float* __restrict__ bias,
    void* __restrict__ Cout,
    int M, int N, int Kd)
{
    __shared__ _Float16 As[128 * 32];
    __shared__ _Float16 Bs[128 * 32];

    const int nTn = N >> 7;
    const int tm = blockIdx.x / nTn, tn = blockIdx.x % nTn;
    const int tid = threadIdx.x;
    const int w = tid >> 6, lane = tid & 63;
    const int g = lane >> 4, c = lane & 15;
    const int wr = w >> 1, wc = w & 1;

    f32x4 acc[4][4];
#pragma unroll
    for (int i = 0; i < 4; i++)
#pragma unroll
        for (int j = 0; j < 4; j++) acc[i][j] = f32x4{0.f, 0.f, 0.f, 0.f};

    const int kIters = Kd >> 5;
    const size_t rowStrideB = (size_t)Kd * 2;

    for (int kt = 0; kt < kIters; ++kt) {
#pragma unroll
        for (int c2 = 0; c2 < 2; ++c2) {
            int L = (w * 2 + c2) * 1024 + lane * 16;
            int row = L >> 6, colb = L & 63;
            const char* gA = (const char*)A + (size_t)(tm * 128 + row) * rowStrideB + (size_t)kt * 64 + colb;
            const char* gB = (const char*)W + (size_t)(tn * 128 + row) * rowStrideB + (size_t)kt * 64 + colb;
            gload16_lds(gA, (char*)As + (w * 2 + c2) * 1024);
            gload16_lds(gB, (char*)Bs + (w * 2 + c2) * 1024);
        }
        __syncthreads();

        f16x8 aF[4], bF[4];
#pragma unroll
        for (int mi = 0; mi < 4; mi++)
            aF[mi] = *(const f16x8*)&As[(wr * 64 + mi * 16 + c) * 32 + g * 8];
#pragma unroll
        for (int ni = 0; ni < 4; ni++)
            bF[ni] = *(const f16x8*)&Bs[(wc * 64 + ni * 16 + c) * 32 + g * 8];
#pragma unroll
        for (int mi = 0; mi < 4; mi++)
#pragma unroll
            for (int ni = 0; ni < 4; ni++)
                acc[mi][ni] = __builtin_amdgcn_mfma_f32_16x16x32_f16(aF[mi], bF[ni], acc[mi][ni], 0, 0, 0);
        __syncthreads();
    }

#pragma unroll
    for (int mi = 0; mi < 4; mi++) {
#pragma unroll
        for (int ni = 0; ni < 4; ni++) {
#pragma unroll
            for (int r = 0; r < 4; r++) {
                int R  = tm * 128 + wr * 64 + mi * 16 + g * 4 + r;
                int Cc = tn * 128 + wc * 64 + ni * 16 + c;
                float v = acc[mi][ni][r];
                if (MODE == 0) {
                    int b = R >> 10, q = R & 1023;
                    int h = Cc >> 6, d = Cc & 63;
                    ((_Float16*)Cout)[((size_t)(b * H_ + h) * LQ_ + q) * D_ + d] = (_Float16)(v * 0.125f);
                } else if (MODE == 1) {
                    int b = R >> 11, k = R & 2047;
                    int h = Cc >> 6, d = Cc & 63;
                    ((_Float16*)Cout)[((size_t)(b * H_ + h) * LKV_ + k) * D_ + d] = (_Float16)v;
                } else if (MODE == 2) {
                    int b = R >> 11, k = R & 2047;
                    int h = Cc >> 6, d = Cc & 63;
                    ((_Float16*)Cout)[((size_t)(b * H_ + h) * D_ + d) * LKV_ + k] = (_Float16)v;
                } else {
                    // FINAL OUTPUT: reference dtype is float32 -> write f32.
                    ((float*)Cout)[(size_t)R * E_ + Cc] = v + bias[Cc];
                }
            }
        }
    }
}

// ---------------- flash attention: 4 waves x 16 q-rows, KV tiles of 64 ----------
__global__ __launch_bounds__(256) void attn5_kernel(
    const _Float16* __restrict__ Qh,   // [B,H,LQ,D] pre-scaled
    const _Float16* __restrict__ Kh,   // [B,H,LKV,D]
    const _Float16* __restrict__ Vt,   // [B,H,D,LKV]
    const unsigned char* __restrict__ mask,  // [B,LQ,LKV] u8
    _Float16* __restrict__ O)          // [B,LQ,E] f16
{
    __shared__ _Float16 Plds[4][16][72];

    const int bid = blockIdx.x;
    const int qt = bid & 15, bh = bid >> 4;
    const int b = bh >> 4, h = bh & 15;
    const int tid = threadIdx.x;
    const int w = tid >> 6, lane = tid & 63;
    const int g = lane >> 4, c = lane & 15;
    const int q0 = qt * 64 + w * 16;

    f16x8 qf[2];
#pragma unroll
    for (int ks = 0; ks < 2; ++ks)
        qf[ks] = *(const f16x8*)&Qh[((size_t)bh * LQ_ + q0 + c) * D_ + ks * 32 + g * 8];

    f32x4 o[4];
    float m[4], lsum[4];
#pragma unroll
    for (int dt = 0; dt < 4; dt++) o[dt] = f32x4{0.f, 0.f, 0.f, 0.f};
#pragma unroll
    for (int r = 0; r < 4; r++) { m[r] = -3e38f; lsum[r] = 0.f; }

    const size_t kBase = (size_t)bh * LKV_ * D_;
    const size_t vBase = (size_t)bh * D_ * LKV_;
    const size_t mBase = (size_t)b * LQ_ * LKV_;

    for (int kv0 = 0; kv0 < LKV_; kv0 += 64) {
        f32x4 s[4];
#pragma unroll
        for (int nt = 0; nt < 4; ++nt) {
            f32x4 accS = f32x4{0.f, 0.f, 0.f, 0.f};
#pragma unroll
            for (int ks = 0; ks < 2; ++ks) {
                f16x8 kf = *(const f16x8*)&Kh[kBase + (size_t)(kv0 + nt * 16 + c) * D_ + ks * 32 + g * 8];
                accS = __builtin_amdgcn_mfma_f32_16x16x32_f16(qf[ks], kf, accS, 0, 0, 0);
            }
            s[nt] = accS;
        }
#pragma unroll
        for (int nt = 0; nt < 4; ++nt) {
#pragma unroll
            for (int r = 0; r < 4; r++) {
                int q = q0 + g * 4 + r;
                int kv = kv0 + nt * 16 + c;
                if (mask[mBase + (size_t)q * LKV_ + kv]) s[nt][r] = -1e9f;
            }
        }
        float scl[4];
#pragma unroll
        for (int r = 0; r < 4; r++) {
            float tm0 = fmaxf(fmaxf(s[0][r], s[1][r]), fmaxf(s[2][r], s[3][r]));
#pragma unroll
            for (int off = 1; off < 16; off <<= 1) tm0 = fmaxf(tm0, __shfl_xor(tm0, off, 64));
            float mn = fmaxf(m[r], tm0);
            scl[r] = __expf(m[r] - mn);
            m[r] = mn;
        }
        float ts[4] = {0.f, 0.f, 0.f, 0.f};
#pragma unroll
        for (int nt = 0; nt < 4; ++nt) {
#pragma unroll
            for (int r = 0; r < 4; r++) {
                float p = __expf(s[nt][r] - m[r]);
                s[nt][r] = p;
                ts[r] += p;
            }
        }
#pragma unroll
        for (int r = 0; r < 4; r++) {
            float t = ts[r];
#pragma unroll
            for (int off = 1; off < 16; off <<= 1) t += __shfl_xor(t, off, 64);
            lsum[r] = lsum[r] * scl[r] + t;
        }
#pragma unroll
        for (int dt = 0; dt < 4; dt++)
#pragma unroll
            for (int r = 0; r < 4; r++) o[dt][r] *= scl[r];
#pragma unroll
        for (int nt = 0; nt < 4; ++nt)
#pragma unroll
            for (int r = 0; r < 4; r++)
                Plds[w][g * 4 + r][nt * 16 + c] = (_Float16)s[nt][r];
#pragma unroll
        for (int ks = 0; ks < 2; ++ks) {
            f16x8 pf = *(const f16x8*)&Plds[w][c][ks * 32 + g * 8];
#pragma unroll
            for (int dt = 0; dt < 4; ++dt) {
                f16x8 vf = *(const f16x8*)&Vt[vBase + (size_t)(dt * 16 + c) * LKV_ + kv0 + ks * 32 + g * 8];
                o[dt] = __builtin_amdgcn_mfma_f32_16x16x32_f16(pf, vf, o[dt], 0, 0, 0);
            }
        }
    }

#pragma unroll
    for (int dt = 0; dt < 4; ++dt) {
#pragma unroll
        for (int r = 0; r < 4; r++) {
            int q = q0 + g * 4 + r;
            int f = h * 64 + dt * 16 + c;
            O[((size_t)b * LQ_ + q) * E_ + f] = (_Float16)(o[dt][r] / lsum[r]);
        }
    }
}

extern "C" void kernel_launch(void* const* d_in, const int* in_sizes, int n_in,
                              void* d_out, int out_size, void* d_ws, size_t ws_size,
                              hipStream_t stream)
{
    const void* x   = d_in[0];
    const void* ctx = d_in[1];
    const void* msk = d_in[2];
    const void* Wq  = d_in[3];
    const void* Wk  = d_in[4];
    const void* Wv  = d_in[5];
    const void* fcw = d_in[6];
    const void* fcb = d_in[7];
    float* out = (float*)d_out;   // reference output dtype: float32

    char* ws = (char*)d_ws;
    size_t off = 0;
    auto alloc = [&](size_t bytes) { char* p = ws + off; off += (bytes + 255) & ~255ull; return p; };

    unsigned char* mU8 = (unsigned char*)alloc((size_t)B_ * LQ_ * LKV_);
    _Float16* xh  = (_Float16*)alloc((size_t)B_ * LQ_ * E_ * 2);
    _Float16* ch  = (_Float16*)alloc((size_t)B_ * LKV_ * E_ * 2);
    _Float16* wqh = (_Float16*)alloc((size_t)E_ * E_ * 2);
    _Float16* wkh = (_Float16*)alloc((size_t)E_ * E_ * 2);
    _Float16* wvh = (_Float16*)alloc((size_t)E_ * E_ * 2);
    _Float16* fwh = (_Float16*)alloc((size_t)E_ * E_ * 2);
    float*    fbf = (float*)alloc((size_t)E_ * 4);
    _Float16* Qh  = (_Float16*)alloc((size_t)B_ * H_ * LQ_ * D_ * 2);
    _Float16* Kh  = (_Float16*)alloc((size_t)B_ * H_ * LKV_ * D_ * 2);
    _Float16* Vt  = (_Float16*)alloc((size_t)B_ * H_ * LKV_ * D_ * 2);
    _Float16* Ob  = xh;  // safe alias: gemm<0> (last reader of xh) completes before attn writes Ob
    (void)ws_size; (void)in_sizes; (void)n_in; (void)out_size;

    const int nmask = B_ * LQ_ * LKV_;

    canon_mask5<<<1024, 256, 0, stream>>>(msk, mU8, nmask);

    canon5_f16<97><<<512, 256, 0, stream>>>(x,   xh,  (B_ * LQ_ * E_) / 8);
    canon5_f16<97><<<512, 256, 0, stream>>>(ctx, ch,  (B_ * LKV_ * E_) / 8);
    canon5_f16<97><<<512, 256, 0, stream>>>(Wq,  wqh, (E_ * E_) / 8);
    canon5_f16<97><<<512, 256, 0, stream>>>(Wk,  wkh, (E_ * E_) / 8);
    canon5_f16<97><<<512, 256, 0, stream>>>(Wv,  wvh, (E_ * E_) / 8);
    canon5_f16<97><<<512, 256, 0, stream>>>(fcw, fwh, (E_ * E_) / 8);
    canon5_bias<<<4, 256, 0, stream>>>(fcb, fbf, E_);

    gemm5_nt<0><<<(2048 / 128) * (1024 / 128), 256, 0, stream>>>(xh, wqh, nullptr, Qh, 2048, 1024, 1024);
    gemm5_nt<1><<<(4096 / 128) * (1024 / 128), 256, 0, stream>>>(ch, wkh, nullptr, Kh, 4096, 1024, 1024);
    gemm5_nt<2><<<(4096 / 128) * (1024 / 128), 256, 0, stream>>>(ch, wvh, nullptr, Vt, 4096, 1024, 1024);

    attn5_kernel<<<B_ * H_ * (LQ_ / 64), 256, 0, stream>>>(Qh, Kh, Vt, mU8, Ob);

    gemm5_nt<3><<<(2048 / 128) * (1024 / 128), 256, 0, stream>>>(Ob, fwh, fbf, out, 2048, 1024, 1024);
}

// Round 6
// 486.968 us; speedup vs baseline: 1.0261x; 1.0261x over previous
//
#include <hip/hip_runtime.h>
#include <hip/hip_bf16.h>

#define B_   2
#define H_   16
#define LQ_  1024
#define LKV_ 2048
#define D_   64
#define E_   1024

typedef __attribute__((ext_vector_type(8))) _Float16 f16x8;
typedef __attribute__((ext_vector_type(8))) short   short8;
typedef __attribute__((ext_vector_type(4))) float   f32x4;

__device__ __forceinline__ float bf2f(unsigned short u) {
    union { unsigned u; float f; } v; v.u = ((unsigned)u) << 16; return v.f;
}

__device__ __forceinline__ void gload16_lds(const void* g, void* l) {
    __builtin_amdgcn_global_load_lds(
        (const __attribute__((address_space(1))) unsigned int*)g,
        (__attribute__((address_space(3))) unsigned int*)l, 16, 0, 0);
}

// ---- self-contained probe: is this float array packed bf16 (vs f32)? ----
__device__ int probe_is_bf16(const unsigned* __restrict__ w, int strideWords) {
    int hits = 0;
#pragma unroll 8
    for (int i = 0; i < 256; ++i) {
        unsigned e = (w[i * strideWords] >> 7) & 0xFFu;
        hits += (e >= 90u && e <= 142u) ? 1 : 0;
    }
    return hits >= 192 ? 1 : 0;
}

// ---------------- mask -> bitmask u64 [B*LQ][LKV/64] (self-probing) ----------------
__global__ void pack_mask6(const void* __restrict__ m, unsigned long long* __restrict__ bits) {
    __shared__ int s_mode;
    if (threadIdx.x == 0) {
        const unsigned* w = (const unsigned*)m;
        int notInt = 0, notF32 = 0, notBF = 0;
        for (int i = 0; i < 256; ++i) {
            unsigned v = w[i * 997];
            if (v > 1u) notInt = 1;
            if (v != 0u && v != 0x3F800000u) notF32 = 1;
            if (v != 0u && v != 0x3F80u && v != 0x3F800000u && v != 0x3F803F80u) notBF = 1;
        }
        s_mode = !notInt ? 0 : (!notF32 ? 1 : (!notBF ? 2 : 3));  // int32/f32/bf16/u8
    }
    __syncthreads();
    const int mode = s_mode;
    const int total = B_ * LQ_ * (LKV_ / 64);
    const int stride = gridDim.x * blockDim.x;
    for (int idx = blockIdx.x * blockDim.x + threadIdx.x; idx < total; idx += stride) {
        const size_t base = (size_t)idx * 64;   // element index of bit 0
        unsigned long long v = 0;
        if (mode == 0) {
            const int* p = (const int*)m + base;
#pragma unroll
            for (int j = 0; j < 64; ++j) if (p[j] != 0) v |= 1ull << j;
        } else if (mode == 1) {
            const float* p = (const float*)m + base;
#pragma unroll
            for (int j = 0; j < 64; ++j) if (p[j] != 0.0f) v |= 1ull << j;
        } else if (mode == 2) {
            const unsigned short* p = (const unsigned short*)m + base;
#pragma unroll
            for (int j = 0; j < 64; ++j) if (p[j] != 0) v |= 1ull << j;
        } else {
            const unsigned char* p = (const unsigned char*)m + base;
#pragma unroll
            for (int j = 0; j < 64; ++j) if (p[j] != 0) v |= 1ull << j;
        }
        bits[idx] = v;
    }
}

// ---------------- float-array canonicalization -> f16 (self-probing) --------
template <int SSTRIDE>
__global__ void canon6_f16(const void* __restrict__ src, _Float16* __restrict__ dst, int n8) {
    __shared__ int s_isbf;
    if (threadIdx.x == 0) s_isbf = probe_is_bf16((const unsigned*)src, SSTRIDE);
    __syncthreads();
    const bool isbf = (s_isbf != 0);
    const int stride = gridDim.x * blockDim.x;
    if (isbf) {
        const short8* s = (const short8*)src;
        for (int i = blockIdx.x * blockDim.x + threadIdx.x; i < n8; i += stride) {
            short8 v = s[i];
            f16x8 o;
#pragma unroll
            for (int j = 0; j < 8; j++) o[j] = (_Float16)bf2f((unsigned short)v[j]);
            ((f16x8*)dst)[i] = o;
        }
    } else {
        const f32x4* s = (const f32x4*)src;
        for (int i = blockIdx.x * blockDim.x + threadIdx.x; i < n8; i += stride) {
            f32x4 a = s[2 * i], b = s[2 * i + 1];
            f16x8 o;
            o[0] = (_Float16)a.x; o[1] = (_Float16)a.y; o[2] = (_Float16)a.z; o[3] = (_Float16)a.w;
            o[4] = (_Float16)b.x; o[5] = (_Float16)b.y; o[6] = (_Float16)b.z; o[7] = (_Float16)b.w;
            ((f16x8*)dst)[i] = o;
        }
    }
}

__global__ void canon6_bias(const void* __restrict__ src, float* __restrict__ dst, int n) {
    __shared__ int s_isbf;
    if (threadIdx.x == 0) s_isbf = probe_is_bf16((const unsigned*)src, 1);
    __syncthreads();
    const bool isbf = (s_isbf != 0);
    int i = blockIdx.x * blockDim.x + threadIdx.x;
    if (i < n) dst[i] = isbf ? bf2f(((const unsigned short*)src)[i]) : ((const float*)src)[i];
}

// ---------------- templated NT GEMM: C[M,N] = A[M,K] * W[N,K]^T (f16 in, f32 acc) ----
// MODE 0: Q proj -> Qh[B,H,LQ,D] f16, scaled 0.125
// MODE 3: FC     -> out f32, + bias
// MODE 4: fused K|V proj (W rows 0..1023 = Wk, 1024..2047 = Wv)
//         -> Kh[B,H,LKV,D] f16 (Cout), Vt[B,H,D,LKV] f16 (Cout2)
template <int MODE>
__global__ __launch_bounds__(256) void gemm6_nt(
    const _Float16* __restrict__ A,
    const _Float16* __restrict__ W,
    const float* __restrict__ bias,
    void* __restrict__ Cout,
    void* __restrict__ Cout2,
    int M, int N, int Kd)
{
    __shared__ _Float16 As[128 * 32];
    __shared__ _Float16 Bs[128 * 32];

    const int nTn = N >> 7;
    const int tm = blockIdx.x / nTn, tn = blockIdx.x % nTn;
    const int tid = threadIdx.x;
    const int w = tid >> 6, lane = tid & 63;
    const int g = lane >> 4, c = lane & 15;
    const int wr = w >> 1, wc = w & 1;

    f32x4 acc[4][4];
#pragma unroll
    for (int i = 0; i < 4; i++)
#pragma unroll
        for (int j = 0; j < 4; j++) acc[i][j] = f32x4{0.f, 0.f, 0.f, 0.f};

    const int kIters = Kd >> 5;
    const size_t rowStrideB = (size_t)Kd * 2;

    for (int kt = 0; kt < kIters; ++kt) {
#pragma unroll
        for (int c2 = 0; c2 < 2; ++c2) {
            int L = (w * 2 + c2) * 1024 + lane * 16;
            int row = L >> 6, colb = L & 63;
            const char* gA = (const char*)A + (size_t)(tm * 128 + row) * rowStrideB + (size_t)kt * 64 + colb;
            const char* gB = (const char*)W + (size_t)(tn * 128 + row) * rowStrideB + (size_t)kt * 64 + colb;
            gload16_lds(gA, (char*)As + (w * 2 + c2) * 1024);
            gload16_lds(gB, (char*)Bs + (w * 2 + c2) * 1024);
        }
        __syncthreads();

        f16x8 aF[4], bF[4];
#pragma unroll
        for (int mi = 0; mi < 4; mi++)
            aF[mi] = *(const f16x8*)&As[(wr * 64 + mi * 16 + c) * 32 + g * 8];
#pragma unroll
        for (int ni = 0; ni < 4; ni++)
            bF[ni] = *(const f16x8*)&Bs[(wc * 64 + ni * 16 + c) * 32 + g * 8];
#pragma unroll
        for (int mi = 0; mi < 4; mi++)
#pragma unroll
            for (int ni = 0; ni < 4; ni++)
                acc[mi][ni] = __builtin_amdgcn_mfma_f32_16x16x32_f16(aF[mi], bF[ni], acc[mi][ni], 0, 0, 0);
        __syncthreads();
    }

#pragma unroll
    for (int mi = 0; mi < 4; mi++) {
#pragma unroll
        for (int ni = 0; ni < 4; ni++) {
#pragma unroll
            for (int r = 0; r < 4; r++) {
                int R  = tm * 128 + wr * 64 + mi * 16 + g * 4 + r;
                int Cc = tn * 128 + wc * 64 + ni * 16 + c;
                float v = acc[mi][ni][r];
                if (MODE == 0) {
                    int b = R >> 10, q = R & 1023;
                    int h = Cc >> 6, d = Cc & 63;
                    ((_Float16*)Cout)[((size_t)(b * H_ + h) * LQ_ + q) * D_ + d] = (_Float16)(v * 0.125f);
                } else if (MODE == 4) {
                    int b = R >> 11, k = R & 2047;
                    int isV = Cc >> 10, cc2 = Cc & 1023;
                    int h = cc2 >> 6, d = cc2 & 63;
                    if (!isV)
                        ((_Float16*)Cout)[((size_t)(b * H_ + h) * LKV_ + k) * D_ + d] = (_Float16)v;
                    else
                        ((_Float16*)Cout2)[((size_t)(b * H_ + h) * D_ + d) * LKV_ + k] = (_Float16)v;
                } else {
                    ((float*)Cout)[(size_t)R * E_ + Cc] = v + bias[Cc];
                }
            }
        }
    }
}

// ---------------- flash attention, in-block KV-split ----------------
// 512 threads = 8 waves: wave w -> ws = w>>2 (KV half), wq = w&3 (16-q subtile).
// Each wave: 16 q-rows x 1024 kv, partials merged through LDS.
__global__ __launch_bounds__(512) void attn6_kernel(
    const _Float16* __restrict__ Qh,   // [B,H,LQ,D] pre-scaled by 1/8
    const _Float16* __restrict__ Kh,   // [B,H,LKV,D]
    const _Float16* __restrict__ Vt,   // [B,H,D,LKV]
    const unsigned long long* __restrict__ Mb,  // [B*LQ][LKV/64] bitmask
    _Float16* __restrict__ O)          // [B,LQ,E] f16
{
    __shared__ float OfP[128 * 68];    // partial O, stride 68 (bank-friendly)
    __shared__ float Ml[128 * 2];      // (m, lsum) per partial row

    const int bid = blockIdx.x;
    const int qt = bid & 15, bh = bid >> 4;
    const int b = bh >> 4, h = bh & 15;
    const int tid = threadIdx.x;
    const int w = tid >> 6, lane = tid & 63;
    const int g = lane >> 4, c = lane & 15;
    const int ws = w >> 2, wq = w & 3;
    const int q0 = qt * 64 + wq * 16;

    _Float16* Pl = (_Float16*)OfP + (size_t)w * (16 * 72);  // aliases OfP (sync-separated)

    f16x8 qf[2];
#pragma unroll
    for (int ks = 0; ks < 2; ++ks)
        qf[ks] = *(const f16x8*)&Qh[((size_t)bh * LQ_ + q0 + c) * D_ + ks * 32 + g * 8];

    f32x4 o[4];
    float m[4], lsum[4];
#pragma unroll
    for (int dt = 0; dt < 4; dt++) o[dt] = f32x4{0.f, 0.f, 0.f, 0.f};
#pragma unroll
    for (int r = 0; r < 4; r++) { m[r] = -3e38f; lsum[r] = 0.f; }

    const size_t kBase = (size_t)bh * LKV_ * D_;
    const size_t vBase = (size_t)bh * D_ * LKV_;
    const size_t mRow0 = (size_t)(b * LQ_ + q0 + g * 4) * (LKV_ / 64);

    const int kvEnd = ws * 1024 + 1024;
    for (int kv0 = ws * 1024; kv0 < kvEnd; kv0 += 64) {
        // mask bits for this tile, pre-shifted by lane column c
        unsigned long long mk[4];
#pragma unroll
        for (int r = 0; r < 4; r++)
            mk[r] = Mb[mRow0 + (size_t)r * (LKV_ / 64) + (kv0 >> 6)] >> c;

        f32x4 s[4];
#pragma unroll
        for (int nt = 0; nt < 4; ++nt) {
            f32x4 accS = f32x4{0.f, 0.f, 0.f, 0.f};
#pragma unroll
            for (int ks = 0; ks < 2; ++ks) {
                f16x8 kf = *(const f16x8*)&Kh[kBase + (size_t)(kv0 + nt * 16 + c) * D_ + ks * 32 + g * 8];
                accS = __builtin_amdgcn_mfma_f32_16x16x32_f16(qf[ks], kf, accS, 0, 0, 0);
            }
            s[nt] = accS;
        }
#pragma unroll
        for (int nt = 0; nt < 4; ++nt)
#pragma unroll
            for (int r = 0; r < 4; r++)
                if ((mk[r] >> (nt * 16)) & 1ull) s[nt][r] = -1e9f;

        float scl[4];
#pragma unroll
        for (int r = 0; r < 4; r++) {
            float tm0 = fmaxf(fmaxf(s[0][r], s[1][r]), fmaxf(s[2][r], s[3][r]));
#pragma unroll
            for (int off = 1; off < 16; off <<= 1) tm0 = fmaxf(tm0, __shfl_xor(tm0, off, 64));
            float mn = fmaxf(m[r], tm0);
            scl[r] = __expf(m[r] - mn);
            m[r] = mn;
        }
        float ts[4] = {0.f, 0.f, 0.f, 0.f};
#pragma unroll
        for (int nt = 0; nt < 4; ++nt) {
#pragma unroll
            for (int r = 0; r < 4; r++) {
                float p = __expf(s[nt][r] - m[r]);
                s[nt][r] = p;
                ts[r] += p;
            }
        }
#pragma unroll
        for (int r = 0; r < 4; r++) {
            float t = ts[r];
#pragma unroll
            for (int off = 1; off < 16; off <<= 1) t += __shfl_xor(t, off, 64);
            lsum[r] = lsum[r] * scl[r] + t;
        }
#pragma unroll
        for (int dt = 0; dt < 4; dt++)
#pragma unroll
            for (int r = 0; r < 4; r++) o[dt][r] *= scl[r];
#pragma unroll
        for (int nt = 0; nt < 4; ++nt)
#pragma unroll
            for (int r = 0; r < 4; r++)
                Pl[(g * 4 + r) * 72 + nt * 16 + c] = (_Float16)s[nt][r];
#pragma unroll
        for (int ks = 0; ks < 2; ++ks) {
            f16x8 pf = *(const f16x8*)&Pl[c * 72 + ks * 32 + g * 8];
#pragma unroll
            for (int dt = 0; dt < 4; ++dt) {
                f16x8 vf = *(const f16x8*)&Vt[vBase + (size_t)(dt * 16 + c) * LKV_ + kv0 + ks * 32 + g * 8];
                o[dt] = __builtin_amdgcn_mfma_f32_16x16x32_f16(pf, vf, o[dt], 0, 0, 0);
            }
        }
    }

    // ---- publish partials (OfP aliases Pl: barrier first) ----
    __syncthreads();
#pragma unroll
    for (int dt = 0; dt < 4; ++dt)
#pragma unroll
        for (int r = 0; r < 4; r++)
            OfP[(w * 16 + g * 4 + r) * 68 + dt * 16 + c] = o[dt][r];
    if (c == 0) {
#pragma unroll
        for (int r = 0; r < 4; r++) {
            Ml[(w * 16 + g * 4 + r) * 2 + 0] = m[r];
            Ml[(w * 16 + g * 4 + r) * 2 + 1] = lsum[r];
        }
    }
    __syncthreads();

    // ---- combine: wave w merges rows w*8 .. w*8+7 ----
    const int d = lane;
#pragma unroll
    for (int j = 0; j < 8; ++j) {
        int ql  = w * 8 + j;               // 0..63 within block's q-tile
        int wq2 = ql >> 4, qlr = ql & 15;
        int s0 = (0 * 4 + wq2) * 16 + qlr;
        int s1 = (1 * 4 + wq2) * 16 + qlr;
        float m0 = Ml[s0 * 2], l0 = Ml[s0 * 2 + 1];
        float m1 = Ml[s1 * 2], l1 = Ml[s1 * 2 + 1];
        float M  = fmaxf(m0, m1);
        float e0 = __expf(m0 - M), e1 = __expf(m1 - M);
        float L  = l0 * e0 + l1 * e1;
        float acc = OfP[s0 * 68 + d] * e0 + OfP[s1 * 68 + d] * e1;
        O[((size_t)b * LQ_ + qt * 64 + ql) * E_ + h * 64 + d] = (_Float16)(acc / L);
    }
}

extern "C" void kernel_launch(void* const* d_in, const int* in_sizes, int n_in,
                              void* d_out, int out_size, void* d_ws, size_t ws_size,
                              hipStream_t stream)
{
    const void* x   = d_in[0];
    const void* ctx = d_in[1];
    const void* msk = d_in[2];
    const void* Wq  = d_in[3];
    const void* Wk  = d_in[4];
    const void* Wv  = d_in[5];
    const void* fcw = d_in[6];
    const void* fcb = d_in[7];
    float* out = (float*)d_out;   // reference output dtype: float32

    char* ws = (char*)d_ws;
    size_t off = 0;
    auto alloc = [&](size_t bytes) { char* p = ws + off; off += (bytes + 255) & ~255ull; return p; };

    unsigned long long* Mb = (unsigned long long*)alloc((size_t)B_ * LQ_ * (LKV_ / 64) * 8);
    _Float16* xh   = (_Float16*)alloc((size_t)B_ * LQ_ * E_ * 2);
    _Float16* ch   = (_Float16*)alloc((size_t)B_ * LKV_ * E_ * 2);
    _Float16* wqh  = (_Float16*)alloc((size_t)E_ * E_ * 2);
    _Float16* wkvh = (_Float16*)alloc((size_t)2 * E_ * E_ * 2);   // [Wk ; Wv]
    _Float16* fwh  = (_Float16*)alloc((size_t)E_ * E_ * 2);
    float*    fbf  = (float*)alloc((size_t)E_ * 4);
    _Float16* Qh   = (_Float16*)alloc((size_t)B_ * H_ * LQ_ * D_ * 2);
    _Float16* Kh   = (_Float16*)alloc((size_t)B_ * H_ * LKV_ * D_ * 2);
    _Float16* Vt   = (_Float16*)alloc((size_t)B_ * H_ * LKV_ * D_ * 2);
    _Float16* Ob   = xh;  // safe alias: gemm<0> (last reader of xh) finishes before attn writes Ob
    (void)ws_size; (void)in_sizes; (void)n_in; (void)out_size;

    pack_mask6<<<256, 256, 0, stream>>>(msk, Mb);

    canon6_f16<97><<<512, 256, 0, stream>>>(x,   xh,  (B_ * LQ_ * E_) / 8);
    canon6_f16<97><<<512, 256, 0, stream>>>(ctx, ch,  (B_ * LKV_ * E_) / 8);
    canon6_f16<97><<<512, 256, 0, stream>>>(Wq,  wqh, (E_ * E_) / 8);
    canon6_f16<97><<<512, 256, 0, stream>>>(Wk,  wkvh, (E_ * E_) / 8);
    canon6_f16<97><<<512, 256, 0, stream>>>(Wv,  wkvh + (size_t)E_ * E_, (E_ * E_) / 8);
    canon6_f16<97><<<512, 256, 0, stream>>>(fcw, fwh, (E_ * E_) / 8);
    canon6_bias<<<4, 256, 0, stream>>>(fcb, fbf, E_);

    // Q projection: M=2048, N=1024
    gemm6_nt<0><<<(2048 / 128) * (1024 / 128), 256, 0, stream>>>(xh, wqh, nullptr, Qh, nullptr, 2048, 1024, 1024);
    // fused K|V projection: M=4096, N=2048
    gemm6_nt<4><<<(4096 / 128) * (2048 / 128), 256, 0, stream>>>(ch, wkvh, nullptr, Kh, Vt, 4096, 2048, 1024);

    attn6_kernel<<<B_ * H_ * (LQ_ / 64), 512, 0, stream>>>(Qh, Kh, Vt, Mb, Ob);

    // final projection + bias: M=2048, N=1024, f32 out
    gemm6_nt<3><<<(2048 / 128) * (1024 / 128), 256, 0, stream>>>(Ob, fwh, fbf, out, nullptr, 2048, 1024, 1024);
}

// Round 7
// 378.897 us; speedup vs baseline: 1.3187x; 1.2852x over previous
//
#include <hip/hip_runtime.h>
#include <hip/hip_bf16.h>

#define B_   2
#define H_   16
#define LQ_  1024
#define LKV_ 2048
#define D_   64
#define E_   1024

typedef __attribute__((ext_vector_type(8))) _Float16 f16x8;
typedef __attribute__((ext_vector_type(8))) short   short8;
typedef __attribute__((ext_vector_type(4))) float   f32x4;

__device__ __forceinline__ float bf2f(unsigned short u) {
    union { unsigned u; float f; } v; v.u = ((unsigned)u) << 16; return v.f;
}

__device__ __forceinline__ void gload16_lds(const void* g, void* l) {
    __builtin_amdgcn_global_load_lds(
        (const __attribute__((address_space(1))) unsigned int*)g,
        (__attribute__((address_space(3))) unsigned int*)l, 16, 0, 0);
}

__device__ int probe_is_bf16(const unsigned* __restrict__ w, int strideWords) {
    int hits = 0;
#pragma unroll 8
    for (int i = 0; i < 256; ++i) {
        unsigned e = (w[i * strideWords] >> 7) & 0xFFu;
        hits += (e >= 90u && e <= 142u) ? 1 : 0;
    }
    return hits >= 192 ? 1 : 0;
}

// ---------------- ONE fused canonicalization kernel ----------------
// group-index space (1 group = 8 f16 outs, or 8 f32 outs for bias, or 1 u64 for mask):
//  [0,262144) x | [262144,786432) ctx | [786432,917504) wq | [917504,1048576) wk
//  [1048576,1179648) wv | [1179648,1310720) fcw | [1310720,1310848) bias
//  [1310848,1376384) mask->bits
__global__ void canon7_all(
    const void* __restrict__ x,  const void* __restrict__ ctx,
    const void* __restrict__ wq, const void* __restrict__ wk,
    const void* __restrict__ wv, const void* __restrict__ fw,
    const void* __restrict__ fb, const void* __restrict__ msk,
    _Float16* __restrict__ xh,  _Float16* __restrict__ ch,
    _Float16* __restrict__ wqh, _Float16* __restrict__ wkvh,
    _Float16* __restrict__ fwh, float* __restrict__ fbf,
    unsigned long long* __restrict__ Mb)
{
    __shared__ int s_isbf, s_mmode;
    if (threadIdx.x == 0) {
        s_isbf = probe_is_bf16((const unsigned*)x, 97);
        const unsigned* w = (const unsigned*)msk;
        int notInt = 0, notF32 = 0, notBF = 0;
        for (int i = 0; i < 256; ++i) {
            unsigned v = w[i * 997];
            if (v > 1u) notInt = 1;
            if (v != 0u && v != 0x3F800000u) notF32 = 1;
            if (v != 0u && v != 0x3F80u && v != 0x3F800000u && v != 0x3F803F80u) notBF = 1;
        }
        s_mmode = !notInt ? 0 : (!notF32 ? 1 : (!notBF ? 2 : 3));  // int32/f32/bf16/u8
    }
    __syncthreads();
    const bool isbf = (s_isbf != 0);
    const int mmode = s_mmode;
    const int total = 1376384;
    const int stride = gridDim.x * blockDim.x;
    for (int idx = blockIdx.x * blockDim.x + threadIdx.x; idx < total; idx += stride) {
        if (idx < 1310720) {
            const void* src; _Float16* dst; int rel;
            if (idx < 262144)       { src = x;   dst = xh;   rel = idx; }
            else if (idx < 786432)  { src = ctx; dst = ch;   rel = idx - 262144; }
            else if (idx < 917504)  { src = wq;  dst = wqh;  rel = idx - 786432; }
            else if (idx < 1048576) { src = wk;  dst = wkvh; rel = idx - 917504; }
            else if (idx < 1179648) { src = wv;  dst = wkvh + (size_t)E_ * E_; rel = idx - 1048576; }
            else                    { src = fw;  dst = fwh;  rel = idx - 1179648; }
            f16x8 o;
            if (isbf) {
                short8 v = ((const short8*)src)[rel];
#pragma unroll
                for (int j = 0; j < 8; j++) o[j] = (_Float16)bf2f((unsigned short)v[j]);
            } else {
                f32x4 a = ((const f32x4*)src)[2 * rel], b = ((const f32x4*)src)[2 * rel + 1];
                o[0] = (_Float16)a.x; o[1] = (_Float16)a.y; o[2] = (_Float16)a.z; o[3] = (_Float16)a.w;
                o[4] = (_Float16)b.x; o[5] = (_Float16)b.y; o[6] = (_Float16)b.z; o[7] = (_Float16)b.w;
            }
            ((f16x8*)dst)[rel] = o;
        } else if (idx < 1310848) {
            int rel = idx - 1310720;
#pragma unroll
            for (int j = 0; j < 8; ++j) {
                int i = rel * 8 + j;
                fbf[i] = isbf ? bf2f(((const unsigned short*)fb)[i]) : ((const float*)fb)[i];
            }
        } else {
            int rel = idx - 1310848;
            const size_t base = (size_t)rel * 64;
            unsigned long long v = 0;
            if (mmode == 0) {
                const int* p = (const int*)msk + base;
#pragma unroll
                for (int j = 0; j < 64; ++j) if (p[j] != 0) v |= 1ull << j;
            } else if (mmode == 1) {
                const float* p = (const float*)msk + base;
#pragma unroll
                for (int j = 0; j < 64; ++j) if (p[j] != 0.0f) v |= 1ull << j;
            } else if (mmode == 2) {
                const unsigned short* p = (const unsigned short*)msk + base;
#pragma unroll
                for (int j = 0; j < 64; ++j) if (p[j] != 0) v |= 1ull << j;
            } else {
                const unsigned char* p = (const unsigned char*)msk + base;
#pragma unroll
                for (int j = 0; j < 64; ++j) if (p[j] != 0) v |= 1ull << j;
            }
            Mb[rel] = v;
        }
    }
}

// ---------------- fused Q + K|V projection GEMM ----------------
// blocks 0..127: Q proj (A=xh, W=wqh, N=1024)  -> Qh[B,H,LQ,D] f16 scaled 1/8
// blocks 128..639: K|V proj (A=ch, W=wkvh, N=2048) -> Kh / Vt
__global__ __launch_bounds__(256) void gemm7_qkv(
    const _Float16* __restrict__ xh, const _Float16* __restrict__ ch,
    const _Float16* __restrict__ wqh, const _Float16* __restrict__ wkvh,
    _Float16* __restrict__ Qh, _Float16* __restrict__ Kh, _Float16* __restrict__ Vt)
{
    __shared__ _Float16 As[128 * 32];
    __shared__ _Float16 Bs[128 * 32];

    const int bid = blockIdx.x;
    const bool isQ = bid < 128;
    const _Float16* A; const _Float16* W; int tm, tn;
    if (isQ) { A = xh; W = wqh; tm = bid >> 3; tn = bid & 7; }
    else     { int b2 = bid - 128; A = ch; W = wkvh; tm = b2 >> 4; tn = b2 & 15; }

    const int tid = threadIdx.x;
    const int w = tid >> 6, lane = tid & 63;
    const int g = lane >> 4, c = lane & 15;
    const int wr = w >> 1, wc = w & 1;

    f32x4 acc[4][4];
#pragma unroll
    for (int i = 0; i < 4; i++)
#pragma unroll
        for (int j = 0; j < 4; j++) acc[i][j] = f32x4{0.f, 0.f, 0.f, 0.f};

    const size_t rowStrideB = (size_t)E_ * 2;
    for (int kt = 0; kt < 32; ++kt) {
#pragma unroll
        for (int c2 = 0; c2 < 2; ++c2) {
            int L = (w * 2 + c2) * 1024 + lane * 16;
            int row = L >> 6, colb = L & 63;
            const char* gA = (const char*)A + (size_t)(tm * 128 + row) * rowStrideB + (size_t)kt * 64 + colb;
            const char* gB = (const char*)W + (size_t)(tn * 128 + row) * rowStrideB + (size_t)kt * 64 + colb;
            gload16_lds(gA, (char*)As + (w * 2 + c2) * 1024);
            gload16_lds(gB, (char*)Bs + (w * 2 + c2) * 1024);
        }
        __syncthreads();

        f16x8 aF[4], bF[4];
#pragma unroll
        for (int mi = 0; mi < 4; mi++)
            aF[mi] = *(const f16x8*)&As[(wr * 64 + mi * 16 + c) * 32 + g * 8];
#pragma unroll
        for (int ni = 0; ni < 4; ni++)
            bF[ni] = *(const f16x8*)&Bs[(wc * 64 + ni * 16 + c) * 32 + g * 8];
#pragma unroll
        for (int mi = 0; mi < 4; mi++)
#pragma unroll
            for (int ni = 0; ni < 4; ni++)
                acc[mi][ni] = __builtin_amdgcn_mfma_f32_16x16x32_f16(aF[mi], bF[ni], acc[mi][ni], 0, 0, 0);
        __syncthreads();
    }

#pragma unroll
    for (int mi = 0; mi < 4; mi++) {
#pragma unroll
        for (int ni = 0; ni < 4; ni++) {
#pragma unroll
            for (int r = 0; r < 4; r++) {
                int R  = tm * 128 + wr * 64 + mi * 16 + g * 4 + r;
                int Cc = tn * 128 + wc * 64 + ni * 16 + c;
                float v = acc[mi][ni][r];
                if (isQ) {
                    int b = R >> 10, q = R & 1023;
                    int h = Cc >> 6, d = Cc & 63;
                    Qh[((size_t)(b * H_ + h) * LQ_ + q) * D_ + d] = (_Float16)(v * 0.125f);
                } else {
                    int b = R >> 11, k = R & 2047;
                    int isV = Cc >> 10, cc2 = Cc & 1023;
                    int h = cc2 >> 6, d = cc2 & 63;
                    if (!isV)
                        Kh[((size_t)(b * H_ + h) * LKV_ + k) * D_ + d] = (_Float16)v;
                    else
                        Vt[((size_t)(b * H_ + h) * D_ + d) * LKV_ + k] = (_Float16)v;
                }
            }
        }
    }
}

// ---------------- FC GEMM: out[M,E] f32 = Ob * fcw^T + bias ----------------
__global__ __launch_bounds__(256) void gemm7_fc(
    const _Float16* __restrict__ A, const _Float16* __restrict__ W,
    const float* __restrict__ bias, float* __restrict__ Cout)
{
    __shared__ _Float16 As[128 * 32];
    __shared__ _Float16 Bs[128 * 32];

    const int tm = blockIdx.x >> 3, tn = blockIdx.x & 7;
    const int tid = threadIdx.x;
    const int w = tid >> 6, lane = tid & 63;
    const int g = lane >> 4, c = lane & 15;
    const int wr = w >> 1, wc = w & 1;

    f32x4 acc[4][4];
#pragma unroll
    for (int i = 0; i < 4; i++)
#pragma unroll
        for (int j = 0; j < 4; j++) acc[i][j] = f32x4{0.f, 0.f, 0.f, 0.f};

    const size_t rowStrideB = (size_t)E_ * 2;
    for (int kt = 0; kt < 32; ++kt) {
#pragma unroll
        for (int c2 = 0; c2 < 2; ++c2) {
            int L = (w * 2 + c2) * 1024 + lane * 16;
            int row = L >> 6, colb = L & 63;
            const char* gA = (const char*)A + (size_t)(tm * 128 + row) * rowStrideB + (size_t)kt * 64 + colb;
            const char* gB = (const char*)W + (size_t)(tn * 128 + row) * rowStrideB + (size_t)kt * 64 + colb;
            gload16_lds(gA, (char*)As + (w * 2 + c2) * 1024);
            gload16_lds(gB, (char*)Bs + (w * 2 + c2) * 1024);
        }
        __syncthreads();

        f16x8 aF[4], bF[4];
#pragma unroll
        for (int mi = 0; mi < 4; mi++)
            aF[mi] = *(const f16x8*)&As[(wr * 64 + mi * 16 + c) * 32 + g * 8];
#pragma unroll
        for (int ni = 0; ni < 4; ni++)
            bF[ni] = *(const f16x8*)&Bs[(wc * 64 + ni * 16 + c) * 32 + g * 8];
#pragma unroll
        for (int mi = 0; mi < 4; mi++)
#pragma unroll
            for (int ni = 0; ni < 4; ni++)
                acc[mi][ni] = __builtin_amdgcn_mfma_f32_16x16x32_f16(aF[mi], bF[ni], acc[mi][ni], 0, 0, 0);
        __syncthreads();
    }

#pragma unroll
    for (int mi = 0; mi < 4; mi++)
#pragma unroll
        for (int ni = 0; ni < 4; ni++)
#pragma unroll
            for (int r = 0; r < 4; r++) {
                int R  = tm * 128 + wr * 64 + mi * 16 + g * 4 + r;
                int Cc = tn * 128 + wc * 64 + ni * 16 + c;
                Cout[(size_t)R * E_ + Cc] = acc[mi][ni][r] + bias[Cc];
            }
}

// ---------------- flash attention, XCD-local + K/mask prefetch ----------------
// Grid 512. Swizzle: all 16 q-tiles of one bh land on one XCD (bid%8 -> XCD).
// 512 threads = 8 waves: ws = w>>2 (KV half), wq = w&3 (16-q subtile).
__global__ __launch_bounds__(512, 4) void attn7_kernel(
    const _Float16* __restrict__ Qh,   // [B,H,LQ,D] pre-scaled by 1/8
    const _Float16* __restrict__ Kh,   // [B,H,LKV,D]
    const _Float16* __restrict__ Vt,   // [B,H,D,LKV]
    const unsigned long long* __restrict__ Mb,  // [B*LQ][LKV/64] bitmask
    _Float16* __restrict__ O)          // [B,LQ,E] f16
{
    __shared__ float OfP[128 * 68];
    __shared__ float Ml[128 * 2];

    const int bid0 = blockIdx.x;
    const int xcd = bid0 & 7, jj = bid0 >> 3;
    const int bh = xcd * 4 + (jj >> 4);   // 4 bh-groups per XCD -> K/V L2-local
    const int qt = jj & 15;
    const int b = bh >> 4, h = bh & 15;
    const int tid = threadIdx.x;
    const int w = tid >> 6, lane = tid & 63;
    const int g = lane >> 4, c = lane & 15;
    const int ws = w >> 2, wq = w & 3;
    const int q0 = qt * 64 + wq * 16;

    _Float16* Pl = (_Float16*)OfP + (size_t)w * (16 * 72);  // aliases OfP (sync-separated)

    f16x8 qf[2];
#pragma unroll
    for (int ks = 0; ks < 2; ++ks)
        qf[ks] = *(const f16x8*)&Qh[((size_t)bh * LQ_ + q0 + c) * D_ + ks * 32 + g * 8];

    f32x4 o[4];
    float m[4], lsum[4];
#pragma unroll
    for (int dt = 0; dt < 4; dt++) o[dt] = f32x4{0.f, 0.f, 0.f, 0.f};
#pragma unroll
    for (int r = 0; r < 4; r++) { m[r] = -3e38f; lsum[r] = 0.f; }

    const size_t kBase = (size_t)bh * LKV_ * D_;
    const size_t vBase = (size_t)bh * D_ * LKV_;
    const size_t mRow0 = (size_t)(b * LQ_ + q0 + g * 4) * (LKV_ / 64);
    const int kvStart = ws * 1024;

    f16x8 kA[8], kB[8];
    unsigned long long mA[4], mB[4];

    auto loadK = [&](int kv0, f16x8 (&kf)[8]) {
#pragma unroll
        for (int nt = 0; nt < 4; ++nt)
#pragma unroll
            for (int ks = 0; ks < 2; ++ks)
                kf[nt * 2 + ks] = *(const f16x8*)&Kh[kBase + (size_t)(kv0 + nt * 16 + c) * D_ + ks * 32 + g * 8];
    };
    auto loadM = [&](int kv0, unsigned long long (&mk)[4]) {
#pragma unroll
        for (int r = 0; r < 4; r++)
            mk[r] = Mb[mRow0 + (size_t)r * (LKV_ / 64) + (kv0 >> 6)] >> c;
    };

    auto process = [&](int kv0, f16x8 (&kf)[8], unsigned long long (&mk)[4]) {
        f32x4 s[4];
#pragma unroll
        for (int nt = 0; nt < 4; ++nt) {
            f32x4 accS = f32x4{0.f, 0.f, 0.f, 0.f};
#pragma unroll
            for (int ks = 0; ks < 2; ++ks)
                accS = __builtin_amdgcn_mfma_f32_16x16x32_f16(qf[ks], kf[nt * 2 + ks], accS, 0, 0, 0);
            s[nt] = accS;
        }
#pragma unroll
        for (int nt = 0; nt < 4; ++nt)
#pragma unroll
            for (int r = 0; r < 4; r++)
                if ((mk[r] >> (nt * 16)) & 1ull) s[nt][r] = -1e9f;

        float scl[4];
#pragma unroll
        for (int r = 0; r < 4; r++) {
            float tm0 = fmaxf(fmaxf(s[0][r], s[1][r]), fmaxf(s[2][r], s[3][r]));
#pragma unroll
            for (int off = 1; off < 16; off <<= 1) tm0 = fmaxf(tm0, __shfl_xor(tm0, off, 64));
            float mn = fmaxf(m[r], tm0);
            scl[r] = __expf(m[r] - mn);
            m[r] = mn;
        }
        float ts[4] = {0.f, 0.f, 0.f, 0.f};
#pragma unroll
        for (int nt = 0; nt < 4; ++nt) {
#pragma unroll
            for (int r = 0; r < 4; r++) {
                float p = __expf(s[nt][r] - m[r]);
                s[nt][r] = p;
                ts[r] += p;
            }
        }
#pragma unroll
        for (int r = 0; r < 4; r++) {
            float t = ts[r];
#pragma unroll
            for (int off = 1; off < 16; off <<= 1) t += __shfl_xor(t, off, 64);
            lsum[r] = lsum[r] * scl[r] + t;
        }
#pragma unroll
        for (int dt = 0; dt < 4; dt++)
#pragma unroll
            for (int r = 0; r < 4; r++) o[dt][r] *= scl[r];
#pragma unroll
        for (int nt = 0; nt < 4; ++nt)
#pragma unroll
            for (int r = 0; r < 4; r++)
                Pl[(g * 4 + r) * 72 + nt * 16 + c] = (_Float16)s[nt][r];
#pragma unroll
        for (int ks = 0; ks < 2; ++ks) {
            f16x8 pf = *(const f16x8*)&Pl[c * 72 + ks * 32 + g * 8];
#pragma unroll
            for (int dt = 0; dt < 4; ++dt) {
                f16x8 vf = *(const f16x8*)&Vt[vBase + (size_t)(dt * 16 + c) * LKV_ + kv0 + ks * 32 + g * 8];
                o[dt] = __builtin_amdgcn_mfma_f32_16x16x32_f16(pf, vf, o[dt], 0, 0, 0);
            }
        }
    };

    loadK(kvStart, kA); loadM(kvStart, mA);
    for (int t = 0; t < 16; t += 2) {
        const int kv0 = kvStart + t * 64;
        loadK(kv0 + 64, kB); loadM(kv0 + 64, mB);       // prefetch t+1 (always valid: t+1 <= 15)
        process(kv0, kA, mA);
        if (t + 2 < 16) { loadK(kv0 + 128, kA); loadM(kv0 + 128, mA); }  // prefetch t+2
        process(kv0 + 64, kB, mB);
    }

    // ---- publish partials (OfP aliases Pl: barrier first) ----
    __syncthreads();
#pragma unroll
    for (int dt = 0; dt < 4; ++dt)
#pragma unroll
        for (int r = 0; r < 4; r++)
            OfP[(w * 16 + g * 4 + r) * 68 + dt * 16 + c] = o[dt][r];
    if (c == 0) {
#pragma unroll
        for (int r = 0; r < 4; r++) {
            Ml[(w * 16 + g * 4 + r) * 2 + 0] = m[r];
            Ml[(w * 16 + g * 4 + r) * 2 + 1] = lsum[r];
        }
    }
    __syncthreads();

    const int d = lane;
#pragma unroll
    for (int j = 0; j < 8; ++j) {
        int ql  = w * 8 + j;
        int wq2 = ql >> 4, qlr = ql & 15;
        int s0 = (0 * 4 + wq2) * 16 + qlr;
        int s1 = (1 * 4 + wq2) * 16 + qlr;
        float m0 = Ml[s0 * 2], l0 = Ml[s0 * 2 + 1];
        float m1 = Ml[s1 * 2], l1 = Ml[s1 * 2 + 1];
        float M  = fmaxf(m0, m1);
        float e0 = __expf(m0 - M), e1 = __expf(m1 - M);
        float L  = l0 * e0 + l1 * e1;
        float acc = OfP[s0 * 68 + d] * e0 + OfP[s1 * 68 + d] * e1;
        O[((size_t)b * LQ_ + qt * 64 + ql) * E_ + h * 64 + d] = (_Float16)(acc / L);
    }
}

extern "C" void kernel_launch(void* const* d_in, const int* in_sizes, int n_in,
                              void* d_out, int out_size, void* d_ws, size_t ws_size,
                              hipStream_t stream)
{
    const void* x   = d_in[0];
    const void* ctx = d_in[1];
    const void* msk = d_in[2];
    const void* Wq  = d_in[3];
    const void* Wk  = d_in[4];
    const void* Wv  = d_in[5];
    const void* fcw = d_in[6];
    const void* fcb = d_in[7];
    float* out = (float*)d_out;

    char* ws = (char*)d_ws;
    size_t off = 0;
    auto alloc = [&](size_t bytes) { char* p = ws + off; off += (bytes + 255) & ~255ull; return p; };

    unsigned long long* Mb = (unsigned long long*)alloc((size_t)B_ * LQ_ * (LKV_ / 64) * 8);
    _Float16* xh   = (_Float16*)alloc((size_t)B_ * LQ_ * E_ * 2);
    _Float16* ch   = (_Float16*)alloc((size_t)B_ * LKV_ * E_ * 2);
    _Float16* wqh  = (_Float16*)alloc((size_t)E_ * E_ * 2);
    _Float16* wkvh = (_Float16*)alloc((size_t)2 * E_ * E_ * 2);
    _Float16* fwh  = (_Float16*)alloc((size_t)E_ * E_ * 2);
    float*    fbf  = (float*)alloc((size_t)E_ * 4);
    _Float16* Qh   = (_Float16*)alloc((size_t)B_ * H_ * LQ_ * D_ * 2);
    _Float16* Kh   = (_Float16*)alloc((size_t)B_ * H_ * LKV_ * D_ * 2);
    _Float16* Vt   = (_Float16*)alloc((size_t)B_ * H_ * LKV_ * D_ * 2);
    _Float16* Ob   = xh;  // safe alias: gemm7_qkv (last reader of xh) finishes before attn writes Ob
    (void)ws_size; (void)in_sizes; (void)n_in; (void)out_size;

    canon7_all<<<2048, 256, 0, stream>>>(x, ctx, Wq, Wk, Wv, fcw, fcb, msk,
                                         xh, ch, wqh, wkvh, fwh, fbf, Mb);

    gemm7_qkv<<<640, 256, 0, stream>>>(xh, ch, wqh, wkvh, Qh, Kh, Vt);

    attn7_kernel<<<B_ * H_ * (LQ_ / 64), 512, 0, stream>>>(Qh, Kh, Vt, Mb, Ob);

    gemm7_fc<<<128, 256, 0, stream>>>(Ob, fwh, fbf, out);
}

// Round 8
// 325.012 us; speedup vs baseline: 1.5374x; 1.1658x over previous
//
#include <hip/hip_runtime.h>
#include <hip/hip_bf16.h>

#define B_   2
#define H_   16
#define LQ_  1024
#define LKV_ 2048
#define D_   64
#define E_   1024

typedef __attribute__((ext_vector_type(8))) _Float16 f16x8;
typedef __attribute__((ext_vector_type(8))) short   short8;
typedef __attribute__((ext_vector_type(4))) float   f32x4;

__device__ __forceinline__ float bf2f(unsigned short u) {
    union { unsigned u; float f; } v; v.u = ((unsigned)u) << 16; return v.f;
}

__device__ __forceinline__ void gload16_lds(const void* g, void* l) {
    __builtin_amdgcn_global_load_lds(
        (const __attribute__((address_space(1))) unsigned int*)g,
        (__attribute__((address_space(3))) unsigned int*)l, 16, 0, 0);
}

__device__ int probe_is_bf16(const unsigned* __restrict__ w, int strideWords) {
    int hits = 0;
#pragma unroll 8
    for (int i = 0; i < 256; ++i) {
        unsigned e = (w[i * strideWords] >> 7) & 0xFFu;
        hits += (e >= 90u && e <= 142u) ? 1 : 0;
    }
    return hits >= 192 ? 1 : 0;
}

// ---------------- ONE fused canonicalization kernel ----------------
__global__ void canon8_all(
    const void* __restrict__ x,  const void* __restrict__ ctx,
    const void* __restrict__ wq, const void* __restrict__ wk,
    const void* __restrict__ wv, const void* __restrict__ fw,
    const void* __restrict__ fb, const void* __restrict__ msk,
    _Float16* __restrict__ xh,  _Float16* __restrict__ ch,
    _Float16* __restrict__ wqh, _Float16* __restrict__ wkvh,
    _Float16* __restrict__ fwh, float* __restrict__ fbf,
    unsigned long long* __restrict__ Mb)
{
    __shared__ int s_isbf, s_mmode;
    if (threadIdx.x == 0) {
        s_isbf = probe_is_bf16((const unsigned*)x, 97);
        const unsigned* w = (const unsigned*)msk;
        int notInt = 0, notF32 = 0, notBF = 0;
        for (int i = 0; i < 256; ++i) {
            unsigned v = w[i * 997];
            if (v > 1u) notInt = 1;
            if (v != 0u && v != 0x3F800000u) notF32 = 1;
            if (v != 0u && v != 0x3F80u && v != 0x3F800000u && v != 0x3F803F80u) notBF = 1;
        }
        s_mmode = !notInt ? 0 : (!notF32 ? 1 : (!notBF ? 2 : 3));  // int32/f32/bf16/u8
    }
    __syncthreads();
    const bool isbf = (s_isbf != 0);
    const int mmode = s_mmode;
    const int total = 1376384;
    const int stride = gridDim.x * blockDim.x;
    for (int idx = blockIdx.x * blockDim.x + threadIdx.x; idx < total; idx += stride) {
        if (idx < 1310720) {
            const void* src; _Float16* dst; int rel;
            if (idx < 262144)       { src = x;   dst = xh;   rel = idx; }
            else if (idx < 786432)  { src = ctx; dst = ch;   rel = idx - 262144; }
            else if (idx < 917504)  { src = wq;  dst = wqh;  rel = idx - 786432; }
            else if (idx < 1048576) { src = wk;  dst = wkvh; rel = idx - 917504; }
            else if (idx < 1179648) { src = wv;  dst = wkvh + (size_t)E_ * E_; rel = idx - 1048576; }
            else                    { src = fw;  dst = fwh;  rel = idx - 1179648; }
            f16x8 o;
            if (isbf) {
                short8 v = ((const short8*)src)[rel];
#pragma unroll
                for (int j = 0; j < 8; j++) o[j] = (_Float16)bf2f((unsigned short)v[j]);
            } else {
                f32x4 a = ((const f32x4*)src)[2 * rel], b = ((const f32x4*)src)[2 * rel + 1];
                o[0] = (_Float16)a.x; o[1] = (_Float16)a.y; o[2] = (_Float16)a.z; o[3] = (_Float16)a.w;
                o[4] = (_Float16)b.x; o[5] = (_Float16)b.y; o[6] = (_Float16)b.z; o[7] = (_Float16)b.w;
            }
            ((f16x8*)dst)[rel] = o;
        } else if (idx < 1310848) {
            int rel = idx - 1310720;
#pragma unroll
            for (int j = 0; j < 8; ++j) {
                int i = rel * 8 + j;
                fbf[i] = isbf ? bf2f(((const unsigned short*)fb)[i]) : ((const float*)fb)[i];
            }
        } else {
            int rel = idx - 1310848;
            const size_t base = (size_t)rel * 64;
            unsigned long long v = 0;
            if (mmode == 0) {
                const int* p = (const int*)msk + base;
#pragma unroll
                for (int j = 0; j < 64; ++j) if (p[j] != 0) v |= 1ull << j;
            } else if (mmode == 1) {
                const float* p = (const float*)msk + base;
#pragma unroll
                for (int j = 0; j < 64; ++j) if (p[j] != 0.0f) v |= 1ull << j;
            } else if (mmode == 2) {
                const unsigned short* p = (const unsigned short*)msk + base;
#pragma unroll
                for (int j = 0; j < 64; ++j) if (p[j] != 0) v |= 1ull << j;
            } else {
                const unsigned char* p = (const unsigned char*)msk + base;
#pragma unroll
                for (int j = 0; j < 64; ++j) if (p[j] != 0) v |= 1ull << j;
            }
            Mb[rel] = v;
        }
    }
}

// ---------------- fused Q + K|V projection GEMM ----------------
__global__ __launch_bounds__(256) void gemm8_qkv(
    const _Float16* __restrict__ xh, const _Float16* __restrict__ ch,
    const _Float16* __restrict__ wqh, const _Float16* __restrict__ wkvh,
    _Float16* __restrict__ Qh, _Float16* __restrict__ Kh, _Float16* __restrict__ Vt)
{
    __shared__ _Float16 As[128 * 32];
    __shared__ _Float16 Bs[128 * 32];

    const int bid = blockIdx.x;
    const bool isQ = bid < 128;
    const _Float16* A; const _Float16* W; int tm, tn;
    if (isQ) { A = xh; W = wqh; tm = bid >> 3; tn = bid & 7; }
    else     { int b2 = bid - 128; A = ch; W = wkvh; tm = b2 >> 4; tn = b2 & 15; }

    const int tid = threadIdx.x;
    const int w = tid >> 6, lane = tid & 63;
    const int g = lane >> 4, c = lane & 15;
    const int wr = w >> 1, wc = w & 1;

    f32x4 acc[4][4];
#pragma unroll
    for (int i = 0; i < 4; i++)
#pragma unroll
        for (int j = 0; j < 4; j++) acc[i][j] = f32x4{0.f, 0.f, 0.f, 0.f};

    const size_t rowStrideB = (size_t)E_ * 2;
    for (int kt = 0; kt < 32; ++kt) {
#pragma unroll
        for (int c2 = 0; c2 < 2; ++c2) {
            int L = (w * 2 + c2) * 1024 + lane * 16;
            int row = L >> 6, colb = L & 63;
            const char* gA = (const char*)A + (size_t)(tm * 128 + row) * rowStrideB + (size_t)kt * 64 + colb;
            const char* gB = (const char*)W + (size_t)(tn * 128 + row) * rowStrideB + (size_t)kt * 64 + colb;
            gload16_lds(gA, (char*)As + (w * 2 + c2) * 1024);
            gload16_lds(gB, (char*)Bs + (w * 2 + c2) * 1024);
        }
        __syncthreads();

        f16x8 aF[4], bF[4];
#pragma unroll
        for (int mi = 0; mi < 4; mi++)
            aF[mi] = *(const f16x8*)&As[(wr * 64 + mi * 16 + c) * 32 + g * 8];
#pragma unroll
        for (int ni = 0; ni < 4; ni++)
            bF[ni] = *(const f16x8*)&Bs[(wc * 64 + ni * 16 + c) * 32 + g * 8];
#pragma unroll
        for (int mi = 0; mi < 4; mi++)
#pragma unroll
            for (int ni = 0; ni < 4; ni++)
                acc[mi][ni] = __builtin_amdgcn_mfma_f32_16x16x32_f16(aF[mi], bF[ni], acc[mi][ni], 0, 0, 0);
        __syncthreads();
    }

#pragma unroll
    for (int mi = 0; mi < 4; mi++) {
#pragma unroll
        for (int ni = 0; ni < 4; ni++) {
#pragma unroll
            for (int r = 0; r < 4; r++) {
                int R  = tm * 128 + wr * 64 + mi * 16 + g * 4 + r;
                int Cc = tn * 128 + wc * 64 + ni * 16 + c;
                float v = acc[mi][ni][r];
                if (isQ) {
                    int b = R >> 10, q = R & 1023;
                    int h = Cc >> 6, d = Cc & 63;
                    Qh[((size_t)(b * H_ + h) * LQ_ + q) * D_ + d] = (_Float16)(v * 0.125f);
                } else {
                    int b = R >> 11, k = R & 2047;
                    int isV = Cc >> 10, cc2 = Cc & 1023;
                    int h = cc2 >> 6, d = cc2 & 63;
                    if (!isV)
                        Kh[((size_t)(b * H_ + h) * LKV_ + k) * D_ + d] = (_Float16)v;
                    else
                        Vt[((size_t)(b * H_ + h) * D_ + d) * LKV_ + k] = (_Float16)v;
                }
            }
        }
    }
}

// ---------------- FC GEMM ----------------
__global__ __launch_bounds__(256) void gemm8_fc(
    const _Float16* __restrict__ A, const _Float16* __restrict__ W,
    const float* __restrict__ bias, float* __restrict__ Cout)
{
    __shared__ _Float16 As[128 * 32];
    __shared__ _Float16 Bs[128 * 32];

    const int tm = blockIdx.x >> 3, tn = blockIdx.x & 7;
    const int tid = threadIdx.x;
    const int w = tid >> 6, lane = tid & 63;
    const int g = lane >> 4, c = lane & 15;
    const int wr = w >> 1, wc = w & 1;

    f32x4 acc[4][4];
#pragma unroll
    for (int i = 0; i < 4; i++)
#pragma unroll
        for (int j = 0; j < 4; j++) acc[i][j] = f32x4{0.f, 0.f, 0.f, 0.f};

    const size_t rowStrideB = (size_t)E_ * 2;
    for (int kt = 0; kt < 32; ++kt) {
#pragma unroll
        for (int c2 = 0; c2 < 2; ++c2) {
            int L = (w * 2 + c2) * 1024 + lane * 16;
            int row = L >> 6, colb = L & 63;
            const char* gA = (const char*)A + (size_t)(tm * 128 + row) * rowStrideB + (size_t)kt * 64 + colb;
            const char* gB = (const char*)W + (size_t)(tn * 128 + row) * rowStrideB + (size_t)kt * 64 + colb;
            gload16_lds(gA, (char*)As + (w * 2 + c2) * 1024);
            gload16_lds(gB, (char*)Bs + (w * 2 + c2) * 1024);
        }
        __syncthreads();

        f16x8 aF[4], bF[4];
#pragma unroll
        for (int mi = 0; mi < 4; mi++)
            aF[mi] = *(const f16x8*)&As[(wr * 64 + mi * 16 + c) * 32 + g * 8];
#pragma unroll
        for (int ni = 0; ni < 4; ni++)
            bF[ni] = *(const f16x8*)&Bs[(wc * 64 + ni * 16 + c) * 32 + g * 8];
#pragma unroll
        for (int mi = 0; mi < 4; mi++)
#pragma unroll
            for (int ni = 0; ni < 4; ni++)
                acc[mi][ni] = __builtin_amdgcn_mfma_f32_16x16x32_f16(aF[mi], bF[ni], acc[mi][ni], 0, 0, 0);
        __syncthreads();
    }

#pragma unroll
    for (int mi = 0; mi < 4; mi++)
#pragma unroll
        for (int ni = 0; ni < 4; ni++)
#pragma unroll
            for (int r = 0; r < 4; r++) {
                int R  = tm * 128 + wr * 64 + mi * 16 + g * 4 + r;
                int Cc = tn * 128 + wc * 64 + ni * 16 + c;
                Cout[(size_t)R * E_ + Cc] = acc[mi][ni][r] + bias[Cc];
            }
}

// ---------------- flash attention: XCD-local swizzle, inline loads ----------------
// Grid 512, 512 threads = 8 waves: ws = w>>2 (KV half), wq = w&3 (16-q subtile).
// Swizzle: all 16 q-tiles of one bh land on one XCD (4 bh per XCD).
__global__ __launch_bounds__(512) void attn8_kernel(
    const _Float16* __restrict__ Qh,   // [B,H,LQ,D] pre-scaled by 1/8
    const _Float16* __restrict__ Kh,   // [B,H,LKV,D]
    const _Float16* __restrict__ Vt,   // [B,H,D,LKV]
    const unsigned long long* __restrict__ Mb,  // [B*LQ][LKV/64] bitmask
    _Float16* __restrict__ O)          // [B,LQ,E] f16
{
    __shared__ float OfP[128 * 68];
    __shared__ float Ml[128 * 2];

    const int bid0 = blockIdx.x;
    const int xcd = bid0 & 7, jj = bid0 >> 3;
    const int bh = xcd * 4 + (jj >> 4);   // K/V L2-local per XCD
    const int qt = jj & 15;
    const int b = bh >> 4, h = bh & 15;
    const int tid = threadIdx.x;
    const int w = tid >> 6, lane = tid & 63;
    const int g = lane >> 4, c = lane & 15;
    const int ws = w >> 2, wq = w & 3;
    const int q0 = qt * 64 + wq * 16;

    _Float16* Pl = (_Float16*)OfP + (size_t)w * (16 * 72);  // aliases OfP (sync-separated)

    f16x8 qf[2];
#pragma unroll
    for (int ks = 0; ks < 2; ++ks)
        qf[ks] = *(const f16x8*)&Qh[((size_t)bh * LQ_ + q0 + c) * D_ + ks * 32 + g * 8];

    f32x4 o[4];
    float m[4], lsum[4];
#pragma unroll
    for (int dt = 0; dt < 4; dt++) o[dt] = f32x4{0.f, 0.f, 0.f, 0.f};
#pragma unroll
    for (int r = 0; r < 4; r++) { m[r] = -3e38f; lsum[r] = 0.f; }

    const size_t kBase = (size_t)bh * LKV_ * D_;
    const size_t vBase = (size_t)bh * D_ * LKV_;
    const size_t mRow0 = (size_t)(b * LQ_ + q0 + g * 4) * (LKV_ / 64);

    const int kvEnd = ws * 1024 + 1024;
    for (int kv0 = ws * 1024; kv0 < kvEnd; kv0 += 64) {
        unsigned long long mk[4];
#pragma unroll
        for (int r = 0; r < 4; r++)
            mk[r] = Mb[mRow0 + (size_t)r * (LKV_ / 64) + (kv0 >> 6)] >> c;

        f32x4 s[4];
#pragma unroll
        for (int nt = 0; nt < 4; ++nt) {
            f32x4 accS = f32x4{0.f, 0.f, 0.f, 0.f};
#pragma unroll
            for (int ks = 0; ks < 2; ++ks) {
                f16x8 kf = *(const f16x8*)&Kh[kBase + (size_t)(kv0 + nt * 16 + c) * D_ + ks * 32 + g * 8];
                accS = __builtin_amdgcn_mfma_f32_16x16x32_f16(qf[ks], kf, accS, 0, 0, 0);
            }
            s[nt] = accS;
        }
#pragma unroll
        for (int nt = 0; nt < 4; ++nt)
#pragma unroll
            for (int r = 0; r < 4; r++)
                if ((mk[r] >> (nt * 16)) & 1ull) s[nt][r] = -1e9f;

        float scl[4];
#pragma unroll
        for (int r = 0; r < 4; r++) {
            float tm0 = fmaxf(fmaxf(s[0][r], s[1][r]), fmaxf(s[2][r], s[3][r]));
#pragma unroll
            for (int off = 1; off < 16; off <<= 1) tm0 = fmaxf(tm0, __shfl_xor(tm0, off, 64));
            float mn = fmaxf(m[r], tm0);
            scl[r] = __expf(m[r] - mn);
            m[r] = mn;
        }
        float ts[4] = {0.f, 0.f, 0.f, 0.f};
#pragma unroll
        for (int nt = 0; nt < 4; ++nt) {
#pragma unroll
            for (int r = 0; r < 4; r++) {
                float p = __expf(s[nt][r] - m[r]);
                s[nt][r] = p;
                ts[r] += p;
            }
        }
#pragma unroll
        for (int r = 0; r < 4; r++) {
            float t = ts[r];
#pragma unroll
            for (int off = 1; off < 16; off <<= 1) t += __shfl_xor(t, off, 64);
            lsum[r] = lsum[r] * scl[r] + t;
        }
#pragma unroll
        for (int dt = 0; dt < 4; dt++)
#pragma unroll
            for (int r = 0; r < 4; r++) o[dt][r] *= scl[r];
#pragma unroll
        for (int nt = 0; nt < 4; ++nt)
#pragma unroll
            for (int r = 0; r < 4; r++)
                Pl[(g * 4 + r) * 72 + nt * 16 + c] = (_Float16)s[nt][r];
#pragma unroll
        for (int ks = 0; ks < 2; ++ks) {
            f16x8 pf = *(const f16x8*)&Pl[c * 72 + ks * 32 + g * 8];
#pragma unroll
            for (int dt = 0; dt < 4; ++dt) {
                f16x8 vf = *(const f16x8*)&Vt[vBase + (size_t)(dt * 16 + c) * LKV_ + kv0 + ks * 32 + g * 8];
                o[dt] = __builtin_amdgcn_mfma_f32_16x16x32_f16(pf, vf, o[dt], 0, 0, 0);
            }
        }
    }

    // ---- publish partials (OfP aliases Pl: barrier first) ----
    __syncthreads();
#pragma unroll
    for (int dt = 0; dt < 4; ++dt)
#pragma unroll
        for (int r = 0; r < 4; r++)
            OfP[(w * 16 + g * 4 + r) * 68 + dt * 16 + c] = o[dt][r];
    if (c == 0) {
#pragma unroll
        for (int r = 0; r < 4; r++) {
            Ml[(w * 16 + g * 4 + r) * 2 + 0] = m[r];
            Ml[(w * 16 + g * 4 + r) * 2 + 1] = lsum[r];
        }
    }
    __syncthreads();

    const int d = lane;
#pragma unroll
    for (int j = 0; j < 8; ++j) {
        int ql  = w * 8 + j;
        int wq2 = ql >> 4, qlr = ql & 15;
        int s0 = (0 * 4 + wq2) * 16 + qlr;
        int s1 = (1 * 4 + wq2) * 16 + qlr;
        float m0 = Ml[s0 * 2], l0 = Ml[s0 * 2 + 1];
        float m1 = Ml[s1 * 2], l1 = Ml[s1 * 2 + 1];
        float M  = fmaxf(m0, m1);
        float e0 = __expf(m0 - M), e1 = __expf(m1 - M);
        float L  = l0 * e0 + l1 * e1;
        float acc = OfP[s0 * 68 + d] * e0 + OfP[s1 * 68 + d] * e1;
        O[((size_t)b * LQ_ + qt * 64 + ql) * E_ + h * 64 + d] = (_Float16)(acc / L);
    }
}

extern "C" void kernel_launch(void* const* d_in, const int* in_sizes, int n_in,
                              void* d_out, int out_size, void* d_ws, size_t ws_size,
                              hipStream_t stream)
{
    const void* x   = d_in[0];
    const void* ctx = d_in[1];
    const void* msk = d_in[2];
    const void* Wq  = d_in[3];
    const void* Wk  = d_in[4];
    const void* Wv  = d_in[5];
    const void* fcw = d_in[6];
    const void* fcb = d_in[7];
    float* out = (float*)d_out;

    char* ws = (char*)d_ws;
    size_t off = 0;
    auto alloc = [&](size_t bytes) { char* p = ws + off; off += (bytes + 255) & ~255ull; return p; };

    unsigned long long* Mb = (unsigned long long*)alloc((size_t)B_ * LQ_ * (LKV_ / 64) * 8);
    _Float16* xh   = (_Float16*)alloc((size_t)B_ * LQ_ * E_ * 2);
    _Float16* ch   = (_Float16*)alloc((size_t)B_ * LKV_ * E_ * 2);
    _Float16* wqh  = (_Float16*)alloc((size_t)E_ * E_ * 2);
    _Float16* wkvh = (_Float16*)alloc((size_t)2 * E_ * E_ * 2);
    _Float16* fwh  = (_Float16*)alloc((size_t)E_ * E_ * 2);
    float*    fbf  = (float*)alloc((size_t)E_ * 4);
    _Float16* Qh   = (_Float16*)alloc((size_t)B_ * H_ * LQ_ * D_ * 2);
    _Float16* Kh   = (_Float16*)alloc((size_t)B_ * H_ * LKV_ * D_ * 2);
    _Float16* Vt   = (_Float16*)alloc((size_t)B_ * H_ * LKV_ * D_ * 2);
    _Float16* Ob   = xh;  // safe alias: gemm8_qkv (last reader of xh) finishes before attn writes Ob
    (void)ws_size; (void)in_sizes; (void)n_in; (void)out_size;

    canon8_all<<<2048, 256, 0, stream>>>(x, ctx, Wq, Wk, Wv, fcw, fcb, msk,
                                         xh, ch, wqh, wkvh, fwh, fbf, Mb);

    gemm8_qkv<<<640, 256, 0, stream>>>(xh, ch, wqh, wkvh, Qh, Kh, Vt);

    attn8_kernel<<<B_ * H_ * (LQ_ / 64), 512, 0, stream>>>(Qh, Kh, Vt, Mb, Ob);

    gemm8_fc<<<128, 256, 0, stream>>>(Ob, fwh, fbf, out);
}

// Round 9
// 308.833 us; speedup vs baseline: 1.6179x; 1.0524x over previous
//
#include <hip/hip_runtime.h>
#include <hip/hip_bf16.h>

#define B_   2
#define H_   16
#define LQ_  1024
#define LKV_ 2048
#define D_   64
#define E_   1024

typedef __attribute__((ext_vector_type(8))) _Float16 f16x8;
typedef __attribute__((ext_vector_type(4))) float   f32x4;

__device__ __forceinline__ void gload16_lds(const void* g, void* l) {
    __builtin_amdgcn_global_load_lds(
        (const __attribute__((address_space(1))) unsigned int*)g,
        (__attribute__((address_space(3))) unsigned int*)l, 16, 0, 0);
}

// ---- DPP 16-lane butterfly reduce (VALU-only, no LDS) ----
template <int CTRL>
__device__ __forceinline__ float dppf(float v) {
    return __builtin_bit_cast(float,
        __builtin_amdgcn_update_dpp(0, __builtin_bit_cast(int, v), CTRL, 0xF, 0xF, true));
}
__device__ __forceinline__ float rmax16(float x) {
    x = fmaxf(x, dppf<0xB1>(x));    // quad_perm [1,0,3,2]  (xor 1)
    x = fmaxf(x, dppf<0x4E>(x));    // quad_perm [2,3,0,1]  (xor 2)
    x = fmaxf(x, dppf<0x141>(x));   // row_half_mirror      (-> 8)
    x = fmaxf(x, dppf<0x140>(x));   // row_mirror           (-> 16)
    return x;
}
__device__ __forceinline__ float rsum16(float x) {
    x += dppf<0xB1>(x);
    x += dppf<0x4E>(x);
    x += dppf<0x141>(x);
    x += dppf<0x140>(x);
    return x;
}

// ---------------- one-wave mask-dtype probe (runs once) ----------------
__global__ void probe9(const void* __restrict__ msk, int* __restrict__ modep) {
    int lane = threadIdx.x;
    int notInt = 0, notF32 = 0, notBF = 0;
    for (int i = lane; i < 256; i += 64) {
        unsigned v = ((const unsigned*)msk)[i * 997];
        if (v > 1u) notInt = 1;
        if (v != 0u && v != 0x3F800000u) notF32 = 1;
        if (v != 0u && v != 0x3F80u && v != 0x3F800000u && v != 0x3F803F80u) notBF = 1;
    }
    notInt = __any(notInt); notF32 = __any(notF32); notBF = __any(notBF);
    if (lane == 0) *modep = !notInt ? 0 : (!notF32 ? 1 : (!notBF ? 2 : 3));
}

// ---------------- streaming canonicalization (f32 inputs, no probes) ----------------
// group-index space: [0,262144) x | [262144,786432) ctx | [786432,917504) wq
// [917504,1048576) wk | [1048576,1179648) wv | [1179648,1310720) fcw
// [1310720,1310848) bias | [1310848,1376384) mask->bits
__global__ void canon9_all(
    const float* __restrict__ x,  const float* __restrict__ ctx,
    const float* __restrict__ wq, const float* __restrict__ wk,
    const float* __restrict__ wv, const float* __restrict__ fw,
    const float* __restrict__ fb, const void* __restrict__ msk,
    _Float16* __restrict__ xh,  _Float16* __restrict__ ch,
    _Float16* __restrict__ wqh, _Float16* __restrict__ wkvh,
    _Float16* __restrict__ fwh, float* __restrict__ fbf,
    unsigned long long* __restrict__ Mb, const int* __restrict__ modep)
{
    const int mmode = *modep;
    const int total = 1376384;
    const int stride = gridDim.x * blockDim.x;
    for (int idx = blockIdx.x * blockDim.x + threadIdx.x; idx < total; idx += stride) {
        if (idx < 1310720) {
            const float* src; _Float16* dst; int rel;
            if (idx < 262144)       { src = x;   dst = xh;   rel = idx; }
            else if (idx < 786432)  { src = ctx; dst = ch;   rel = idx - 262144; }
            else if (idx < 917504)  { src = wq;  dst = wqh;  rel = idx - 786432; }
            else if (idx < 1048576) { src = wk;  dst = wkvh; rel = idx - 917504; }
            else if (idx < 1179648) { src = wv;  dst = wkvh + (size_t)E_ * E_; rel = idx - 1048576; }
            else                    { src = fw;  dst = fwh;  rel = idx - 1179648; }
            f32x4 a = ((const f32x4*)src)[2 * rel], b = ((const f32x4*)src)[2 * rel + 1];
            f16x8 o;
            o[0] = (_Float16)a.x; o[1] = (_Float16)a.y; o[2] = (_Float16)a.z; o[3] = (_Float16)a.w;
            o[4] = (_Float16)b.x; o[5] = (_Float16)b.y; o[6] = (_Float16)b.z; o[7] = (_Float16)b.w;
            ((f16x8*)dst)[rel] = o;
        } else if (idx < 1310848) {
            int rel = idx - 1310720;
#pragma unroll
            for (int j = 0; j < 8; ++j) fbf[rel * 8 + j] = fb[rel * 8 + j];
        } else {
            int rel = idx - 1310848;
            const size_t base = (size_t)rel * 64;
            unsigned long long v = 0;
            if (mmode == 0) {
                const int* p = (const int*)msk + base;
#pragma unroll
                for (int j = 0; j < 64; ++j) if (p[j] != 0) v |= 1ull << j;
            } else if (mmode == 1) {
                const float* p = (const float*)msk + base;
#pragma unroll
                for (int j = 0; j < 64; ++j) if (p[j] != 0.0f) v |= 1ull << j;
            } else if (mmode == 2) {
                const unsigned short* p = (const unsigned short*)msk + base;
#pragma unroll
                for (int j = 0; j < 64; ++j) if (p[j] != 0) v |= 1ull << j;
            } else {
                const unsigned char* p = (const unsigned char*)msk + base;
#pragma unroll
                for (int j = 0; j < 64; ++j) if (p[j] != 0) v |= 1ull << j;
            }
            Mb[rel] = v;
        }
    }
}

// ---------------- fused Q + K|V projection GEMM (unchanged structure) ----------------
__global__ __launch_bounds__(256) void gemm9_qkv(
    const _Float16* __restrict__ xh, const _Float16* __restrict__ ch,
    const _Float16* __restrict__ wqh, const _Float16* __restrict__ wkvh,
    _Float16* __restrict__ Qh, _Float16* __restrict__ Kh, _Float16* __restrict__ Vt)
{
    __shared__ _Float16 As[128 * 32];
    __shared__ _Float16 Bs[128 * 32];

    const int bid = blockIdx.x;
    const bool isQ = bid < 128;
    const _Float16* A; const _Float16* W; int tm, tn;
    if (isQ) { A = xh; W = wqh; tm = bid >> 3; tn = bid & 7; }
    else     { int b2 = bid - 128; A = ch; W = wkvh; tm = b2 >> 4; tn = b2 & 15; }

    const int tid = threadIdx.x;
    const int w = tid >> 6, lane = tid & 63;
    const int g = lane >> 4, c = lane & 15;
    const int wr = w >> 1, wc = w & 1;

    f32x4 acc[4][4];
#pragma unroll
    for (int i = 0; i < 4; i++)
#pragma unroll
        for (int j = 0; j < 4; j++) acc[i][j] = f32x4{0.f, 0.f, 0.f, 0.f};

    const size_t rowStrideB = (size_t)E_ * 2;
    for (int kt = 0; kt < 32; ++kt) {
#pragma unroll
        for (int c2 = 0; c2 < 2; ++c2) {
            int L = (w * 2 + c2) * 1024 + lane * 16;
            int row = L >> 6, colb = L & 63;
            const char* gA = (const char*)A + (size_t)(tm * 128 + row) * rowStrideB + (size_t)kt * 64 + colb;
            const char* gB = (const char*)W + (size_t)(tn * 128 + row) * rowStrideB + (size_t)kt * 64 + colb;
            gload16_lds(gA, (char*)As + (w * 2 + c2) * 1024);
            gload16_lds(gB, (char*)Bs + (w * 2 + c2) * 1024);
        }
        __syncthreads();

        f16x8 aF[4], bF[4];
#pragma unroll
        for (int mi = 0; mi < 4; mi++)
            aF[mi] = *(const f16x8*)&As[(wr * 64 + mi * 16 + c) * 32 + g * 8];
#pragma unroll
        for (int ni = 0; ni < 4; ni++)
            bF[ni] = *(const f16x8*)&Bs[(wc * 64 + ni * 16 + c) * 32 + g * 8];
#pragma unroll
        for (int mi = 0; mi < 4; mi++)
#pragma unroll
            for (int ni = 0; ni < 4; ni++)
                acc[mi][ni] = __builtin_amdgcn_mfma_f32_16x16x32_f16(aF[mi], bF[ni], acc[mi][ni], 0, 0, 0);
        __syncthreads();
    }

#pragma unroll
    for (int mi = 0; mi < 4; mi++) {
#pragma unroll
        for (int ni = 0; ni < 4; ni++) {
#pragma unroll
            for (int r = 0; r < 4; r++) {
                int R  = tm * 128 + wr * 64 + mi * 16 + g * 4 + r;
                int Cc = tn * 128 + wc * 64 + ni * 16 + c;
                float v = acc[mi][ni][r];
                if (isQ) {
                    int b = R >> 10, q = R & 1023;
                    int h = Cc >> 6, d = Cc & 63;
                    Qh[((size_t)(b * H_ + h) * LQ_ + q) * D_ + d] = (_Float16)(v * 0.125f);
                } else {
                    int b = R >> 11, k = R & 2047;
                    int isV = Cc >> 10, cc2 = Cc & 1023;
                    int h = cc2 >> 6, d = cc2 & 63;
                    if (!isV)
                        Kh[((size_t)(b * H_ + h) * LKV_ + k) * D_ + d] = (_Float16)v;
                    else
                        Vt[((size_t)(b * H_ + h) * D_ + d) * LKV_ + k] = (_Float16)v;
                }
            }
        }
    }
}

// ---------------- FC GEMM (unchanged) ----------------
__global__ __launch_bounds__(256) void gemm9_fc(
    const _Float16* __restrict__ A, const _Float16* __restrict__ W,
    const float* __restrict__ bias, float* __restrict__ Cout)
{
    __shared__ _Float16 As[128 * 32];
    __shared__ _Float16 Bs[128 * 32];

    const int tm = blockIdx.x >> 3, tn = blockIdx.x & 7;
    const int tid = threadIdx.x;
    const int w = tid >> 6, lane = tid & 63;
    const int g = lane >> 4, c = lane & 15;
    const int wr = w >> 1, wc = w & 1;

    f32x4 acc[4][4];
#pragma unroll
    for (int i = 0; i < 4; i++)
#pragma unroll
        for (int j = 0; j < 4; j++) acc[i][j] = f32x4{0.f, 0.f, 0.f, 0.f};

    const size_t rowStrideB = (size_t)E_ * 2;
    for (int kt = 0; kt < 32; ++kt) {
#pragma unroll
        for (int c2 = 0; c2 < 2; ++c2) {
            int L = (w * 2 + c2) * 1024 + lane * 16;
            int row = L >> 6, colb = L & 63;
            const char* gA = (const char*)A + (size_t)(tm * 128 + row) * rowStrideB + (size_t)kt * 64 + colb;
            const char* gB = (const char*)W + (size_t)(tn * 128 + row) * rowStrideB + (size_t)kt * 64 + colb;
            gload16_lds(gA, (char*)As + (w * 2 + c2) * 1024);
            gload16_lds(gB, (char*)Bs + (w * 2 + c2) * 1024);
        }
        __syncthreads();

        f16x8 aF[4], bF[4];
#pragma unroll
        for (int mi = 0; mi < 4; mi++)
            aF[mi] = *(const f16x8*)&As[(wr * 64 + mi * 16 + c) * 32 + g * 8];
#pragma unroll
        for (int ni = 0; ni < 4; ni++)
            bF[ni] = *(const f16x8*)&Bs[(wc * 64 + ni * 16 + c) * 32 + g * 8];
#pragma unroll
        for (int mi = 0; mi < 4; mi++)
#pragma unroll
            for (int ni = 0; ni < 4; ni++)
                acc[mi][ni] = __builtin_amdgcn_mfma_f32_16x16x32_f16(aF[mi], bF[ni], acc[mi][ni], 0, 0, 0);
        __syncthreads();
    }

#pragma unroll
    for (int mi = 0; mi < 4; mi++)
#pragma unroll
        for (int ni = 0; ni < 4; ni++)
#pragma unroll
            for (int r = 0; r < 4; r++) {
                int R  = tm * 128 + wr * 64 + mi * 16 + g * 4 + r;
                int Cc = tn * 128 + wc * 64 + ni * 16 + c;
                Cout[(size_t)R * E_ + Cc] = acc[mi][ni][r] + bias[Cc];
            }
}

// ---------------- flash attention: 4-way kv split, DPP softmax, VGPR<=64 ----------------
// Grid 1024 (32 bh x 32 q-tiles of 32 rows). Block 512 = 8 waves:
// wq = w&1 (16-q subtile), ws = w>>1 (kv quarter: 512 kv each).
// XCD swizzle: 4 bh per XCD (128 consecutive-on-XCD blocks per XCD).
__global__ __launch_bounds__(512, 8) void attn9_kernel(
    const _Float16* __restrict__ Qh,   // [B,H,LQ,D] pre-scaled by 1/8
    const _Float16* __restrict__ Kh,   // [B,H,LKV,D]
    const _Float16* __restrict__ Vt,   // [B,H,D,LKV]
    const unsigned long long* __restrict__ Mb,  // [B*LQ][LKV/64] bitmask
    _Float16* __restrict__ O)          // [B,LQ,E] f16
{
    __shared__ char ldsraw[36864];
    float* OfP = (float*)ldsraw;                   // [128 rows][68] after barrier
    float* Ml  = (float*)(ldsraw + 34816);         // [128][2]

    const int bid0 = blockIdx.x;
    const int xcd = bid0 & 7, jj = bid0 >> 3;
    const int bh = xcd * 4 + (jj >> 5);            // K/V L2-local per XCD
    const int qt = jj & 31;
    const int b = bh >> 4, h = bh & 15;
    const int tid = threadIdx.x;
    const int w = tid >> 6, lane = tid & 63;
    const int g = lane >> 4, c = lane & 15;
    const int wq = w & 1, ws = w >> 1;
    const int q0 = qt * 32 + wq * 16;

    _Float16* Pl = (_Float16*)ldsraw + (size_t)w * (16 * 72);  // per-wave P tile (pre-barrier)

    f16x8 qf[2];
#pragma unroll
    for (int ks = 0; ks < 2; ++ks)
        qf[ks] = *(const f16x8*)&Qh[((size_t)bh * LQ_ + q0 + c) * D_ + ks * 32 + g * 8];

    f32x4 o[4];
    float m[4], lsum[4];
#pragma unroll
    for (int dt = 0; dt < 4; dt++) o[dt] = f32x4{0.f, 0.f, 0.f, 0.f};
#pragma unroll
    for (int r = 0; r < 4; r++) { m[r] = -3e38f; lsum[r] = 0.f; }

    const size_t kBase = (size_t)bh * LKV_ * D_;
    const size_t vBase = (size_t)bh * D_ * LKV_;
    const size_t mRow0 = (size_t)(b * LQ_ + q0 + g * 4) * (LKV_ / 64);

    const int kvStart = ws * 512, kvEnd = kvStart + 512;
    for (int kv0 = kvStart; kv0 < kvEnd; kv0 += 64) {
        f32x4 s[4];
#pragma unroll
        for (int nt = 0; nt < 4; ++nt) {
            f32x4 accS = f32x4{0.f, 0.f, 0.f, 0.f};
#pragma unroll
            for (int ks = 0; ks < 2; ++ks) {
                f16x8 kf = *(const f16x8*)&Kh[kBase + (size_t)(kv0 + nt * 16 + c) * D_ + ks * 32 + g * 8];
                accS = __builtin_amdgcn_mfma_f32_16x16x32_f16(qf[ks], kf, accS, 0, 0, 0);
            }
            s[nt] = accS;
        }
        float scl[4];
#pragma unroll
        for (int r = 0; r < 4; ++r) {
            unsigned long long mkr = Mb[mRow0 + (size_t)r * (LKV_ / 64) + (kv0 >> 6)] >> c;
            if (mkr & 1ull)         s[0][r] = -1e9f;
            if ((mkr >> 16) & 1ull) s[1][r] = -1e9f;
            if ((mkr >> 32) & 1ull) s[2][r] = -1e9f;
            if ((mkr >> 48) & 1ull) s[3][r] = -1e9f;
            float t = fmaxf(fmaxf(s[0][r], s[1][r]), fmaxf(s[2][r], s[3][r]));
            t = rmax16(t);
            float mn = fmaxf(m[r], t);
            scl[r] = __expf(m[r] - mn);
            m[r] = mn;
        }
#pragma unroll
        for (int r = 0; r < 4; ++r) {
            float p0 = __expf(s[0][r] - m[r]);
            float p1 = __expf(s[1][r] - m[r]);
            float p2 = __expf(s[2][r] - m[r]);
            float p3 = __expf(s[3][r] - m[r]);
            s[0][r] = p0; s[1][r] = p1; s[2][r] = p2; s[3][r] = p3;
            float ts = rsum16((p0 + p1) + (p2 + p3));
            lsum[r] = lsum[r] * scl[r] + ts;
        }
#pragma unroll
        for (int dt = 0; dt < 4; dt++)
#pragma unroll
            for (int r = 0; r < 4; r++) o[dt][r] *= scl[r];
#pragma unroll
        for (int nt = 0; nt < 4; ++nt)
#pragma unroll
            for (int r = 0; r < 4; r++)
                Pl[(g * 4 + r) * 72 + nt * 16 + c] = (_Float16)s[nt][r];
#pragma unroll
        for (int ks = 0; ks < 2; ++ks) {
            f16x8 pf = *(const f16x8*)&Pl[c * 72 + ks * 32 + g * 8];
#pragma unroll
            for (int dt = 0; dt < 4; ++dt) {
                f16x8 vf = *(const f16x8*)&Vt[vBase + (size_t)(dt * 16 + c) * LKV_ + kv0 + ks * 32 + g * 8];
                o[dt] = __builtin_amdgcn_mfma_f32_16x16x32_f16(pf, vf, o[dt], 0, 0, 0);
            }
        }
    }

    // ---- publish partials (OfP aliases Pl: barrier first) ----
    __syncthreads();
#pragma unroll
    for (int dt = 0; dt < 4; ++dt)
#pragma unroll
        for (int r = 0; r < 4; r++)
            OfP[(w * 16 + g * 4 + r) * 68 + dt * 16 + c] = o[dt][r];
    if (c == 0) {
#pragma unroll
        for (int r = 0; r < 4; r++) {
            Ml[(w * 16 + g * 4 + r) * 2 + 0] = m[r];
            Ml[(w * 16 + g * 4 + r) * 2 + 1] = lsum[r];
        }
    }
    __syncthreads();

    // ---- combine 4 kv-partials per q-row: 4 passes x (8 rows x 64 d) ----
    const int d = tid & 63;
    const int qlBase = tid >> 6;
#pragma unroll
    for (int pass = 0; pass < 4; ++pass) {
        int ql = pass * 8 + qlBase;          // 0..31
        int wq2 = ql >> 4, qlr = ql & 15;
        float mm[4];
        float M = -3e38f;
#pragma unroll
        for (int w2 = 0; w2 < 4; ++w2) {
            mm[w2] = Ml[((w2 * 2 + wq2) * 16 + qlr) * 2];
            M = fmaxf(M, mm[w2]);
        }
        float L = 0.f, acc = 0.f;
#pragma unroll
        for (int w2 = 0; w2 < 4; ++w2) {
            int sr = (w2 * 2 + wq2) * 16 + qlr;
            float e = __expf(mm[w2] - M);
            L += Ml[sr * 2 + 1] * e;
            acc += OfP[sr * 68 + d] * e;
        }
        O[((size_t)b * LQ_ + qt * 32 + ql) * E_ + h * 64 + d] = (_Float16)(acc / L);
    }
}

extern "C" void kernel_launch(void* const* d_in, const int* in_sizes, int n_in,
                              void* d_out, int out_size, void* d_ws, size_t ws_size,
                              hipStream_t stream)
{
    const float* x   = (const float*)d_in[0];
    const float* ctx = (const float*)d_in[1];
    const void*  msk = d_in[2];
    const float* Wq  = (const float*)d_in[3];
    const float* Wk  = (const float*)d_in[4];
    const float* Wv  = (const float*)d_in[5];
    const float* fcw = (const float*)d_in[6];
    const float* fcb = (const float*)d_in[7];
    float* out = (float*)d_out;

    char* ws = (char*)d_ws;
    size_t off = 0;
    auto alloc = [&](size_t bytes) { char* p = ws + off; off += (bytes + 255) & ~255ull; return p; };

    int* modep = (int*)alloc(256);
    unsigned long long* Mb = (unsigned long long*)alloc((size_t)B_ * LQ_ * (LKV_ / 64) * 8);
    _Float16* xh   = (_Float16*)alloc((size_t)B_ * LQ_ * E_ * 2);
    _Float16* ch   = (_Float16*)alloc((size_t)B_ * LKV_ * E_ * 2);
    _Float16* wqh  = (_Float16*)alloc((size_t)E_ * E_ * 2);
    _Float16* wkvh = (_Float16*)alloc((size_t)2 * E_ * E_ * 2);
    _Float16* fwh  = (_Float16*)alloc((size_t)E_ * E_ * 2);
    float*    fbf  = (float*)alloc((size_t)E_ * 4);
    _Float16* Qh   = (_Float16*)alloc((size_t)B_ * H_ * LQ_ * D_ * 2);
    _Float16* Kh   = (_Float16*)alloc((size_t)B_ * H_ * LKV_ * D_ * 2);
    _Float16* Vt   = (_Float16*)alloc((size_t)B_ * H_ * LKV_ * D_ * 2);
    _Float16* Ob   = xh;  // safe alias: gemm9_qkv (last reader of xh) finishes before attn writes Ob
    (void)ws_size; (void)in_sizes; (void)n_in; (void)out_size;

    probe9<<<1, 64, 0, stream>>>(msk, modep);

    canon9_all<<<2048, 256, 0, stream>>>(x, ctx, Wq, Wk, Wv, fcw, fcb, msk,
                                         xh, ch, wqh, wkvh, fwh, fbf, Mb, modep);

    gemm9_qkv<<<640, 256, 0, stream>>>(xh, ch, wqh, wkvh, Qh, Kh, Vt);

    attn9_kernel<<<1024, 512, 0, stream>>>(Qh, Kh, Vt, Mb, Ob);

    gemm9_fc<<<128, 256, 0, stream>>>(Ob, fwh, fbf, out);
}

// Round 10
// 233.138 us; speedup vs baseline: 2.1432x; 1.3247x over previous
//
#include <hip/hip_runtime.h>
#include <hip/hip_bf16.h>

#define B_   2
#define H_   16
#define LQ_  1024
#define LKV_ 2048
#define D_   64
#define E_   1024

typedef __attribute__((ext_vector_type(8))) _Float16 f16x8;
typedef __attribute__((ext_vector_type(4))) float   f32x4;

__device__ __forceinline__ void gload16_lds(const void* g, void* l) {
    __builtin_amdgcn_global_load_lds(
        (const __attribute__((address_space(1))) unsigned int*)g,
        (__attribute__((address_space(3))) unsigned int*)l, 16, 0, 0);
}

// ---- DPP 16-lane butterfly reduce (VALU-only; HW-verified in round 9) ----
template <int CTRL>
__device__ __forceinline__ float dppf(float v) {
    return __builtin_bit_cast(float,
        __builtin_amdgcn_update_dpp(0, __builtin_bit_cast(int, v), CTRL, 0xF, 0xF, true));
}
__device__ __forceinline__ float rmax16(float x) {
    x = fmaxf(x, dppf<0xB1>(x));    // quad_perm [1,0,3,2]
    x = fmaxf(x, dppf<0x4E>(x));    // quad_perm [2,3,0,1]
    x = fmaxf(x, dppf<0x141>(x));   // row_half_mirror
    x = fmaxf(x, dppf<0x140>(x));   // row_mirror
    return x;
}
__device__ __forceinline__ float rsum16(float x) {
    x += dppf<0xB1>(x);
    x += dppf<0x4E>(x);
    x += dppf<0x141>(x);
    x += dppf<0x140>(x);
    return x;
}

// ---------------- one-wave mask-dtype probe ----------------
__global__ void probe10(const void* __restrict__ msk, int* __restrict__ modep) {
    int lane = threadIdx.x;
    int notInt = 0, notF32 = 0, notBF = 0;
    for (int i = lane; i < 256; i += 64) {
        unsigned v = ((const unsigned*)msk)[i * 997];
        if (v > 1u) notInt = 1;
        if (v != 0u && v != 0x3F800000u) notF32 = 1;
        if (v != 0u && v != 0x3F80u && v != 0x3F800000u && v != 0x3F803F80u) notBF = 1;
    }
    notInt = __any(notInt); notF32 = __any(notF32); notBF = __any(notBF);
    if (lane == 0) *modep = !notInt ? 0 : (!notF32 ? 1 : (!notBF ? 2 : 3));
}

// ---------------- streaming canonicalization ----------------
__global__ void canon10_all(
    const float* __restrict__ x,  const float* __restrict__ ctx,
    const float* __restrict__ wq, const float* __restrict__ wk,
    const float* __restrict__ wv, const float* __restrict__ fw,
    const float* __restrict__ fb, const void* __restrict__ msk,
    _Float16* __restrict__ xh,  _Float16* __restrict__ ch,
    _Float16* __restrict__ wqh, _Float16* __restrict__ wkvh,
    _Float16* __restrict__ fwh, float* __restrict__ fbf,
    unsigned long long* __restrict__ Mb, const int* __restrict__ modep)
{
    const int mmode = *modep;
    const int total = 1376384;
    const int stride = gridDim.x * blockDim.x;
    for (int idx = blockIdx.x * blockDim.x + threadIdx.x; idx < total; idx += stride) {
        if (idx < 1310720) {
            const float* src; _Float16* dst; int rel;
            if (idx < 262144)       { src = x;   dst = xh;   rel = idx; }
            else if (idx < 786432)  { src = ctx; dst = ch;   rel = idx - 262144; }
            else if (idx < 917504)  { src = wq;  dst = wqh;  rel = idx - 786432; }
            else if (idx < 1048576) { src = wk;  dst = wkvh; rel = idx - 917504; }
            else if (idx < 1179648) { src = wv;  dst = wkvh + (size_t)E_ * E_; rel = idx - 1048576; }
            else                    { src = fw;  dst = fwh;  rel = idx - 1179648; }
            f32x4 a = ((const f32x4*)src)[2 * rel], b = ((const f32x4*)src)[2 * rel + 1];
            f16x8 o;
            o[0] = (_Float16)a.x; o[1] = (_Float16)a.y; o[2] = (_Float16)a.z; o[3] = (_Float16)a.w;
            o[4] = (_Float16)b.x; o[5] = (_Float16)b.y; o[6] = (_Float16)b.z; o[7] = (_Float16)b.w;
            ((f16x8*)dst)[rel] = o;
        } else if (idx < 1310848) {
            int rel = idx - 1310720;
#pragma unroll
            for (int j = 0; j < 8; ++j) fbf[rel * 8 + j] = fb[rel * 8 + j];
        } else {
            int rel = idx - 1310848;
            const size_t base = (size_t)rel * 64;
            unsigned long long v = 0;
            if (mmode == 0) {
                const int* p = (const int*)msk + base;
#pragma unroll
                for (int j = 0; j < 64; ++j) if (p[j] != 0) v |= 1ull << j;
            } else if (mmode == 1) {
                const float* p = (const float*)msk + base;
#pragma unroll
                for (int j = 0; j < 64; ++j) if (p[j] != 0.0f) v |= 1ull << j;
            } else if (mmode == 2) {
                const unsigned short* p = (const unsigned short*)msk + base;
#pragma unroll
                for (int j = 0; j < 64; ++j) if (p[j] != 0) v |= 1ull << j;
            } else {
                const unsigned char* p = (const unsigned char*)msk + base;
#pragma unroll
                for (int j = 0; j < 64; ++j) if (p[j] != 0) v |= 1ull << j;
            }
            Mb[rel] = v;
        }
    }
}

// ---------------- fused Q + K|V projection GEMM ----------------
// Q scale folds 1/sqrt(64) * log2(e) so attention can use raw exp2.
__global__ __launch_bounds__(256) void gemm10_qkv(
    const _Float16* __restrict__ xh, const _Float16* __restrict__ ch,
    const _Float16* __restrict__ wqh, const _Float16* __restrict__ wkvh,
    _Float16* __restrict__ Qh, _Float16* __restrict__ Kh, _Float16* __restrict__ Vt)
{
    __shared__ _Float16 As[128 * 32];
    __shared__ _Float16 Bs[128 * 32];

    const int bid = blockIdx.x;
    const bool isQ = bid < 128;
    const _Float16* A; const _Float16* W; int tm, tn;
    if (isQ) { A = xh; W = wqh; tm = bid >> 3; tn = bid & 7; }
    else     { int b2 = bid - 128; A = ch; W = wkvh; tm = b2 >> 4; tn = b2 & 15; }

    const int tid = threadIdx.x;
    const int w = tid >> 6, lane = tid & 63;
    const int g = lane >> 4, c = lane & 15;
    const int wr = w >> 1, wc = w & 1;

    f32x4 acc[4][4];
#pragma unroll
    for (int i = 0; i < 4; i++)
#pragma unroll
        for (int j = 0; j < 4; j++) acc[i][j] = f32x4{0.f, 0.f, 0.f, 0.f};

    const size_t rowStrideB = (size_t)E_ * 2;
    for (int kt = 0; kt < 32; ++kt) {
#pragma unroll
        for (int c2 = 0; c2 < 2; ++c2) {
            int L = (w * 2 + c2) * 1024 + lane * 16;
            int row = L >> 6, colb = L & 63;
            const char* gA = (const char*)A + (size_t)(tm * 128 + row) * rowStrideB + (size_t)kt * 64 + colb;
            const char* gB = (const char*)W + (size_t)(tn * 128 + row) * rowStrideB + (size_t)kt * 64 + colb;
            gload16_lds(gA, (char*)As + (w * 2 + c2) * 1024);
            gload16_lds(gB, (char*)Bs + (w * 2 + c2) * 1024);
        }
        __syncthreads();

        f16x8 aF[4], bF[4];
#pragma unroll
        for (int mi = 0; mi < 4; mi++)
            aF[mi] = *(const f16x8*)&As[(wr * 64 + mi * 16 + c) * 32 + g * 8];
#pragma unroll
        for (int ni = 0; ni < 4; ni++)
            bF[ni] = *(const f16x8*)&Bs[(wc * 64 + ni * 16 + c) * 32 + g * 8];
#pragma unroll
        for (int mi = 0; mi < 4; mi++)
#pragma unroll
            for (int ni = 0; ni < 4; ni++)
                acc[mi][ni] = __builtin_amdgcn_mfma_f32_16x16x32_f16(aF[mi], bF[ni], acc[mi][ni], 0, 0, 0);
        __syncthreads();
    }

#pragma unroll
    for (int mi = 0; mi < 4; mi++) {
#pragma unroll
        for (int ni = 0; ni < 4; ni++) {
#pragma unroll
            for (int r = 0; r < 4; r++) {
                int R  = tm * 128 + wr * 64 + mi * 16 + g * 4 + r;
                int Cc = tn * 128 + wc * 64 + ni * 16 + c;
                float v = acc[mi][ni][r];
                if (isQ) {
                    int b = R >> 10, q = R & 1023;
                    int h = Cc >> 6, d = Cc & 63;
                    // 0.125 * log2(e)
                    Qh[((size_t)(b * H_ + h) * LQ_ + q) * D_ + d] = (_Float16)(v * 0.18033688011112042f);
                } else {
                    int b = R >> 11, k = R & 2047;
                    int isV = Cc >> 10, cc2 = Cc & 1023;
                    int h = cc2 >> 6, d = cc2 & 63;
                    if (!isV)
                        Kh[((size_t)(b * H_ + h) * LKV_ + k) * D_ + d] = (_Float16)v;
                    else
                        Vt[((size_t)(b * H_ + h) * D_ + d) * LKV_ + k] = (_Float16)v;
                }
            }
        }
    }
}

// ---------------- FC GEMM ----------------
__global__ __launch_bounds__(256) void gemm10_fc(
    const _Float16* __restrict__ A, const _Float16* __restrict__ W,
    const float* __restrict__ bias, float* __restrict__ Cout)
{
    __shared__ _Float16 As[128 * 32];
    __shared__ _Float16 Bs[128 * 32];

    const int tm = blockIdx.x >> 3, tn = blockIdx.x & 7;
    const int tid = threadIdx.x;
    const int w = tid >> 6, lane = tid & 63;
    const int g = lane >> 4, c = lane & 15;
    const int wr = w >> 1, wc = w & 1;

    f32x4 acc[4][4];
#pragma unroll
    for (int i = 0; i < 4; i++)
#pragma unroll
        for (int j = 0; j < 4; j++) acc[i][j] = f32x4{0.f, 0.f, 0.f, 0.f};

    const size_t rowStrideB = (size_t)E_ * 2;
    for (int kt = 0; kt < 32; ++kt) {
#pragma unroll
        for (int c2 = 0; c2 < 2; ++c2) {
            int L = (w * 2 + c2) * 1024 + lane * 16;
            int row = L >> 6, colb = L & 63;
            const char* gA = (const char*)A + (size_t)(tm * 128 + row) * rowStrideB + (size_t)kt * 64 + colb;
            const char* gB = (const char*)W + (size_t)(tn * 128 + row) * rowStrideB + (size_t)kt * 64 + colb;
            gload16_lds(gA, (char*)As + (w * 2 + c2) * 1024);
            gload16_lds(gB, (char*)Bs + (w * 2 + c2) * 1024);
        }
        __syncthreads();

        f16x8 aF[4], bF[4];
#pragma unroll
        for (int mi = 0; mi < 4; mi++)
            aF[mi] = *(const f16x8*)&As[(wr * 64 + mi * 16 + c) * 32 + g * 8];
#pragma unroll
        for (int ni = 0; ni < 4; ni++)
            bF[ni] = *(const f16x8*)&Bs[(wc * 64 + ni * 16 + c) * 32 + g * 8];
#pragma unroll
        for (int mi = 0; mi < 4; mi++)
#pragma unroll
            for (int ni = 0; ni < 4; ni++)
                acc[mi][ni] = __builtin_amdgcn_mfma_f32_16x16x32_f16(aF[mi], bF[ni], acc[mi][ni], 0, 0, 0);
        __syncthreads();
    }

#pragma unroll
    for (int mi = 0; mi < 4; mi++)
#pragma unroll
        for (int ni = 0; ni < 4; ni++)
#pragma unroll
            for (int r = 0; r < 4; r++) {
                int R  = tm * 128 + wr * 64 + mi * 16 + g * 4 + r;
                int Cc = tn * 128 + wc * 64 + ni * 16 + c;
                Cout[(size_t)R * E_ + Cc] = acc[mi][ni][r] + bias[Cc];
            }
}

// ---------------- flash attention: 4-way kv split, DPP softmax, exp2 domain ----------------
// Grid 1024 (8 xcd x 4 bh x 32 q-tiles of 32 rows). Block 512 = 8 waves:
// wq = w&1 (16-q subtile), ws = w>>1 (kv quarter, 512 kv each).
// NO min-waves clause: VGPR must float (~70). Round 9's (512,8) caused spills.
__global__ __launch_bounds__(512) void attn10_kernel(
    const _Float16* __restrict__ Qh,   // [B,H,LQ,D] pre-scaled by 0.125*log2e
    const _Float16* __restrict__ Kh,   // [B,H,LKV,D]
    const _Float16* __restrict__ Vt,   // [B,H,D,LKV]
    const unsigned long long* __restrict__ Mb,  // [B*LQ][LKV/64] bitmask
    _Float16* __restrict__ O)          // [B,LQ,E] f16
{
    __shared__ char ldsraw[36864];
    float* OfP = (float*)ldsraw;                   // [128 rows][68] after barrier
    float* Ml  = (float*)(ldsraw + 34816);         // [128][2]

    const int bid0 = blockIdx.x;
    const int xcd = bid0 & 7, jj = bid0 >> 3;
    const int bh = xcd * 4 + (jj >> 5);            // K/V L2-local per XCD
    const int qt = jj & 31;
    const int b = bh >> 4, h = bh & 15;
    const int tid = threadIdx.x;
    const int w = tid >> 6, lane = tid & 63;
    const int g = lane >> 4, c = lane & 15;
    const int wq = w & 1, ws = w >> 1;
    const int q0 = qt * 32 + wq * 16;

    _Float16* Pl = (_Float16*)ldsraw + (size_t)w * (16 * 72);  // per-wave P tile (pre-barrier)

    f16x8 qf[2];
#pragma unroll
    for (int ks = 0; ks < 2; ++ks)
        qf[ks] = *(const f16x8*)&Qh[((size_t)bh * LQ_ + q0 + c) * D_ + ks * 32 + g * 8];

    f32x4 o[4];
    float m[4], lsum[4];
#pragma unroll
    for (int dt = 0; dt < 4; dt++) o[dt] = f32x4{0.f, 0.f, 0.f, 0.f};
#pragma unroll
    for (int r = 0; r < 4; r++) { m[r] = -3e38f; lsum[r] = 0.f; }

    const size_t kBase = (size_t)bh * LKV_ * D_;
    const size_t vBase = (size_t)bh * D_ * LKV_;
    const size_t mRow0 = (size_t)(b * LQ_ + q0 + g * 4) * (LKV_ / 64);

    const int kvStart = ws * 512, kvEnd = kvStart + 512;
    for (int kv0 = kvStart; kv0 < kvEnd; kv0 += 64) {
        f32x4 s[4];
#pragma unroll
        for (int nt = 0; nt < 4; ++nt) {
            f32x4 accS = f32x4{0.f, 0.f, 0.f, 0.f};
#pragma unroll
            for (int ks = 0; ks < 2; ++ks) {
                f16x8 kf = *(const f16x8*)&Kh[kBase + (size_t)(kv0 + nt * 16 + c) * D_ + ks * 32 + g * 8];
                accS = __builtin_amdgcn_mfma_f32_16x16x32_f16(qf[ks], kf, accS, 0, 0, 0);
            }
            s[nt] = accS;
        }
        float scl[4];
#pragma unroll
        for (int r = 0; r < 4; ++r) {
            unsigned long long mkr = Mb[mRow0 + (size_t)r * (LKV_ / 64) + (kv0 >> 6)] >> c;
            if (mkr & 1ull)         s[0][r] = -1e9f;
            if ((mkr >> 16) & 1ull) s[1][r] = -1e9f;
            if ((mkr >> 32) & 1ull) s[2][r] = -1e9f;
            if ((mkr >> 48) & 1ull) s[3][r] = -1e9f;
            float t = fmaxf(fmaxf(s[0][r], s[1][r]), fmaxf(s[2][r], s[3][r]));
            t = rmax16(t);
            float mn = fmaxf(m[r], t);
            scl[r] = exp2f(m[r] - mn);    // base-2 domain
            m[r] = mn;
        }
#pragma unroll
        for (int r = 0; r < 4; ++r) {
            float p0 = exp2f(s[0][r] - m[r]);
            float p1 = exp2f(s[1][r] - m[r]);
            float p2 = exp2f(s[2][r] - m[r]);
            float p3 = exp2f(s[3][r] - m[r]);
            s[0][r] = p0; s[1][r] = p1; s[2][r] = p2; s[3][r] = p3;
            float ts = rsum16((p0 + p1) + (p2 + p3));
            lsum[r] = lsum[r] * scl[r] + ts;
        }
#pragma unroll
        for (int dt = 0; dt < 4; dt++)
#pragma unroll
            for (int r = 0; r < 4; r++) o[dt][r] *= scl[r];
#pragma unroll
        for (int nt = 0; nt < 4; ++nt)
#pragma unroll
            for (int r = 0; r < 4; r++)
                Pl[(g * 4 + r) * 72 + nt * 16 + c] = (_Float16)s[nt][r];
#pragma unroll
        for (int ks = 0; ks < 2; ++ks) {
            f16x8 pf = *(const f16x8*)&Pl[c * 72 + ks * 32 + g * 8];
#pragma unroll
            for (int dt = 0; dt < 4; ++dt) {
                f16x8 vf = *(const f16x8*)&Vt[vBase + (size_t)(dt * 16 + c) * LKV_ + kv0 + ks * 32 + g * 8];
                o[dt] = __builtin_amdgcn_mfma_f32_16x16x32_f16(pf, vf, o[dt], 0, 0, 0);
            }
        }
    }

    // ---- publish partials (OfP aliases Pl: barrier first) ----
    __syncthreads();
#pragma unroll
    for (int dt = 0; dt < 4; ++dt)
#pragma unroll
        for (int r = 0; r < 4; r++)
            OfP[(w * 16 + g * 4 + r) * 68 + dt * 16 + c] = o[dt][r];
    if (c == 0) {
#pragma unroll
        for (int r = 0; r < 4; r++) {
            Ml[(w * 16 + g * 4 + r) * 2 + 0] = m[r];
            Ml[(w * 16 + g * 4 + r) * 2 + 1] = lsum[r];
        }
    }
    __syncthreads();

    // ---- combine 4 kv-partials per q-row (base-2 domain) ----
    const int d = tid & 63;
    const int qlBase = tid >> 6;
#pragma unroll
    for (int pass = 0; pass < 4; ++pass) {
        int ql = pass * 8 + qlBase;          // 0..31
        int wq2 = ql >> 4, qlr = ql & 15;
        float mm[4];
        float M = -3e38f;
#pragma unroll
        for (int w2 = 0; w2 < 4; ++w2) {
            mm[w2] = Ml[((w2 * 2 + wq2) * 16 + qlr) * 2];
            M = fmaxf(M, mm[w2]);
        }
        float L = 0.f, acc = 0.f;
#pragma unroll
        for (int w2 = 0; w2 < 4; ++w2) {
            int sr = (w2 * 2 + wq2) * 16 + qlr;
            float e = exp2f(mm[w2] - M);
            L += Ml[sr * 2 + 1] * e;
            acc += OfP[sr * 68 + d] * e;
        }
        O[((size_t)b * LQ_ + qt * 32 + ql) * E_ + h * 64 + d] = (_Float16)(acc / L);
    }
}

extern "C" void kernel_launch(void* const* d_in, const int* in_sizes, int n_in,
                              void* d_out, int out_size, void* d_ws, size_t ws_size,
                              hipStream_t stream)
{
    const float* x   = (const float*)d_in[0];
    const float* ctx = (const float*)d_in[1];
    const void*  msk = d_in[2];
    const float* Wq  = (const float*)d_in[3];
    const float* Wk  = (const float*)d_in[4];
    const float* Wv  = (const float*)d_in[5];
    const float* fcw = (const float*)d_in[6];
    const float* fcb = (const float*)d_in[7];
    float* out = (float*)d_out;

    char* ws = (char*)d_ws;
    size_t off = 0;
    auto alloc = [&](size_t bytes) { char* p = ws + off; off += (bytes + 255) & ~255ull; return p; };

    int* modep = (int*)alloc(256);
    unsigned long long* Mb = (unsigned long long*)alloc((size_t)B_ * LQ_ * (LKV_ / 64) * 8);
    _Float16* xh   = (_Float16*)alloc((size_t)B_ * LQ_ * E_ * 2);
    _Float16* ch   = (_Float16*)alloc((size_t)B_ * LKV_ * E_ * 2);
    _Float16* wqh  = (_Float16*)alloc((size_t)E_ * E_ * 2);
    _Float16* wkvh = (_Float16*)alloc((size_t)2 * E_ * E_ * 2);
    _Float16* fwh  = (_Float16*)alloc((size_t)E_ * E_ * 2);
    float*    fbf  = (float*)alloc((size_t)E_ * 4);
    _Float16* Qh   = (_Float16*)alloc((size_t)B_ * H_ * LQ_ * D_ * 2);
    _Float16* Kh   = (_Float16*)alloc((size_t)B_ * H_ * LKV_ * D_ * 2);
    _Float16* Vt   = (_Float16*)alloc((size_t)B_ * H_ * LKV_ * D_ * 2);
    _Float16* Ob   = xh;  // safe alias: gemm10_qkv (last reader of xh) finishes before attn writes Ob
    (void)ws_size; (void)in_sizes; (void)n_in; (void)out_size;

    probe10<<<1, 64, 0, stream>>>(msk, modep);

    canon10_all<<<2048, 256, 0, stream>>>(x, ctx, Wq, Wk, Wv, fcw, fcb, msk,
                                          xh, ch, wqh, wkvh, fwh, fbf, Mb, modep);

    gemm10_qkv<<<640, 256, 0, stream>>>(xh, ch, wqh, wkvh, Qh, Kh, Vt);

    attn10_kernel<<<1024, 512, 0, stream>>>(Qh, Kh, Vt, Mb, Ob);

    gemm10_fc<<<128, 256, 0, stream>>>(Ob, fwh, fbf, out);
}

// Round 11
// 228.302 us; speedup vs baseline: 2.1886x; 1.0212x over previous
//
#include <hip/hip_runtime.h>
#include <hip/hip_bf16.h>

#define B_   2
#define H_   16
#define LQ_  1024
#define LKV_ 2048
#define D_   64
#define E_   1024

typedef __attribute__((ext_vector_type(8))) _Float16 f16x8;
typedef __attribute__((ext_vector_type(4))) float   f32x4;
typedef __attribute__((ext_vector_type(2))) _Float16 f16x2;

__device__ __forceinline__ void gload16_lds(const void* g, void* l) {
    __builtin_amdgcn_global_load_lds(
        (const __attribute__((address_space(1))) unsigned int*)g,
        (__attribute__((address_space(3))) unsigned int*)l, 16, 0, 0);
}

// ---------------- one-wave mask-dtype probe ----------------
__global__ void probe11(const void* __restrict__ msk, int* __restrict__ modep) {
    int lane = threadIdx.x;
    int notInt = 0, notF32 = 0, notBF = 0;
    for (int i = lane; i < 256; i += 64) {
        unsigned v = ((const unsigned*)msk)[i * 997];
        if (v > 1u) notInt = 1;
        if (v != 0u && v != 0x3F800000u) notF32 = 1;
        if (v != 0u && v != 0x3F80u && v != 0x3F800000u && v != 0x3F803F80u) notBF = 1;
    }
    notInt = __any(notInt); notF32 = __any(notF32); notBF = __any(notBF);
    if (lane == 0) *modep = !notInt ? 0 : (!notF32 ? 1 : (!notBF ? 2 : 3));
}

// ---------------- streaming canonicalization ----------------
__global__ void canon11_all(
    const float* __restrict__ x,  const float* __restrict__ ctx,
    const float* __restrict__ wq, const float* __restrict__ wk,
    const float* __restrict__ wv, const float* __restrict__ fw,
    const float* __restrict__ fb, const void* __restrict__ msk,
    _Float16* __restrict__ xh,  _Float16* __restrict__ ch,
    _Float16* __restrict__ wqh, _Float16* __restrict__ wkvh,
    _Float16* __restrict__ fwh, float* __restrict__ fbf,
    unsigned long long* __restrict__ Mb, const int* __restrict__ modep)
{
    const int mmode = *modep;
    const int total = 1376384;
    const int stride = gridDim.x * blockDim.x;
    for (int idx = blockIdx.x * blockDim.x + threadIdx.x; idx < total; idx += stride) {
        if (idx < 1310720) {
            const float* src; _Float16* dst; int rel;
            if (idx < 262144)       { src = x;   dst = xh;   rel = idx; }
            else if (idx < 786432)  { src = ctx; dst = ch;   rel = idx - 262144; }
            else if (idx < 917504)  { src = wq;  dst = wqh;  rel = idx - 786432; }
            else if (idx < 1048576) { src = wk;  dst = wkvh; rel = idx - 917504; }
            else if (idx < 1179648) { src = wv;  dst = wkvh + (size_t)E_ * E_; rel = idx - 1048576; }
            else                    { src = fw;  dst = fwh;  rel = idx - 1179648; }
            f32x4 a = ((const f32x4*)src)[2 * rel], b = ((const f32x4*)src)[2 * rel + 1];
            f16x8 o;
            o[0] = (_Float16)a.x; o[1] = (_Float16)a.y; o[2] = (_Float16)a.z; o[3] = (_Float16)a.w;
            o[4] = (_Float16)b.x; o[5] = (_Float16)b.y; o[6] = (_Float16)b.z; o[7] = (_Float16)b.w;
            ((f16x8*)dst)[rel] = o;
        } else if (idx < 1310848) {
            int rel = idx - 1310720;
#pragma unroll
            for (int j = 0; j < 8; ++j) fbf[rel * 8 + j] = fb[rel * 8 + j];
        } else {
            int rel = idx - 1310848;
            const size_t base = (size_t)rel * 64;
            unsigned long long v = 0;
            if (mmode == 0) {
                const int* p = (const int*)msk + base;
#pragma unroll
                for (int j = 0; j < 64; ++j) if (p[j] != 0) v |= 1ull << j;
            } else if (mmode == 1) {
                const float* p = (const float*)msk + base;
#pragma unroll
                for (int j = 0; j < 64; ++j) if (p[j] != 0.0f) v |= 1ull << j;
            } else if (mmode == 2) {
                const unsigned short* p = (const unsigned short*)msk + base;
#pragma unroll
                for (int j = 0; j < 64; ++j) if (p[j] != 0) v |= 1ull << j;
            } else {
                const unsigned char* p = (const unsigned char*)msk + base;
#pragma unroll
                for (int j = 0; j < 64; ++j) if (p[j] != 0) v |= 1ull << j;
            }
            Mb[rel] = v;
        }
    }
}

// ---------------- fused Q + K|V projection GEMM ----------------
__global__ __launch_bounds__(256) void gemm11_qkv(
    const _Float16* __restrict__ xh, const _Float16* __restrict__ ch,
    const _Float16* __restrict__ wqh, const _Float16* __restrict__ wkvh,
    _Float16* __restrict__ Qh, _Float16* __restrict__ Kh, _Float16* __restrict__ Vt)
{
    __shared__ _Float16 As[128 * 32];
    __shared__ _Float16 Bs[128 * 32];

    const int bid = blockIdx.x;
    const bool isQ = bid < 128;
    const _Float16* A; const _Float16* W; int tm, tn;
    if (isQ) { A = xh; W = wqh; tm = bid >> 3; tn = bid & 7; }
    else     { int b2 = bid - 128; A = ch; W = wkvh; tm = b2 >> 4; tn = b2 & 15; }

    const int tid = threadIdx.x;
    const int w = tid >> 6, lane = tid & 63;
    const int g = lane >> 4, c = lane & 15;
    const int wr = w >> 1, wc = w & 1;

    f32x4 acc[4][4];
#pragma unroll
    for (int i = 0; i < 4; i++)
#pragma unroll
        for (int j = 0; j < 4; j++) acc[i][j] = f32x4{0.f, 0.f, 0.f, 0.f};

    const size_t rowStrideB = (size_t)E_ * 2;
    for (int kt = 0; kt < 32; ++kt) {
#pragma unroll
        for (int c2 = 0; c2 < 2; ++c2) {
            int L = (w * 2 + c2) * 1024 + lane * 16;
            int row = L >> 6, colb = L & 63;
            const char* gA = (const char*)A + (size_t)(tm * 128 + row) * rowStrideB + (size_t)kt * 64 + colb;
            const char* gB = (const char*)W + (size_t)(tn * 128 + row) * rowStrideB + (size_t)kt * 64 + colb;
            gload16_lds(gA, (char*)As + (w * 2 + c2) * 1024);
            gload16_lds(gB, (char*)Bs + (w * 2 + c2) * 1024);
        }
        __syncthreads();

        f16x8 aF[4], bF[4];
#pragma unroll
        for (int mi = 0; mi < 4; mi++)
            aF[mi] = *(const f16x8*)&As[(wr * 64 + mi * 16 + c) * 32 + g * 8];
#pragma unroll
        for (int ni = 0; ni < 4; ni++)
            bF[ni] = *(const f16x8*)&Bs[(wc * 64 + ni * 16 + c) * 32 + g * 8];
#pragma unroll
        for (int mi = 0; mi < 4; mi++)
#pragma unroll
            for (int ni = 0; ni < 4; ni++)
                acc[mi][ni] = __builtin_amdgcn_mfma_f32_16x16x32_f16(aF[mi], bF[ni], acc[mi][ni], 0, 0, 0);
        __syncthreads();
    }

#pragma unroll
    for (int mi = 0; mi < 4; mi++) {
#pragma unroll
        for (int ni = 0; ni < 4; ni++) {
#pragma unroll
            for (int r = 0; r < 4; r++) {
                int R  = tm * 128 + wr * 64 + mi * 16 + g * 4 + r;
                int Cc = tn * 128 + wc * 64 + ni * 16 + c;
                float v = acc[mi][ni][r];
                if (isQ) {
                    int b = R >> 10, q = R & 1023;
                    int h = Cc >> 6, d = Cc & 63;
                    // 0.125 * log2(e): attention works in exp2 domain
                    Qh[((size_t)(b * H_ + h) * LQ_ + q) * D_ + d] = (_Float16)(v * 0.18033688011112042f);
                } else {
                    int b = R >> 11, k = R & 2047;
                    int isV = Cc >> 10, cc2 = Cc & 1023;
                    int h = cc2 >> 6, d = cc2 & 63;
                    if (!isV)
                        Kh[((size_t)(b * H_ + h) * LKV_ + k) * D_ + d] = (_Float16)v;
                    else
                        Vt[((size_t)(b * H_ + h) * D_ + d) * LKV_ + k] = (_Float16)v;
                }
            }
        }
    }
}

// ---------------- FC GEMM ----------------
__global__ __launch_bounds__(256) void gemm11_fc(
    const _Float16* __restrict__ A, const _Float16* __restrict__ W,
    const float* __restrict__ bias, float* __restrict__ Cout)
{
    __shared__ _Float16 As[128 * 32];
    __shared__ _Float16 Bs[128 * 32];

    const int tm = blockIdx.x >> 3, tn = blockIdx.x & 7;
    const int tid = threadIdx.x;
    const int w = tid >> 6, lane = tid & 63;
    const int g = lane >> 4, c = lane & 15;
    const int wr = w >> 1, wc = w & 1;

    f32x4 acc[4][4];
#pragma unroll
    for (int i = 0; i < 4; i++)
#pragma unroll
        for (int j = 0; j < 4; j++) acc[i][j] = f32x4{0.f, 0.f, 0.f, 0.f};

    const size_t rowStrideB = (size_t)E_ * 2;
    for (int kt = 0; kt < 32; ++kt) {
#pragma unroll
        for (int c2 = 0; c2 < 2; ++c2) {
            int L = (w * 2 + c2) * 1024 + lane * 16;
            int row = L >> 6, colb = L & 63;
            const char* gA = (const char*)A + (size_t)(tm * 128 + row) * rowStrideB + (size_t)kt * 64 + colb;
            const char* gB = (const char*)W + (size_t)(tn * 128 + row) * rowStrideB + (size_t)kt * 64 + colb;
            gload16_lds(gA, (char*)As + (w * 2 + c2) * 1024);
            gload16_lds(gB, (char*)Bs + (w * 2 + c2) * 1024);
        }
        __syncthreads();

        f16x8 aF[4], bF[4];
#pragma unroll
        for (int mi = 0; mi < 4; mi++)
            aF[mi] = *(const f16x8*)&As[(wr * 64 + mi * 16 + c) * 32 + g * 8];
#pragma unroll
        for (int ni = 0; ni < 4; ni++)
            bF[ni] = *(const f16x8*)&Bs[(wc * 64 + ni * 16 + c) * 32 + g * 8];
#pragma unroll
        for (int mi = 0; mi < 4; mi++)
#pragma unroll
            for (int ni = 0; ni < 4; ni++)
                acc[mi][ni] = __builtin_amdgcn_mfma_f32_16x16x32_f16(aF[mi], bF[ni], acc[mi][ni], 0, 0, 0);
        __syncthreads();
    }

#pragma unroll
    for (int mi = 0; mi < 4; mi++)
#pragma unroll
        for (int ni = 0; ni < 4; ni++)
#pragma unroll
            for (int r = 0; r < 4; r++) {
                int R  = tm * 128 + wr * 64 + mi * 16 + g * 4 + r;
                int Cc = tn * 128 + wc * 64 + ni * 16 + c;
                Cout[(size_t)R * E_ + Cc] = acc[mi][ni][r] + bias[Cc];
            }
}

// ---------------- flash attention: SWAPPED QK^T, in-register softmax ----------------
// Grid 1024 (8 xcd x 4 bh x 32 q-tiles of 32). Block 512 = 8 waves:
// wq = w&1 (16-q subtile), ws = w>>1 (kv quarter, 512 kv).
// Swapped: S = mfma(K,Q) -> lane (g,c) owns S[kv = nt*16+4g+r][q = q0+c]:
//   softmax per q = in-lane tree + 2 shfl_xor; mask = 1 u64/tile;
//   PV: O^T = mfma(V^T, P), P B-frag assembled via 16 ds_bpermute.
__global__ __launch_bounds__(512) void attn11_kernel(
    const _Float16* __restrict__ Qh,   // [B,H,LQ,D] pre-scaled by 0.125*log2e
    const _Float16* __restrict__ Kh,   // [B,H,LKV,D]
    const _Float16* __restrict__ Vt,   // [B,H,D,LKV]
    const unsigned long long* __restrict__ Mb,  // [B*LQ][LKV/64] bitmask
    _Float16* __restrict__ O)          // [B,LQ,E] f16
{
    __shared__ char ldsraw[35840];
    float* OfP = (float*)ldsraw;                   // [128 rows][68]
    float* Ml  = (float*)(ldsraw + 34816);         // [128][2]

    const int bid0 = blockIdx.x;
    const int xcd = bid0 & 7, jj = bid0 >> 3;
    const int bh = xcd * 4 + (jj >> 5);            // K/V L2-local per XCD
    const int qt = jj & 31;
    const int b = bh >> 4, h = bh & 15;
    const int tid = threadIdx.x;
    const int w = tid >> 6, lane = tid & 63;
    const int g = lane >> 4, c = lane & 15;
    const int wq = w & 1, ws = w >> 1;
    const int q0 = qt * 32 + wq * 16;

    // Q fragment (B-operand): q = q0+c, k = ks*32 + 8g + j
    f16x8 qf[2];
#pragma unroll
    for (int ks = 0; ks < 2; ++ks)
        qf[ks] = *(const f16x8*)&Qh[((size_t)bh * LQ_ + q0 + c) * D_ + ks * 32 + g * 8];

    f32x4 o[4];                 // o[dt][r] = O[q0+c][dt*16 + 4g + r] (pre-normalize)
#pragma unroll
    for (int dt = 0; dt < 4; dt++) o[dt] = f32x4{0.f, 0.f, 0.f, 0.f};
    float m = -1e30f, lsum = 0.f;

    const size_t kBase = (size_t)bh * LKV_ * D_;
    const size_t vBase = (size_t)bh * D_ * LKV_;
    const size_t mRow  = (size_t)(b * LQ_ + q0 + c) * (LKV_ / 64);

    // bpermute byte-indices (constant per lane): src groups 2(g&1), 2(g&1)+1
    const int srcLo = (((g & 1) << 1) * 16 + c) << 2;
    const int srcHi = ((((g & 1) << 1) + 1) * 16 + c) << 2;
    const bool hiSel = (g >= 2);

    const int kvStart = ws * 512, kvEnd = kvStart + 512;
    for (int kv0 = kvStart; kv0 < kvEnd; kv0 += 64) {
        // ---- swapped QK^T: s[nt][r] = S[kv0+nt*16+4g+r][q0+c] ----
        f32x4 s[4];
#pragma unroll
        for (int nt = 0; nt < 4; ++nt) {
            f32x4 accS = f32x4{0.f, 0.f, 0.f, 0.f};
#pragma unroll
            for (int ks = 0; ks < 2; ++ks) {
                f16x8 kf = *(const f16x8*)&Kh[kBase + (size_t)(kv0 + nt * 16 + c) * D_ + ks * 32 + g * 8];
                accS = __builtin_amdgcn_mfma_f32_16x16x32_f16(kf, qf[ks], accS, 0, 0, 0);
            }
            s[nt] = accS;
        }
        // ---- mask: one u64 per lane per tile; bit = nt*16 + 4g + r ----
        unsigned long long mks = Mb[mRow + (kv0 >> 6)] >> (g * 4);
#pragma unroll
        for (int nt = 0; nt < 4; ++nt) {
            unsigned nib = (unsigned)(mks >> (nt * 16)) & 0xFu;
            if (nib & 1u) s[nt][0] = -1e9f;
            if (nib & 2u) s[nt][1] = -1e9f;
            if (nib & 4u) s[nt][2] = -1e9f;
            if (nib & 8u) s[nt][3] = -1e9f;
        }
        // ---- online softmax per q (= c): in-lane 16-tree + cross-group ----
        float t0 = fmaxf(fmaxf(s[0][0], s[0][1]), fmaxf(s[0][2], s[0][3]));
        float t1 = fmaxf(fmaxf(s[1][0], s[1][1]), fmaxf(s[1][2], s[1][3]));
        float t2 = fmaxf(fmaxf(s[2][0], s[2][1]), fmaxf(s[2][2], s[2][3]));
        float t3 = fmaxf(fmaxf(s[3][0], s[3][1]), fmaxf(s[3][2], s[3][3]));
        float tmax = fmaxf(fmaxf(t0, t1), fmaxf(t2, t3));
        tmax = fmaxf(tmax, __shfl_xor(tmax, 16, 64));
        tmax = fmaxf(tmax, __shfl_xor(tmax, 32, 64));
        float mn = fmaxf(m, tmax);
        float scl = exp2f(m - mn);
        m = mn;
        float ts = 0.f;
#pragma unroll
        for (int nt = 0; nt < 4; ++nt) {
            float p0 = exp2f(s[nt][0] - m);
            float p1 = exp2f(s[nt][1] - m);
            float p2 = exp2f(s[nt][2] - m);
            float p3 = exp2f(s[nt][3] - m);
            s[nt][0] = p0; s[nt][1] = p1; s[nt][2] = p2; s[nt][3] = p3;
            ts += (p0 + p1) + (p2 + p3);
        }
        ts += __shfl_xor(ts, 16, 64);
        ts += __shfl_xor(ts, 32, 64);
        lsum = lsum * scl + ts;
#pragma unroll
        for (int dt = 0; dt < 4; dt++)
#pragma unroll
            for (int r = 0; r < 4; r++) o[dt][r] *= scl;
        // ---- pack P to f16 pairs: pk[nt][0]=(r0,r1), pk[nt][1]=(r2,r3) ----
        int pk[4][2];
#pragma unroll
        for (int nt = 0; nt < 4; ++nt) {
            pk[nt][0] = __builtin_bit_cast(int, __builtin_amdgcn_cvt_pkrtz(s[nt][0], s[nt][1]));
            pk[nt][1] = __builtin_bit_cast(int, __builtin_amdgcn_cvt_pkrtz(s[nt][2], s[nt][3]));
        }
        // ---- PV: assemble P B-frag via bpermute, O^T += V^T * P ----
#pragma unroll
        for (int ks = 0; ks < 2; ++ks) {
            const int ntL = 2 * ks, ntH = 2 * ks + 1;
            int aL0 = __builtin_amdgcn_ds_bpermute(srcLo, pk[ntL][0]);
            int aL1 = __builtin_amdgcn_ds_bpermute(srcLo, pk[ntL][1]);
            int aH0 = __builtin_amdgcn_ds_bpermute(srcHi, pk[ntL][0]);
            int aH1 = __builtin_amdgcn_ds_bpermute(srcHi, pk[ntL][1]);
            int bL0 = __builtin_amdgcn_ds_bpermute(srcLo, pk[ntH][0]);
            int bL1 = __builtin_amdgcn_ds_bpermute(srcLo, pk[ntH][1]);
            int bH0 = __builtin_amdgcn_ds_bpermute(srcHi, pk[ntH][0]);
            int bH1 = __builtin_amdgcn_ds_bpermute(srcHi, pk[ntH][1]);
            int u[4];
            u[0] = hiSel ? bL0 : aL0;
            u[1] = hiSel ? bL1 : aL1;
            u[2] = hiSel ? bH0 : aH0;
            u[3] = hiSel ? bH1 : aH1;
            f16x8 pf;
            {   // bit-assemble 4 u32 -> f16x8
                union { int i[4]; f16x8 v; } cvt;
                cvt.i[0] = u[0]; cvt.i[1] = u[1]; cvt.i[2] = u[2]; cvt.i[3] = u[3];
                pf = cvt.v;
            }
#pragma unroll
            for (int dt = 0; dt < 4; ++dt) {
                f16x8 vf = *(const f16x8*)&Vt[vBase + (size_t)(dt * 16 + c) * LKV_ + kv0 + ks * 32 + g * 8];
                o[dt] = __builtin_amdgcn_mfma_f32_16x16x32_f16(vf, pf, o[dt], 0, 0, 0);
            }
        }
    }

    // ---- publish partials: row = w*16 + q-local(c), col = d ----
#pragma unroll
    for (int dt = 0; dt < 4; ++dt)
#pragma unroll
        for (int r = 0; r < 4; r++)
            OfP[(w * 16 + c) * 68 + dt * 16 + 4 * g + r] = o[dt][r];
    if (lane < 16) {
        Ml[(w * 16 + lane) * 2 + 0] = m;
        Ml[(w * 16 + lane) * 2 + 1] = lsum;
    }
    __syncthreads();

    // ---- combine 4 kv-partials per q-row (base-2 domain) ----
    const int d = tid & 63;
    const int qlBase = tid >> 6;
#pragma unroll
    for (int pass = 0; pass < 4; ++pass) {
        int ql = pass * 8 + qlBase;          // 0..31
        int wq2 = ql >> 4, qlr = ql & 15;
        float mm[4];
        float M = -3e38f;
#pragma unroll
        for (int w2 = 0; w2 < 4; ++w2) {
            mm[w2] = Ml[((w2 * 2 + wq2) * 16 + qlr) * 2];
            M = fmaxf(M, mm[w2]);
        }
        float L = 0.f, acc = 0.f;
#pragma unroll
        for (int w2 = 0; w2 < 4; ++w2) {
            int sr = (w2 * 2 + wq2) * 16 + qlr;
            float e = exp2f(mm[w2] - M);
            L += Ml[sr * 2 + 1] * e;
            acc += OfP[sr * 68 + d] * e;
        }
        O[((size_t)b * LQ_ + qt * 32 + ql) * E_ + h * 64 + d] = (_Float16)(acc / L);
    }
}

extern "C" void kernel_launch(void* const* d_in, const int* in_sizes, int n_in,
                              void* d_out, int out_size, void* d_ws, size_t ws_size,
                              hipStream_t stream)
{
    const float* x   = (const float*)d_in[0];
    const float* ctx = (const float*)d_in[1];
    const void*  msk = d_in[2];
    const float* Wq  = (const float*)d_in[3];
    const float* Wk  = (const float*)d_in[4];
    const float* Wv  = (const float*)d_in[5];
    const float* fcw = (const float*)d_in[6];
    const float* fcb = (const float*)d_in[7];
    float* out = (float*)d_out;

    char* ws = (char*)d_ws;
    size_t off = 0;
    auto alloc = [&](size_t bytes) { char* p = ws + off; off += (bytes + 255) & ~255ull; return p; };

    int* modep = (int*)alloc(256);
    unsigned long long* Mb = (unsigned long long*)alloc((size_t)B_ * LQ_ * (LKV_ / 64) * 8);
    _Float16* xh   = (_Float16*)alloc((size_t)B_ * LQ_ * E_ * 2);
    _Float16* ch   = (_Float16*)alloc((size_t)B_ * LKV_ * E_ * 2);
    _Float16* wqh  = (_Float16*)alloc((size_t)E_ * E_ * 2);
    _Float16* wkvh = (_Float16*)alloc((size_t)2 * E_ * E_ * 2);
    _Float16* fwh  = (_Float16*)alloc((size_t)E_ * E_ * 2);
    float*    fbf  = (float*)alloc((size_t)E_ * 4);
    _Float16* Qh   = (_Float16*)alloc((size_t)B_ * H_ * LQ_ * D_ * 2);
    _Float16* Kh   = (_Float16*)alloc((size_t)B_ * H_ * LKV_ * D_ * 2);
    _Float16* Vt   = (_Float16*)alloc((size_t)B_ * H_ * LKV_ * D_ * 2);
    _Float16* Ob   = xh;  // safe alias: gemm11_qkv (last reader of xh) finishes before attn writes Ob
    (void)ws_size; (void)in_sizes; (void)n_in; (void)out_size;

    probe11<<<1, 64, 0, stream>>>(msk, modep);

    canon11_all<<<2048, 256, 0, stream>>>(x, ctx, Wq, Wk, Wv, fcw, fcb, msk,
                                          xh, ch, wqh, wkvh, fwh, fbf, Mb, modep);

    gemm11_qkv<<<640, 256, 0, stream>>>(xh, ch, wqh, wkvh, Qh, Kh, Vt);

    attn11_kernel<<<1024, 512, 0, stream>>>(Qh, Kh, Vt, Mb, Ob);

    gemm11_fc<<<128, 256, 0, stream>>>(Ob, fwh, fbf, out);
}

// Round 12
// 226.538 us; speedup vs baseline: 2.2056x; 1.0078x over previous
//
#include <hip/hip_runtime.h>
#include <hip/hip_bf16.h>

#define B_   2
#define H_   16
#define LQ_  1024
#define LKV_ 2048
#define D_   64
#define E_   1024

typedef __attribute__((ext_vector_type(8))) _Float16 f16x8;
typedef __attribute__((ext_vector_type(4))) float   f32x4;

__device__ __forceinline__ void gload16_lds(const void* g, void* l) {
    __builtin_amdgcn_global_load_lds(
        (const __attribute__((address_space(1))) unsigned int*)g,
        (__attribute__((address_space(3))) unsigned int*)l, 16, 0, 0);
}

// ---------------- one-wave mask-dtype probe ----------------
__global__ void probe12(const void* __restrict__ msk, int* __restrict__ modep) {
    int lane = threadIdx.x;
    int notInt = 0, notF32 = 0, notBF = 0;
    for (int i = lane; i < 256; i += 64) {
        unsigned v = ((const unsigned*)msk)[i * 997];
        if (v > 1u) notInt = 1;
        if (v != 0u && v != 0x3F800000u) notF32 = 1;
        if (v != 0u && v != 0x3F80u && v != 0x3F800000u && v != 0x3F803F80u) notBF = 1;
    }
    notInt = __any(notInt); notF32 = __any(notF32); notBF = __any(notBF);
    if (lane == 0) *modep = !notInt ? 0 : (!notF32 ? 1 : (!notBF ? 2 : 3));
}

// ---------------- streaming canonicalization ----------------
__global__ void canon12_all(
    const float* __restrict__ x,  const float* __restrict__ ctx,
    const float* __restrict__ wq, const float* __restrict__ wk,
    const float* __restrict__ wv, const float* __restrict__ fw,
    const float* __restrict__ fb, const void* __restrict__ msk,
    _Float16* __restrict__ xh,  _Float16* __restrict__ ch,
    _Float16* __restrict__ wqh, _Float16* __restrict__ wkvh,
    _Float16* __restrict__ fwh, float* __restrict__ fbf,
    unsigned long long* __restrict__ Mb, const int* __restrict__ modep)
{
    const int mmode = *modep;
    const int total = 1376384;
    const int stride = gridDim.x * blockDim.x;
    for (int idx = blockIdx.x * blockDim.x + threadIdx.x; idx < total; idx += stride) {
        if (idx < 1310720) {
            const float* src; _Float16* dst; int rel;
            if (idx < 262144)       { src = x;   dst = xh;   rel = idx; }
            else if (idx < 786432)  { src = ctx; dst = ch;   rel = idx - 262144; }
            else if (idx < 917504)  { src = wq;  dst = wqh;  rel = idx - 786432; }
            else if (idx < 1048576) { src = wk;  dst = wkvh; rel = idx - 917504; }
            else if (idx < 1179648) { src = wv;  dst = wkvh + (size_t)E_ * E_; rel = idx - 1048576; }
            else                    { src = fw;  dst = fwh;  rel = idx - 1179648; }
            f32x4 a = ((const f32x4*)src)[2 * rel], b = ((const f32x4*)src)[2 * rel + 1];
            f16x8 o;
            o[0] = (_Float16)a.x; o[1] = (_Float16)a.y; o[2] = (_Float16)a.z; o[3] = (_Float16)a.w;
            o[4] = (_Float16)b.x; o[5] = (_Float16)b.y; o[6] = (_Float16)b.z; o[7] = (_Float16)b.w;
            ((f16x8*)dst)[rel] = o;
        } else if (idx < 1310848) {
            int rel = idx - 1310720;
#pragma unroll
            for (int j = 0; j < 8; ++j) fbf[rel * 8 + j] = fb[rel * 8 + j];
        } else {
            int rel = idx - 1310848;
            const size_t base = (size_t)rel * 64;
            unsigned long long v = 0;
            if (mmode == 0) {
                const int* p = (const int*)msk + base;
#pragma unroll
                for (int j = 0; j < 64; ++j) if (p[j] != 0) v |= 1ull << j;
            } else if (mmode == 1) {
                const float* p = (const float*)msk + base;
#pragma unroll
                for (int j = 0; j < 64; ++j) if (p[j] != 0.0f) v |= 1ull << j;
            } else if (mmode == 2) {
                const unsigned short* p = (const unsigned short*)msk + base;
#pragma unroll
                for (int j = 0; j < 64; ++j) if (p[j] != 0) v |= 1ull << j;
            } else {
                const unsigned char* p = (const unsigned char*)msk + base;
#pragma unroll
                for (int j = 0; j < 64; ++j) if (p[j] != 0) v |= 1ull << j;
            }
            Mb[rel] = v;
        }
    }
}

// ---------------- fused Q + K|V projection GEMM ----------------
// V epilogue now writes TILED layout: Vt[bh][kv>>6][d][kv&63]
// -> PV loads become 128B-strided (L2-channel friendly) instead of 4KB-strided.
__global__ __launch_bounds__(256) void gemm12_qkv(
    const _Float16* __restrict__ xh, const _Float16* __restrict__ ch,
    const _Float16* __restrict__ wqh, const _Float16* __restrict__ wkvh,
    _Float16* __restrict__ Qh, _Float16* __restrict__ Kh, _Float16* __restrict__ Vt)
{
    __shared__ _Float16 As[128 * 32];
    __shared__ _Float16 Bs[128 * 32];

    const int bid = blockIdx.x;
    const bool isQ = bid < 128;
    const _Float16* A; const _Float16* W; int tm, tn;
    if (isQ) { A = xh; W = wqh; tm = bid >> 3; tn = bid & 7; }
    else     { int b2 = bid - 128; A = ch; W = wkvh; tm = b2 >> 4; tn = b2 & 15; }

    const int tid = threadIdx.x;
    const int w = tid >> 6, lane = tid & 63;
    const int g = lane >> 4, c = lane & 15;
    const int wr = w >> 1, wc = w & 1;

    f32x4 acc[4][4];
#pragma unroll
    for (int i = 0; i < 4; i++)
#pragma unroll
        for (int j = 0; j < 4; j++) acc[i][j] = f32x4{0.f, 0.f, 0.f, 0.f};

    const size_t rowStrideB = (size_t)E_ * 2;
    for (int kt = 0; kt < 32; ++kt) {
#pragma unroll
        for (int c2 = 0; c2 < 2; ++c2) {
            int L = (w * 2 + c2) * 1024 + lane * 16;
            int row = L >> 6, colb = L & 63;
            const char* gA = (const char*)A + (size_t)(tm * 128 + row) * rowStrideB + (size_t)kt * 64 + colb;
            const char* gB = (const char*)W + (size_t)(tn * 128 + row) * rowStrideB + (size_t)kt * 64 + colb;
            gload16_lds(gA, (char*)As + (w * 2 + c2) * 1024);
            gload16_lds(gB, (char*)Bs + (w * 2 + c2) * 1024);
        }
        __syncthreads();

        f16x8 aF[4], bF[4];
#pragma unroll
        for (int mi = 0; mi < 4; mi++)
            aF[mi] = *(const f16x8*)&As[(wr * 64 + mi * 16 + c) * 32 + g * 8];
#pragma unroll
        for (int ni = 0; ni < 4; ni++)
            bF[ni] = *(const f16x8*)&Bs[(wc * 64 + ni * 16 + c) * 32 + g * 8];
#pragma unroll
        for (int mi = 0; mi < 4; mi++)
#pragma unroll
            for (int ni = 0; ni < 4; ni++)
                acc[mi][ni] = __builtin_amdgcn_mfma_f32_16x16x32_f16(aF[mi], bF[ni], acc[mi][ni], 0, 0, 0);
        __syncthreads();
    }

#pragma unroll
    for (int mi = 0; mi < 4; mi++) {
#pragma unroll
        for (int ni = 0; ni < 4; ni++) {
#pragma unroll
            for (int r = 0; r < 4; r++) {
                int R  = tm * 128 + wr * 64 + mi * 16 + g * 4 + r;
                int Cc = tn * 128 + wc * 64 + ni * 16 + c;
                float v = acc[mi][ni][r];
                if (isQ) {
                    int b = R >> 10, q = R & 1023;
                    int h = Cc >> 6, d = Cc & 63;
                    // 0.125 * log2(e): attention works in exp2 domain
                    Qh[((size_t)(b * H_ + h) * LQ_ + q) * D_ + d] = (_Float16)(v * 0.18033688011112042f);
                } else {
                    int b = R >> 11, k = R & 2047;
                    int isV = Cc >> 10, cc2 = Cc & 1023;
                    int h = cc2 >> 6, d = cc2 & 63;
                    if (!isV)
                        Kh[((size_t)(b * H_ + h) * LKV_ + k) * D_ + d] = (_Float16)v;
                    else {
                        // tiled: [bh][k>>6][d][k&63]
                        size_t bh = (size_t)(b * H_ + h);
                        Vt[((bh * (LKV_ / 64) + (k >> 6)) * D_ + d) * 64 + (k & 63)] = (_Float16)v;
                    }
                }
            }
        }
    }
}

// ---------------- FC GEMM ----------------
__global__ __launch_bounds__(256) void gemm12_fc(
    const _Float16* __restrict__ A, const _Float16* __restrict__ W,
    const float* __restrict__ bias, float* __restrict__ Cout)
{
    __shared__ _Float16 As[128 * 32];
    __shared__ _Float16 Bs[128 * 32];

    const int tm = blockIdx.x >> 3, tn = blockIdx.x & 7;
    const int tid = threadIdx.x;
    const int w = tid >> 6, lane = tid & 63;
    const int g = lane >> 4, c = lane & 15;
    const int wr = w >> 1, wc = w & 1;

    f32x4 acc[4][4];
#pragma unroll
    for (int i = 0; i < 4; i++)
#pragma unroll
        for (int j = 0; j < 4; j++) acc[i][j] = f32x4{0.f, 0.f, 0.f, 0.f};

    const size_t rowStrideB = (size_t)E_ * 2;
    for (int kt = 0; kt < 32; ++kt) {
#pragma unroll
        for (int c2 = 0; c2 < 2; ++c2) {
            int L = (w * 2 + c2) * 1024 + lane * 16;
            int row = L >> 6, colb = L & 63;
            const char* gA = (const char*)A + (size_t)(tm * 128 + row) * rowStrideB + (size_t)kt * 64 + colb;
            const char* gB = (const char*)W + (size_t)(tn * 128 + row) * rowStrideB + (size_t)kt * 64 + colb;
            gload16_lds(gA, (char*)As + (w * 2 + c2) * 1024);
            gload16_lds(gB, (char*)Bs + (w * 2 + c2) * 1024);
        }
        __syncthreads();

        f16x8 aF[4], bF[4];
#pragma unroll
        for (int mi = 0; mi < 4; mi++)
            aF[mi] = *(const f16x8*)&As[(wr * 64 + mi * 16 + c) * 32 + g * 8];
#pragma unroll
        for (int ni = 0; ni < 4; ni++)
            bF[ni] = *(const f16x8*)&Bs[(wc * 64 + ni * 16 + c) * 32 + g * 8];
#pragma unroll
        for (int mi = 0; mi < 4; mi++)
#pragma unroll
            for (int ni = 0; ni < 4; ni++)
                acc[mi][ni] = __builtin_amdgcn_mfma_f32_16x16x32_f16(aF[mi], bF[ni], acc[mi][ni], 0, 0, 0);
        __syncthreads();
    }

#pragma unroll
    for (int mi = 0; mi < 4; mi++)
#pragma unroll
        for (int ni = 0; ni < 4; ni++)
#pragma unroll
            for (int r = 0; r < 4; r++) {
                int R  = tm * 128 + wr * 64 + mi * 16 + g * 4 + r;
                int Cc = tn * 128 + wc * 64 + ni * 16 + c;
                Cout[(size_t)R * E_ + Cc] = acc[mi][ni][r] + bias[Cc];
            }
}

// ---------------- flash attention: swapped QK^T + TILED V ----------------
// Identical to round 11 except the V load indexing (single-variable A/B).
__global__ __launch_bounds__(512) void attn12_kernel(
    const _Float16* __restrict__ Qh,   // [B,H,LQ,D] pre-scaled by 0.125*log2e
    const _Float16* __restrict__ Kh,   // [B,H,LKV,D]
    const _Float16* __restrict__ Vt,   // [B*H][LKV/64][D][64] tiled
    const unsigned long long* __restrict__ Mb,  // [B*LQ][LKV/64] bitmask
    _Float16* __restrict__ O)          // [B,LQ,E] f16
{
    __shared__ char ldsraw[35840];
    float* OfP = (float*)ldsraw;                   // [128 rows][68]
    float* Ml  = (float*)(ldsraw + 34816);         // [128][2]

    const int bid0 = blockIdx.x;
    const int xcd = bid0 & 7, jj = bid0 >> 3;
    const int bh = xcd * 4 + (jj >> 5);            // K/V L2-local per XCD
    const int qt = jj & 31;
    const int b = bh >> 4, h = bh & 15;
    const int tid = threadIdx.x;
    const int w = tid >> 6, lane = tid & 63;
    const int g = lane >> 4, c = lane & 15;
    const int wq = w & 1, ws = w >> 1;
    const int q0 = qt * 32 + wq * 16;

    f16x8 qf[2];
#pragma unroll
    for (int ks = 0; ks < 2; ++ks)
        qf[ks] = *(const f16x8*)&Qh[((size_t)bh * LQ_ + q0 + c) * D_ + ks * 32 + g * 8];

    f32x4 o[4];                 // o[dt][r] = O[q0+c][dt*16 + 4g + r]
#pragma unroll
    for (int dt = 0; dt < 4; dt++) o[dt] = f32x4{0.f, 0.f, 0.f, 0.f};
    float m = -1e30f, lsum = 0.f;

    const size_t kBase = (size_t)bh * LKV_ * D_;
    const size_t vTileBase = (size_t)bh * (LKV_ / 64);
    const size_t mRow  = (size_t)(b * LQ_ + q0 + c) * (LKV_ / 64);

    const int srcLo = (((g & 1) << 1) * 16 + c) << 2;
    const int srcHi = ((((g & 1) << 1) + 1) * 16 + c) << 2;
    const bool hiSel = (g >= 2);

    const int kvStart = ws * 512, kvEnd = kvStart + 512;
    for (int kv0 = kvStart; kv0 < kvEnd; kv0 += 64) {
        // ---- swapped QK^T: s[nt][r] = S[kv0+nt*16+4g+r][q0+c] ----
        f32x4 s[4];
#pragma unroll
        for (int nt = 0; nt < 4; ++nt) {
            f32x4 accS = f32x4{0.f, 0.f, 0.f, 0.f};
#pragma unroll
            for (int ks = 0; ks < 2; ++ks) {
                f16x8 kf = *(const f16x8*)&Kh[kBase + (size_t)(kv0 + nt * 16 + c) * D_ + ks * 32 + g * 8];
                accS = __builtin_amdgcn_mfma_f32_16x16x32_f16(kf, qf[ks], accS, 0, 0, 0);
            }
            s[nt] = accS;
        }
        // ---- mask ----
        unsigned long long mks = Mb[mRow + (kv0 >> 6)] >> (g * 4);
#pragma unroll
        for (int nt = 0; nt < 4; ++nt) {
            unsigned nib = (unsigned)(mks >> (nt * 16)) & 0xFu;
            if (nib & 1u) s[nt][0] = -1e9f;
            if (nib & 2u) s[nt][1] = -1e9f;
            if (nib & 4u) s[nt][2] = -1e9f;
            if (nib & 8u) s[nt][3] = -1e9f;
        }
        // ---- online softmax per q (= c) ----
        float t0 = fmaxf(fmaxf(s[0][0], s[0][1]), fmaxf(s[0][2], s[0][3]));
        float t1 = fmaxf(fmaxf(s[1][0], s[1][1]), fmaxf(s[1][2], s[1][3]));
        float t2 = fmaxf(fmaxf(s[2][0], s[2][1]), fmaxf(s[2][2], s[2][3]));
        float t3 = fmaxf(fmaxf(s[3][0], s[3][1]), fmaxf(s[3][2], s[3][3]));
        float tmax = fmaxf(fmaxf(t0, t1), fmaxf(t2, t3));
        tmax = fmaxf(tmax, __shfl_xor(tmax, 16, 64));
        tmax = fmaxf(tmax, __shfl_xor(tmax, 32, 64));
        float mn = fmaxf(m, tmax);
        float scl = exp2f(m - mn);
        m = mn;
        float ts = 0.f;
#pragma unroll
        for (int nt = 0; nt < 4; ++nt) {
            float p0 = exp2f(s[nt][0] - m);
            float p1 = exp2f(s[nt][1] - m);
            float p2 = exp2f(s[nt][2] - m);
            float p3 = exp2f(s[nt][3] - m);
            s[nt][0] = p0; s[nt][1] = p1; s[nt][2] = p2; s[nt][3] = p3;
            ts += (p0 + p1) + (p2 + p3);
        }
        ts += __shfl_xor(ts, 16, 64);
        ts += __shfl_xor(ts, 32, 64);
        lsum = lsum * scl + ts;
#pragma unroll
        for (int dt = 0; dt < 4; dt++)
#pragma unroll
            for (int r = 0; r < 4; r++) o[dt][r] *= scl;
        // ---- pack P to f16 pairs ----
        int pk[4][2];
#pragma unroll
        for (int nt = 0; nt < 4; ++nt) {
            pk[nt][0] = __builtin_bit_cast(int, __builtin_amdgcn_cvt_pkrtz(s[nt][0], s[nt][1]));
            pk[nt][1] = __builtin_bit_cast(int, __builtin_amdgcn_cvt_pkrtz(s[nt][2], s[nt][3]));
        }
        // ---- PV with tiled V: 128B-strided loads ----
        const _Float16* vTile = Vt + (vTileBase + (kv0 >> 6)) * (size_t)(D_ * 64);
#pragma unroll
        for (int ks = 0; ks < 2; ++ks) {
            const int ntL = 2 * ks, ntH = 2 * ks + 1;
            int aL0 = __builtin_amdgcn_ds_bpermute(srcLo, pk[ntL][0]);
            int aL1 = __builtin_amdgcn_ds_bpermute(srcLo, pk[ntL][1]);
            int aH0 = __builtin_amdgcn_ds_bpermute(srcHi, pk[ntL][0]);
            int aH1 = __builtin_amdgcn_ds_bpermute(srcHi, pk[ntL][1]);
            int bL0 = __builtin_amdgcn_ds_bpermute(srcLo, pk[ntH][0]);
            int bL1 = __builtin_amdgcn_ds_bpermute(srcLo, pk[ntH][1]);
            int bH0 = __builtin_amdgcn_ds_bpermute(srcHi, pk[ntH][0]);
            int bH1 = __builtin_amdgcn_ds_bpermute(srcHi, pk[ntH][1]);
            int u[4];
            u[0] = hiSel ? bL0 : aL0;
            u[1] = hiSel ? bL1 : aL1;
            u[2] = hiSel ? bH0 : aH0;
            u[3] = hiSel ? bH1 : aH1;
            f16x8 pf;
            {
                union { int i[4]; f16x8 v; } cvt;
                cvt.i[0] = u[0]; cvt.i[1] = u[1]; cvt.i[2] = u[2]; cvt.i[3] = u[3];
                pf = cvt.v;
            }
#pragma unroll
            for (int dt = 0; dt < 4; ++dt) {
                f16x8 vf = *(const f16x8*)&vTile[(size_t)(dt * 16 + c) * 64 + ks * 32 + g * 8];
                o[dt] = __builtin_amdgcn_mfma_f32_16x16x32_f16(vf, pf, o[dt], 0, 0, 0);
            }
        }
    }

    // ---- publish partials ----
#pragma unroll
    for (int dt = 0; dt < 4; ++dt)
#pragma unroll
        for (int r = 0; r < 4; r++)
            OfP[(w * 16 + c) * 68 + dt * 16 + 4 * g + r] = o[dt][r];
    if (lane < 16) {
        Ml[(w * 16 + lane) * 2 + 0] = m;
        Ml[(w * 16 + lane) * 2 + 1] = lsum;
    }
    __syncthreads();

    // ---- combine 4 kv-partials per q-row ----
    const int d = tid & 63;
    const int qlBase = tid >> 6;
#pragma unroll
    for (int pass = 0; pass < 4; ++pass) {
        int ql = pass * 8 + qlBase;
        int wq2 = ql >> 4, qlr = ql & 15;
        float mm[4];
        float M = -3e38f;
#pragma unroll
        for (int w2 = 0; w2 < 4; ++w2) {
            mm[w2] = Ml[((w2 * 2 + wq2) * 16 + qlr) * 2];
            M = fmaxf(M, mm[w2]);
        }
        float L = 0.f, acc = 0.f;
#pragma unroll
        for (int w2 = 0; w2 < 4; ++w2) {
            int sr = (w2 * 2 + wq2) * 16 + qlr;
            float e = exp2f(mm[w2] - M);
            L += Ml[sr * 2 + 1] * e;
            acc += OfP[sr * 68 + d] * e;
        }
        O[((size_t)b * LQ_ + qt * 32 + ql) * E_ + h * 64 + d] = (_Float16)(acc / L);
    }
}

extern "C" void kernel_launch(void* const* d_in, const int* in_sizes, int n_in,
                              void* d_out, int out_size, void* d_ws, size_t ws_size,
                              hipStream_t stream)
{
    const float* x   = (const float*)d_in[0];
    const float* ctx = (const float*)d_in[1];
    const void*  msk = d_in[2];
    const float* Wq  = (const float*)d_in[3];
    const float* Wk  = (const float*)d_in[4];
    const float* Wv  = (const float*)d_in[5];
    const float* fcw = (const float*)d_in[6];
    const float* fcb = (const float*)d_in[7];
    float* out = (float*)d_out;

    char* ws = (char*)d_ws;
    size_t off = 0;
    auto alloc = [&](size_t bytes) { char* p = ws + off; off += (bytes + 255) & ~255ull; return p; };

    int* modep = (int*)alloc(256);
    unsigned long long* Mb = (unsigned long long*)alloc((size_t)B_ * LQ_ * (LKV_ / 64) * 8);
    _Float16* xh   = (_Float16*)alloc((size_t)B_ * LQ_ * E_ * 2);
    _Float16* ch   = (_Float16*)alloc((size_t)B_ * LKV_ * E_ * 2);
    _Float16* wqh  = (_Float16*)alloc((size_t)E_ * E_ * 2);
    _Float16* wkvh = (_Float16*)alloc((size_t)2 * E_ * E_ * 2);
    _Float16* fwh  = (_Float16*)alloc((size_t)E_ * E_ * 2);
    float*    fbf  = (float*)alloc((size_t)E_ * 4);
    _Float16* Qh   = (_Float16*)alloc((size_t)B_ * H_ * LQ_ * D_ * 2);
    _Float16* Kh   = (_Float16*)alloc((size_t)B_ * H_ * LKV_ * D_ * 2);
    _Float16* Vt   = (_Float16*)alloc((size_t)B_ * H_ * LKV_ * D_ * 2);
    _Float16* Ob   = xh;  // safe alias: gemm12_qkv (last reader of xh) finishes before attn writes Ob
    (void)ws_size; (void)in_sizes; (void)n_in; (void)out_size;

    probe12<<<1, 64, 0, stream>>>(msk, modep);

    canon12_all<<<2048, 256, 0, stream>>>(x, ctx, Wq, Wk, Wv, fcw, fcb, msk,
                                          xh, ch, wqh, wkvh, fwh, fbf, Mb, modep);

    gemm12_qkv<<<640, 256, 0, stream>>>(xh, ch, wqh, wkvh, Qh, Kh, Vt);

    attn12_kernel<<<1024, 512, 0, stream>>>(Qh, Kh, Vt, Mb, Ob);

    gemm12_fc<<<128, 256, 0, stream>>>(Ob, fwh, fbf, out);
}

// Round 13
// 160.085 us; speedup vs baseline: 3.1212x; 1.4151x over previous
//
#include <hip/hip_runtime.h>
#include <hip/hip_bf16.h>

#define B_   2
#define H_   16
#define LQ_  1024
#define LKV_ 2048
#define D_   64
#define E_   1024

typedef __attribute__((ext_vector_type(8))) _Float16 f16x8;
typedef __attribute__((ext_vector_type(4))) float   f32x4;

__device__ __forceinline__ void gload16_lds(const void* g, void* l) {
    __builtin_amdgcn_global_load_lds(
        (const __attribute__((address_space(1))) unsigned int*)g,
        (__attribute__((address_space(3))) unsigned int*)l, 16, 0, 0);
}

// ---------------- one-wave mask-dtype probe ----------------
__global__ void probe13(const void* __restrict__ msk, int* __restrict__ modep) {
    int lane = threadIdx.x;
    int notInt = 0, notF32 = 0, notBF = 0;
    for (int i = lane; i < 256; i += 64) {
        unsigned v = ((const unsigned*)msk)[i * 997];
        if (v > 1u) notInt = 1;
        if (v != 0u && v != 0x3F800000u) notF32 = 1;
        if (v != 0u && v != 0x3F80u && v != 0x3F800000u && v != 0x3F803F80u) notBF = 1;
    }
    notInt = __any(notInt); notF32 = __any(notF32); notBF = __any(notBF);
    if (lane == 0) *modep = !notInt ? 0 : (!notF32 ? 1 : (!notBF ? 2 : 3));
}

// ---------------- streaming canonicalization (mask -> TRANSPOSED bits [t][row]) --------
__global__ void canon13_all(
    const float* __restrict__ x,  const float* __restrict__ ctx,
    const float* __restrict__ wq, const float* __restrict__ wk,
    const float* __restrict__ wv, const float* __restrict__ fw,
    const float* __restrict__ fb, const void* __restrict__ msk,
    _Float16* __restrict__ xh,  _Float16* __restrict__ ch,
    _Float16* __restrict__ wqh, _Float16* __restrict__ wkvh,
    _Float16* __restrict__ fwh, float* __restrict__ fbf,
    unsigned long long* __restrict__ Mbt, const int* __restrict__ modep)
{
    const int mmode = *modep;
    const int total = 1376384;
    const int stride = gridDim.x * blockDim.x;
    for (int idx = blockIdx.x * blockDim.x + threadIdx.x; idx < total; idx += stride) {
        if (idx < 1310720) {
            const float* src; _Float16* dst; int rel;
            if (idx < 262144)       { src = x;   dst = xh;   rel = idx; }
            else if (idx < 786432)  { src = ctx; dst = ch;   rel = idx - 262144; }
            else if (idx < 917504)  { src = wq;  dst = wqh;  rel = idx - 786432; }
            else if (idx < 1048576) { src = wk;  dst = wkvh; rel = idx - 917504; }
            else if (idx < 1179648) { src = wv;  dst = wkvh + (size_t)E_ * E_; rel = idx - 1048576; }
            else                    { src = fw;  dst = fwh;  rel = idx - 1179648; }
            f32x4 a = ((const f32x4*)src)[2 * rel], b = ((const f32x4*)src)[2 * rel + 1];
            f16x8 o;
            o[0] = (_Float16)a.x; o[1] = (_Float16)a.y; o[2] = (_Float16)a.z; o[3] = (_Float16)a.w;
            o[4] = (_Float16)b.x; o[5] = (_Float16)b.y; o[6] = (_Float16)b.z; o[7] = (_Float16)b.w;
            ((f16x8*)dst)[rel] = o;
        } else if (idx < 1310848) {
            int rel = idx - 1310720;
#pragma unroll
            for (int j = 0; j < 8; ++j) fbf[rel * 8 + j] = fb[rel * 8 + j];
        } else {
            int rel = idx - 1310848;           // rel = row*32 + t
            const size_t base = (size_t)rel * 64;
            unsigned long long v = 0;
            if (mmode == 0) {
                const int* p = (const int*)msk + base;
#pragma unroll
                for (int j = 0; j < 64; ++j) if (p[j] != 0) v |= 1ull << j;
            } else if (mmode == 1) {
                const float* p = (const float*)msk + base;
#pragma unroll
                for (int j = 0; j < 64; ++j) if (p[j] != 0.0f) v |= 1ull << j;
            } else if (mmode == 2) {
                const unsigned short* p = (const unsigned short*)msk + base;
#pragma unroll
                for (int j = 0; j < 64; ++j) if (p[j] != 0) v |= 1ull << j;
            } else {
                const unsigned char* p = (const unsigned char*)msk + base;
#pragma unroll
                for (int j = 0; j < 64; ++j) if (p[j] != 0) v |= 1ull << j;
            }
            Mbt[(rel & 31) * 2048 + (rel >> 5)] = v;   // transposed: [t][b*LQ+q]
        }
    }
}

// ---------------- fused Q + K|V projection GEMM (V tiled [bh][t][d][64]) ----------------
__global__ __launch_bounds__(256) void gemm13_qkv(
    const _Float16* __restrict__ xh, const _Float16* __restrict__ ch,
    const _Float16* __restrict__ wqh, const _Float16* __restrict__ wkvh,
    _Float16* __restrict__ Qh, _Float16* __restrict__ Kh, _Float16* __restrict__ Vt)
{
    __shared__ _Float16 As[128 * 32];
    __shared__ _Float16 Bs[128 * 32];

    const int bid = blockIdx.x;
    const bool isQ = bid < 128;
    const _Float16* A; const _Float16* W; int tm, tn;
    if (isQ) { A = xh; W = wqh; tm = bid >> 3; tn = bid & 7; }
    else     { int b2 = bid - 128; A = ch; W = wkvh; tm = b2 >> 4; tn = b2 & 15; }

    const int tid = threadIdx.x;
    const int w = tid >> 6, lane = tid & 63;
    const int g = lane >> 4, c = lane & 15;
    const int wr = w >> 1, wc = w & 1;

    f32x4 acc[4][4];
#pragma unroll
    for (int i = 0; i < 4; i++)
#pragma unroll
        for (int j = 0; j < 4; j++) acc[i][j] = f32x4{0.f, 0.f, 0.f, 0.f};

    const size_t rowStrideB = (size_t)E_ * 2;
    for (int kt = 0; kt < 32; ++kt) {
#pragma unroll
        for (int c2 = 0; c2 < 2; ++c2) {
            int L = (w * 2 + c2) * 1024 + lane * 16;
            int row = L >> 6, colb = L & 63;
            const char* gA = (const char*)A + (size_t)(tm * 128 + row) * rowStrideB + (size_t)kt * 64 + colb;
            const char* gB = (const char*)W + (size_t)(tn * 128 + row) * rowStrideB + (size_t)kt * 64 + colb;
            gload16_lds(gA, (char*)As + (w * 2 + c2) * 1024);
            gload16_lds(gB, (char*)Bs + (w * 2 + c2) * 1024);
        }
        __syncthreads();

        f16x8 aF[4], bF[4];
#pragma unroll
        for (int mi = 0; mi < 4; mi++)
            aF[mi] = *(const f16x8*)&As[(wr * 64 + mi * 16 + c) * 32 + g * 8];
#pragma unroll
        for (int ni = 0; ni < 4; ni++)
            bF[ni] = *(const f16x8*)&Bs[(wc * 64 + ni * 16 + c) * 32 + g * 8];
#pragma unroll
        for (int mi = 0; mi < 4; mi++)
#pragma unroll
            for (int ni = 0; ni < 4; ni++)
                acc[mi][ni] = __builtin_amdgcn_mfma_f32_16x16x32_f16(aF[mi], bF[ni], acc[mi][ni], 0, 0, 0);
        __syncthreads();
    }

#pragma unroll
    for (int mi = 0; mi < 4; mi++) {
#pragma unroll
        for (int ni = 0; ni < 4; ni++) {
#pragma unroll
            for (int r = 0; r < 4; r++) {
                int R  = tm * 128 + wr * 64 + mi * 16 + g * 4 + r;
                int Cc = tn * 128 + wc * 64 + ni * 16 + c;
                float v = acc[mi][ni][r];
                if (isQ) {
                    int b = R >> 10, q = R & 1023;
                    int h = Cc >> 6, d = Cc & 63;
                    // 0.125 * log2(e): attention works in exp2 domain
                    Qh[((size_t)(b * H_ + h) * LQ_ + q) * D_ + d] = (_Float16)(v * 0.18033688011112042f);
                } else {
                    int b = R >> 11, k = R & 2047;
                    int isV = Cc >> 10, cc2 = Cc & 1023;
                    int h = cc2 >> 6, d = cc2 & 63;
                    if (!isV)
                        Kh[((size_t)(b * H_ + h) * LKV_ + k) * D_ + d] = (_Float16)v;
                    else {
                        size_t bh = (size_t)(b * H_ + h);
                        Vt[((bh * (LKV_ / 64) + (k >> 6)) * D_ + d) * 64 + (k & 63)] = (_Float16)v;
                    }
                }
            }
        }
    }
}

// ---------------- FC GEMM ----------------
__global__ __launch_bounds__(256) void gemm13_fc(
    const _Float16* __restrict__ A, const _Float16* __restrict__ W,
    const float* __restrict__ bias, float* __restrict__ Cout)
{
    __shared__ _Float16 As[128 * 32];
    __shared__ _Float16 Bs[128 * 32];

    const int tm = blockIdx.x >> 3, tn = blockIdx.x & 7;
    const int tid = threadIdx.x;
    const int w = tid >> 6, lane = tid & 63;
    const int g = lane >> 4, c = lane & 15;
    const int wr = w >> 1, wc = w & 1;

    f32x4 acc[4][4];
#pragma unroll
    for (int i = 0; i < 4; i++)
#pragma unroll
        for (int j = 0; j < 4; j++) acc[i][j] = f32x4{0.f, 0.f, 0.f, 0.f};

    const size_t rowStrideB = (size_t)E_ * 2;
    for (int kt = 0; kt < 32; ++kt) {
#pragma unroll
        for (int c2 = 0; c2 < 2; ++c2) {
            int L = (w * 2 + c2) * 1024 + lane * 16;
            int row = L >> 6, colb = L & 63;
            const char* gA = (const char*)A + (size_t)(tm * 128 + row) * rowStrideB + (size_t)kt * 64 + colb;
            const char* gB = (const char*)W + (size_t)(tn * 128 + row) * rowStrideB + (size_t)kt * 64 + colb;
            gload16_lds(gA, (char*)As + (w * 2 + c2) * 1024);
            gload16_lds(gB, (char*)Bs + (w * 2 + c2) * 1024);
        }
        __syncthreads();

        f16x8 aF[4], bF[4];
#pragma unroll
        for (int mi = 0; mi < 4; mi++)
            aF[mi] = *(const f16x8*)&As[(wr * 64 + mi * 16 + c) * 32 + g * 8];
#pragma unroll
        for (int ni = 0; ni < 4; ni++)
            bF[ni] = *(const f16x8*)&Bs[(wc * 64 + ni * 16 + c) * 32 + g * 8];
#pragma unroll
        for (int mi = 0; mi < 4; mi++)
#pragma unroll
            for (int ni = 0; ni < 4; ni++)
                acc[mi][ni] = __builtin_amdgcn_mfma_f32_16x16x32_f16(aF[mi], bF[ni], acc[mi][ni], 0, 0, 0);
        __syncthreads();
    }

#pragma unroll
    for (int mi = 0; mi < 4; mi++)
#pragma unroll
        for (int ni = 0; ni < 4; ni++)
#pragma unroll
            for (int r = 0; r < 4; r++) {
                int R  = tm * 128 + wr * 64 + mi * 16 + g * 4 + r;
                int Cc = tn * 128 + wc * 64 + ni * 16 + c;
                Cout[(size_t)R * E_ + Cc] = acc[mi][ni][r] + bias[Cc];
            }
}

// ---------------- flash attention: LDS-staged K/V (dbuf), swapped QK^T ----------------
// Grid 512 (8 xcd x 4 bh x 16 q-tiles of 64). Block 256 = 4 waves, each wave 16 q.
// All waves share each staged 64-kv tile (K 8KB + V 8KB per buffer, XOR-swizzled
// on the GLOBAL source so LDS dest stays linear; ds_read applies the same XOR).
__global__ __launch_bounds__(256) void attn13_kernel(
    const _Float16* __restrict__ Qh,   // [B,H,LQ,D] pre-scaled by 0.125*log2e
    const _Float16* __restrict__ Kh,   // [B,H,LKV,D]
    const _Float16* __restrict__ Vt,   // [B*H][LKV/64][D][64] tiled
    const unsigned long long* __restrict__ Mbt,  // [32][B*LQ] transposed bitmask
    _Float16* __restrict__ O)          // [B,LQ,E] f16
{
    __shared__ __align__(16) char ldsraw[32768];  // 2 x (K 8KB | V 8KB); epilogue reuses

    const int bid0 = blockIdx.x;
    const int xcd = bid0 & 7, jj = bid0 >> 3;
    const int bh = xcd * 4 + (jj >> 4);           // K/V L2-local per XCD
    const int qt = jj & 15;
    const int b = bh >> 4, h = bh & 15;
    const int tid = threadIdx.x;
    const int w = tid >> 6, lane = tid & 63;
    const int g = lane >> 4, c = lane & 15;
    const int q0 = qt * 64 + w * 16;

    // Q fragment (B-operand of swapped QK^T)
    f16x8 qf[2];
#pragma unroll
    for (int ks = 0; ks < 2; ++ks)
        qf[ks] = *(const f16x8*)&Qh[((size_t)bh * LQ_ + q0 + c) * D_ + ks * 32 + g * 8];

    f32x4 o[4];
#pragma unroll
    for (int dt = 0; dt < 4; dt++) o[dt] = f32x4{0.f, 0.f, 0.f, 0.f};
    float m = -1e30f, lsum = 0.f;

    // staging geometry: wave w stages rows w*16 + j*8 + (lane>>3), colIdx = lane&7,
    // global col pre-swizzled by (row&7) = (lane>>3)&7.
    const int rowS = (lane >> 3);
    const int stOffBase = (rowS * 128) + (((lane & 7) ^ (rowS & 7)) * 16);   // + w*2048 + j*1024
    const char* kTile0 = (const char*)Kh + (size_t)bh * (LKV_ * D_ * 2);
    const char* vTile0 = (const char*)Vt + (size_t)bh * (LKV_ * D_ * 2);

    // ds_read column swizzle (per ks), row part c*128 added via immediate-friendly form
    int rdOff[2];
#pragma unroll
    for (int ks = 0; ks < 2; ++ks)
        rdOff[ks] = c * 128 + (((ks * 4 + g) ^ (c & 7)) * 16);

    // bpermute lane sources for P-fragment assembly (proven in r11/r12)
    const int srcLo = (((g & 1) << 1) * 16 + c) << 2;
    const int srcHi = ((((g & 1) << 1) + 1) * 16 + c) << 2;
    const bool hiSel = (g >= 2);

    const int mRowIdx = b * LQ_ + q0 + c;

    // prologue: stage tile 0 into buffer 0
    {
        const char* kt = kTile0;
        const char* vt = vTile0;
#pragma unroll
        for (int j = 0; j < 2; ++j) {
            gload16_lds(kt + (w * 2048 + j * 1024) + stOffBase, ldsraw + (w * 2048 + j * 1024));
            gload16_lds(vt + (w * 2048 + j * 1024) + stOffBase, ldsraw + 8192 + (w * 2048 + j * 1024));
        }
    }
    __syncthreads();

    for (int t = 0; t < 32; ++t) {
        // stage next tile into other buffer (overlaps with compute; drained at end barrier)
        if (t < 31) {
            const char* kt = kTile0 + (size_t)(t + 1) * 8192;
            const char* vt = vTile0 + (size_t)(t + 1) * 8192;
            char* dst = ldsraw + ((t + 1) & 1) * 16384;
#pragma unroll
            for (int j = 0; j < 2; ++j) {
                gload16_lds(kt + (w * 2048 + j * 1024) + stOffBase, dst + (w * 2048 + j * 1024));
                gload16_lds(vt + (w * 2048 + j * 1024) + stOffBase, dst + 8192 + (w * 2048 + j * 1024));
            }
        }

        const char* bufp = ldsraw + (t & 1) * 16384;

        // ---- swapped QK^T from LDS: s[nt][r] = S[t*64+nt*16+4g+r][q0+c] ----
        f32x4 s[4];
#pragma unroll
        for (int nt = 0; nt < 4; ++nt) {
            f32x4 accS = f32x4{0.f, 0.f, 0.f, 0.f};
#pragma unroll
            for (int ks = 0; ks < 2; ++ks) {
                f16x8 kf = *(const f16x8*)(bufp + nt * 2048 + rdOff[ks]);
                accS = __builtin_amdgcn_mfma_f32_16x16x32_f16(kf, qf[ks], accS, 0, 0, 0);
            }
            s[nt] = accS;
        }
        // ---- mask: transposed bitfield, lanes read contiguous u64 ----
        unsigned long long mks = Mbt[(size_t)t * 2048 + mRowIdx] >> (g * 4);
#pragma unroll
        for (int nt = 0; nt < 4; ++nt) {
            unsigned nib = (unsigned)(mks >> (nt * 16)) & 0xFu;
            if (nib & 1u) s[nt][0] = -1e9f;
            if (nib & 2u) s[nt][1] = -1e9f;
            if (nib & 4u) s[nt][2] = -1e9f;
            if (nib & 8u) s[nt][3] = -1e9f;
        }
        // ---- online softmax per q (= c) ----
        float t0 = fmaxf(fmaxf(s[0][0], s[0][1]), fmaxf(s[0][2], s[0][3]));
        float t1 = fmaxf(fmaxf(s[1][0], s[1][1]), fmaxf(s[1][2], s[1][3]));
        float t2 = fmaxf(fmaxf(s[2][0], s[2][1]), fmaxf(s[2][2], s[2][3]));
        float t3 = fmaxf(fmaxf(s[3][0], s[3][1]), fmaxf(s[3][2], s[3][3]));
        float tmax = fmaxf(fmaxf(t0, t1), fmaxf(t2, t3));
        tmax = fmaxf(tmax, __shfl_xor(tmax, 16, 64));
        tmax = fmaxf(tmax, __shfl_xor(tmax, 32, 64));
        float mn = fmaxf(m, tmax);
        float scl = exp2f(m - mn);
        m = mn;
        float ts = 0.f;
#pragma unroll
        for (int nt = 0; nt < 4; ++nt) {
            float p0 = exp2f(s[nt][0] - m);
            float p1 = exp2f(s[nt][1] - m);
            float p2 = exp2f(s[nt][2] - m);
            float p3 = exp2f(s[nt][3] - m);
            s[nt][0] = p0; s[nt][1] = p1; s[nt][2] = p2; s[nt][3] = p3;
            ts += (p0 + p1) + (p2 + p3);
        }
        ts += __shfl_xor(ts, 16, 64);
        ts += __shfl_xor(ts, 32, 64);
        lsum = lsum * scl + ts;
#pragma unroll
        for (int dt = 0; dt < 4; dt++)
#pragma unroll
            for (int r = 0; r < 4; r++) o[dt][r] *= scl;
        // ---- pack P to f16 pairs ----
        int pk[4][2];
#pragma unroll
        for (int nt = 0; nt < 4; ++nt) {
            pk[nt][0] = __builtin_bit_cast(int, __builtin_amdgcn_cvt_pkrtz(s[nt][0], s[nt][1]));
            pk[nt][1] = __builtin_bit_cast(int, __builtin_amdgcn_cvt_pkrtz(s[nt][2], s[nt][3]));
        }
        // ---- PV from LDS V: O^T += V^T * P ----
#pragma unroll
        for (int ks = 0; ks < 2; ++ks) {
            const int ntL = 2 * ks, ntH = 2 * ks + 1;
            int aL0 = __builtin_amdgcn_ds_bpermute(srcLo, pk[ntL][0]);
            int aL1 = __builtin_amdgcn_ds_bpermute(srcLo, pk[ntL][1]);
            int aH0 = __builtin_amdgcn_ds_bpermute(srcHi, pk[ntL][0]);
            int aH1 = __builtin_amdgcn_ds_bpermute(srcHi, pk[ntL][1]);
            int bL0 = __builtin_amdgcn_ds_bpermute(srcLo, pk[ntH][0]);
            int bL1 = __builtin_amdgcn_ds_bpermute(srcLo, pk[ntH][1]);
            int bH0 = __builtin_amdgcn_ds_bpermute(srcHi, pk[ntH][0]);
            int bH1 = __builtin_amdgcn_ds_bpermute(srcHi, pk[ntH][1]);
            int u[4];
            u[0] = hiSel ? bL0 : aL0;
            u[1] = hiSel ? bL1 : aL1;
            u[2] = hiSel ? bH0 : aH0;
            u[3] = hiSel ? bH1 : aH1;
            f16x8 pf;
            {
                union { int i[4]; f16x8 v; } cvt;
                cvt.i[0] = u[0]; cvt.i[1] = u[1]; cvt.i[2] = u[2]; cvt.i[3] = u[3];
                pf = cvt.v;
            }
#pragma unroll
            for (int dt = 0; dt < 4; ++dt) {
                f16x8 vf = *(const f16x8*)(bufp + 8192 + dt * 2048 + rdOff[ks]);
                o[dt] = __builtin_amdgcn_mfma_f32_16x16x32_f16(vf, pf, o[dt], 0, 0, 0);
            }
        }
        __syncthreads();   // stage(t+1) drained (vmcnt0) + buffer swap safe
    }

    // ---- epilogue: normalize in-lane, transpose via LDS, coalesced store ----
    float inv = 1.0f / lsum;       // lsum is per-q (= per-lane c) resident
    float* OfP = (float*)ldsraw;   // [64][68] f32 (17.4KB, staging buffers dead)
#pragma unroll
    for (int dt = 0; dt < 4; ++dt)
#pragma unroll
        for (int r = 0; r < 4; r++)
            OfP[(w * 16 + c) * 68 + dt * 16 + 4 * g + r] = o[dt][r] * inv;
    __syncthreads();

    {
        int row = tid >> 2, seg = tid & 3;
        const float* src = &OfP[row * 68 + seg * 16];
        f16x8 lo, hi;
#pragma unroll
        for (int i = 0; i < 8; ++i) { lo[i] = (_Float16)src[i]; hi[i] = (_Float16)src[8 + i]; }
        _Float16* dst = &O[((size_t)b * LQ_ + qt * 64 + row) * E_ + h * 64 + seg * 16];
        *(f16x8*)dst = lo;
        *(f16x8*)(dst + 8) = hi;
    }
}

extern "C" void kernel_launch(void* const* d_in, const int* in_sizes, int n_in,
                              void* d_out, int out_size, void* d_ws, size_t ws_size,
                              hipStream_t stream)
{
    const float* x   = (const float*)d_in[0];
    const float* ctx = (const float*)d_in[1];
    const void*  msk = d_in[2];
    const float* Wq  = (const float*)d_in[3];
    const float* Wk  = (const float*)d_in[4];
    const float* Wv  = (const float*)d_in[5];
    const float* fcw = (const float*)d_in[6];
    const float* fcb = (const float*)d_in[7];
    float* out = (float*)d_out;

    char* ws = (char*)d_ws;
    size_t off = 0;
    auto alloc = [&](size_t bytes) { char* p = ws + off; off += (bytes + 255) & ~255ull; return p; };

    int* modep = (int*)alloc(256);
    unsigned long long* Mbt = (unsigned long long*)alloc((size_t)B_ * LQ_ * (LKV_ / 64) * 8);
    _Float16* xh   = (_Float16*)alloc((size_t)B_ * LQ_ * E_ * 2);
    _Float16* ch   = (_Float16*)alloc((size_t)B_ * LKV_ * E_ * 2);
    _Float16* wqh  = (_Float16*)alloc((size_t)E_ * E_ * 2);
    _Float16* wkvh = (_Float16*)alloc((size_t)2 * E_ * E_ * 2);
    _Float16* fwh  = (_Float16*)alloc((size_t)E_ * E_ * 2);
    float*    fbf  = (float*)alloc((size_t)E_ * 4);
    _Float16* Qh   = (_Float16*)alloc((size_t)B_ * H_ * LQ_ * D_ * 2);
    _Float16* Kh   = (_Float16*)alloc((size_t)B_ * H_ * LKV_ * D_ * 2);
    _Float16* Vt   = (_Float16*)alloc((size_t)B_ * H_ * LKV_ * D_ * 2);
    _Float16* Ob   = xh;  // safe alias: gemm13_qkv (last reader of xh) finishes before attn writes Ob
    (void)ws_size; (void)in_sizes; (void)n_in; (void)out_size;

    probe13<<<1, 64, 0, stream>>>(msk, modep);

    canon13_all<<<2048, 256, 0, stream>>>(x, ctx, Wq, Wk, Wv, fcw, fcb, msk,
                                          xh, ch, wqh, wkvh, fwh, fbf, Mbt, modep);

    gemm13_qkv<<<640, 256, 0, stream>>>(xh, ch, wqh, wkvh, Qh, Kh, Vt);

    attn13_kernel<<<512, 256, 0, stream>>>(Qh, Kh, Vt, Mbt, Ob);

    gemm13_fc<<<128, 256, 0, stream>>>(Ob, fwh, fbf, out);
}

// Round 14
// 151.018 us; speedup vs baseline: 3.3086x; 1.0600x over previous
//
#include <hip/hip_runtime.h>
#include <hip/hip_bf16.h>

#define B_   2
#define H_   16
#define LQ_  1024
#define LKV_ 2048
#define D_   64
#define E_   1024

typedef __attribute__((ext_vector_type(8))) _Float16 f16x8;
typedef __attribute__((ext_vector_type(4))) float   f32x4;

__device__ __forceinline__ void gload16_lds(const void* g, void* l) {
    __builtin_amdgcn_global_load_lds(
        (const __attribute__((address_space(1))) unsigned int*)g,
        (__attribute__((address_space(3))) unsigned int*)l, 16, 0, 0);
}

// ---------------- one-wave mask-dtype probe ----------------
__global__ void probe14(const void* __restrict__ msk, int* __restrict__ modep) {
    int lane = threadIdx.x;
    int notInt = 0, notF32 = 0, notBF = 0;
    for (int i = lane; i < 256; i += 64) {
        unsigned v = ((const unsigned*)msk)[i * 997];
        if (v > 1u) notInt = 1;
        if (v != 0u && v != 0x3F800000u) notF32 = 1;
        if (v != 0u && v != 0x3F80u && v != 0x3F800000u && v != 0x3F803F80u) notBF = 1;
    }
    notInt = __any(notInt); notF32 = __any(notF32); notBF = __any(notBF);
    if (lane == 0) *modep = !notInt ? 0 : (!notF32 ? 1 : (!notBF ? 2 : 3));
}

// ---------------- streaming canonicalization (mask -> TRANSPOSED bits [t][row]) --------
__global__ void canon14_all(
    const float* __restrict__ x,  const float* __restrict__ ctx,
    const float* __restrict__ wq, const float* __restrict__ wk,
    const float* __restrict__ wv, const float* __restrict__ fw,
    const float* __restrict__ fb, const void* __restrict__ msk,
    _Float16* __restrict__ xh,  _Float16* __restrict__ ch,
    _Float16* __restrict__ wqh, _Float16* __restrict__ wkvh,
    _Float16* __restrict__ fwh, float* __restrict__ fbf,
    unsigned long long* __restrict__ Mbt, const int* __restrict__ modep)
{
    const int mmode = *modep;
    const int total = 1376384;
    const int stride = gridDim.x * blockDim.x;
    for (int idx = blockIdx.x * blockDim.x + threadIdx.x; idx < total; idx += stride) {
        if (idx < 1310720) {
            const float* src; _Float16* dst; int rel;
            if (idx < 262144)       { src = x;   dst = xh;   rel = idx; }
            else if (idx < 786432)  { src = ctx; dst = ch;   rel = idx - 262144; }
            else if (idx < 917504)  { src = wq;  dst = wqh;  rel = idx - 786432; }
            else if (idx < 1048576) { src = wk;  dst = wkvh; rel = idx - 917504; }
            else if (idx < 1179648) { src = wv;  dst = wkvh + (size_t)E_ * E_; rel = idx - 1048576; }
            else                    { src = fw;  dst = fwh;  rel = idx - 1179648; }
            f32x4 a = ((const f32x4*)src)[2 * rel], b = ((const f32x4*)src)[2 * rel + 1];
            f16x8 o;
            o[0] = (_Float16)a.x; o[1] = (_Float16)a.y; o[2] = (_Float16)a.z; o[3] = (_Float16)a.w;
            o[4] = (_Float16)b.x; o[5] = (_Float16)b.y; o[6] = (_Float16)b.z; o[7] = (_Float16)b.w;
            ((f16x8*)dst)[rel] = o;
        } else if (idx < 1310848) {
            int rel = idx - 1310720;
#pragma unroll
            for (int j = 0; j < 8; ++j) fbf[rel * 8 + j] = fb[rel * 8 + j];
        } else {
            int rel = idx - 1310848;           // rel = row*32 + t
            const size_t base = (size_t)rel * 64;
            unsigned long long v = 0;
            if (mmode == 0) {
                const int* p = (const int*)msk + base;
#pragma unroll
                for (int j = 0; j < 64; ++j) if (p[j] != 0) v |= 1ull << j;
            } else if (mmode == 1) {
                const float* p = (const float*)msk + base;
#pragma unroll
                for (int j = 0; j < 64; ++j) if (p[j] != 0.0f) v |= 1ull << j;
            } else if (mmode == 2) {
                const unsigned short* p = (const unsigned short*)msk + base;
#pragma unroll
                for (int j = 0; j < 64; ++j) if (p[j] != 0) v |= 1ull << j;
            } else {
                const unsigned char* p = (const unsigned char*)msk + base;
#pragma unroll
                for (int j = 0; j < 64; ++j) if (p[j] != 0) v |= 1ull << j;
            }
            Mbt[(rel & 31) * 2048 + (rel >> 5)] = v;   // transposed: [t][b*LQ+q]
        }
    }
}

// ---------------- fused Q + K|V projection GEMM: BK=64, swizzled LDS ----------------
// blocks 0..127: Q proj (tm=bid>>3, tn=bid&7); 128..639: K|V (tm=b2>>4, tn=b2&15).
__global__ __launch_bounds__(256) void gemm14_qkv(
    const _Float16* __restrict__ xh, const _Float16* __restrict__ ch,
    const _Float16* __restrict__ wqh, const _Float16* __restrict__ wkvh,
    _Float16* __restrict__ Qh, _Float16* __restrict__ Kh, _Float16* __restrict__ Vt)
{
    __shared__ __align__(16) _Float16 As[128 * 64];   // 16KB, rows of 128B
    __shared__ __align__(16) _Float16 Bs[128 * 64];

    const int bid = blockIdx.x;
    const bool isQ = bid < 128;
    const _Float16* A; const _Float16* W; int tm, tn;
    if (isQ) { A = xh; W = wqh; tm = bid >> 3; tn = bid & 7; }
    else     { int b2 = bid - 128; A = ch; W = wkvh; tm = b2 >> 4; tn = b2 & 15; }

    const int tid = threadIdx.x;
    const int w = tid >> 6, lane = tid & 63;
    const int g = lane >> 4, c = lane & 15;
    const int wr = w >> 1, wc = w & 1;
    const int rowS = lane >> 3, slot = lane & 7;
    const int stSwz = ((slot ^ (rowS & 7)) << 4);       // pre-swizzled GLOBAL col slot
    const int swz0 = ((g ^ (c & 7)) << 4);              // ds_read slot swizzle, ks2=0
    const int swz1 = (((4 + g) ^ (c & 7)) << 4);        // ks2=1

    f32x4 acc[4][4];
#pragma unroll
    for (int i = 0; i < 4; i++)
#pragma unroll
        for (int j = 0; j < 4; j++) acc[i][j] = f32x4{0.f, 0.f, 0.f, 0.f};

    const size_t rowB = (size_t)E_ * 2;
    const char* gAbase = (const char*)A + (size_t)(tm * 128) * rowB;
    const char* gBbase = (const char*)W + (size_t)(tn * 128) * rowB;

    for (int kt = 0; kt < 16; ++kt) {
#pragma unroll
        for (int j = 0; j < 4; ++j) {
            int rloc = w * 32 + j * 8 + rowS;
            gload16_lds(gAbase + (size_t)rloc * rowB + kt * 128 + stSwz,
                        (char*)As + (w * 32 + j * 8) * 128 + lane * 16);
            gload16_lds(gBbase + (size_t)rloc * rowB + kt * 128 + stSwz,
                        (char*)Bs + (w * 32 + j * 8) * 128 + lane * 16);
        }
        __syncthreads();

        f16x8 bF[4][2];
#pragma unroll
        for (int ni = 0; ni < 4; ni++) {
            const char* bp = (const char*)Bs + (wc * 64 + ni * 16 + c) * 128;
            bF[ni][0] = *(const f16x8*)(bp + swz0);
            bF[ni][1] = *(const f16x8*)(bp + swz1);
        }
#pragma unroll
        for (int mi = 0; mi < 4; mi++) {
            const char* ap = (const char*)As + (wr * 64 + mi * 16 + c) * 128;
            f16x8 a0 = *(const f16x8*)(ap + swz0);
            f16x8 a1 = *(const f16x8*)(ap + swz1);
#pragma unroll
            for (int ni = 0; ni < 4; ni++) {
                acc[mi][ni] = __builtin_amdgcn_mfma_f32_16x16x32_f16(a0, bF[ni][0], acc[mi][ni], 0, 0, 0);
                acc[mi][ni] = __builtin_amdgcn_mfma_f32_16x16x32_f16(a1, bF[ni][1], acc[mi][ni], 0, 0, 0);
            }
        }
        __syncthreads();
    }

#pragma unroll
    for (int mi = 0; mi < 4; mi++) {
#pragma unroll
        for (int ni = 0; ni < 4; ni++) {
#pragma unroll
            for (int r = 0; r < 4; r++) {
                int R  = tm * 128 + wr * 64 + mi * 16 + g * 4 + r;
                int Cc = tn * 128 + wc * 64 + ni * 16 + c;
                float v = acc[mi][ni][r];
                if (isQ) {
                    int b = R >> 10, q = R & 1023;
                    int h = Cc >> 6, d = Cc & 63;
                    // 0.125 * log2(e): attention works in exp2 domain
                    Qh[((size_t)(b * H_ + h) * LQ_ + q) * D_ + d] = (_Float16)(v * 0.18033688011112042f);
                } else {
                    int b = R >> 11, k = R & 2047;
                    int isV = Cc >> 10, cc2 = Cc & 1023;
                    int h = cc2 >> 6, d = cc2 & 63;
                    if (!isV)
                        Kh[((size_t)(b * H_ + h) * LKV_ + k) * D_ + d] = (_Float16)v;
                    else {
                        size_t bh = (size_t)(b * H_ + h);
                        Vt[((bh * (LKV_ / 64) + (k >> 6)) * D_ + d) * 64 + (k & 63)] = (_Float16)v;
                    }
                }
            }
        }
    }
}

// ---------------- FC GEMM: BK=64, swizzled LDS ----------------
__global__ __launch_bounds__(256) void gemm14_fc(
    const _Float16* __restrict__ A, const _Float16* __restrict__ W,
    const float* __restrict__ bias, float* __restrict__ Cout)
{
    __shared__ __align__(16) _Float16 As[128 * 64];
    __shared__ __align__(16) _Float16 Bs[128 * 64];

    const int tm = blockIdx.x >> 3, tn = blockIdx.x & 7;
    const int tid = threadIdx.x;
    const int w = tid >> 6, lane = tid & 63;
    const int g = lane >> 4, c = lane & 15;
    const int wr = w >> 1, wc = w & 1;
    const int rowS = lane >> 3, slot = lane & 7;
    const int stSwz = ((slot ^ (rowS & 7)) << 4);
    const int swz0 = ((g ^ (c & 7)) << 4);
    const int swz1 = (((4 + g) ^ (c & 7)) << 4);

    f32x4 acc[4][4];
#pragma unroll
    for (int i = 0; i < 4; i++)
#pragma unroll
        for (int j = 0; j < 4; j++) acc[i][j] = f32x4{0.f, 0.f, 0.f, 0.f};

    const size_t rowB = (size_t)E_ * 2;
    const char* gAbase = (const char*)A + (size_t)(tm * 128) * rowB;
    const char* gBbase = (const char*)W + (size_t)(tn * 128) * rowB;

    for (int kt = 0; kt < 16; ++kt) {
#pragma unroll
        for (int j = 0; j < 4; ++j) {
            int rloc = w * 32 + j * 8 + rowS;
            gload16_lds(gAbase + (size_t)rloc * rowB + kt * 128 + stSwz,
                        (char*)As + (w * 32 + j * 8) * 128 + lane * 16);
            gload16_lds(gBbase + (size_t)rloc * rowB + kt * 128 + stSwz,
                        (char*)Bs + (w * 32 + j * 8) * 128 + lane * 16);
        }
        __syncthreads();

        f16x8 bF[4][2];
#pragma unroll
        for (int ni = 0; ni < 4; ni++) {
            const char* bp = (const char*)Bs + (wc * 64 + ni * 16 + c) * 128;
            bF[ni][0] = *(const f16x8*)(bp + swz0);
            bF[ni][1] = *(const f16x8*)(bp + swz1);
        }
#pragma unroll
        for (int mi = 0; mi < 4; mi++) {
            const char* ap = (const char*)As + (wr * 64 + mi * 16 + c) * 128;
            f16x8 a0 = *(const f16x8*)(ap + swz0);
            f16x8 a1 = *(const f16x8*)(ap + swz1);
#pragma unroll
            for (int ni = 0; ni < 4; ni++) {
                acc[mi][ni] = __builtin_amdgcn_mfma_f32_16x16x32_f16(a0, bF[ni][0], acc[mi][ni], 0, 0, 0);
                acc[mi][ni] = __builtin_amdgcn_mfma_f32_16x16x32_f16(a1, bF[ni][1], acc[mi][ni], 0, 0, 0);
            }
        }
        __syncthreads();
    }

#pragma unroll
    for (int mi = 0; mi < 4; mi++)
#pragma unroll
        for (int ni = 0; ni < 4; ni++)
#pragma unroll
            for (int r = 0; r < 4; r++) {
                int R  = tm * 128 + wr * 64 + mi * 16 + g * 4 + r;
                int Cc = tn * 128 + wc * 64 + ni * 16 + c;
                Cout[(size_t)R * E_ + Cc] = acc[mi][ni][r] + bias[Cc];
            }
}

// ---------------- flash attention: LDS-staged K/V (dbuf), swapped QK^T ----------------
// (unchanged from round 13 — it just improved 2.2x; isolating GEMM changes this round)
__global__ __launch_bounds__(256) void attn14_kernel(
    const _Float16* __restrict__ Qh,   // [B,H,LQ,D] pre-scaled by 0.125*log2e
    const _Float16* __restrict__ Kh,   // [B,H,LKV,D]
    const _Float16* __restrict__ Vt,   // [B*H][LKV/64][D][64] tiled
    const unsigned long long* __restrict__ Mbt,  // [32][B*LQ] transposed bitmask
    _Float16* __restrict__ O)          // [B,LQ,E] f16
{
    __shared__ __align__(16) char ldsraw[32768];

    const int bid0 = blockIdx.x;
    const int xcd = bid0 & 7, jj = bid0 >> 3;
    const int bh = xcd * 4 + (jj >> 4);
    const int qt = jj & 15;
    const int b = bh >> 4, h = bh & 15;
    const int tid = threadIdx.x;
    const int w = tid >> 6, lane = tid & 63;
    const int g = lane >> 4, c = lane & 15;
    const int q0 = qt * 64 + w * 16;

    f16x8 qf[2];
#pragma unroll
    for (int ks = 0; ks < 2; ++ks)
        qf[ks] = *(const f16x8*)&Qh[((size_t)bh * LQ_ + q0 + c) * D_ + ks * 32 + g * 8];

    f32x4 o[4];
#pragma unroll
    for (int dt = 0; dt < 4; dt++) o[dt] = f32x4{0.f, 0.f, 0.f, 0.f};
    float m = -1e30f, lsum = 0.f;

    const int rowS = (lane >> 3);
    const int stOffBase = (rowS * 128) + (((lane & 7) ^ (rowS & 7)) * 16);
    const char* kTile0 = (const char*)Kh + (size_t)bh * (LKV_ * D_ * 2);
    const char* vTile0 = (const char*)Vt + (size_t)bh * (LKV_ * D_ * 2);

    int rdOff[2];
#pragma unroll
    for (int ks = 0; ks < 2; ++ks)
        rdOff[ks] = c * 128 + (((ks * 4 + g) ^ (c & 7)) * 16);

    const int srcLo = (((g & 1) << 1) * 16 + c) << 2;
    const int srcHi = ((((g & 1) << 1) + 1) * 16 + c) << 2;
    const bool hiSel = (g >= 2);

    const int mRowIdx = b * LQ_ + q0 + c;

    {
#pragma unroll
        for (int j = 0; j < 2; ++j) {
            gload16_lds(kTile0 + (w * 2048 + j * 1024) + stOffBase, ldsraw + (w * 2048 + j * 1024));
            gload16_lds(vTile0 + (w * 2048 + j * 1024) + stOffBase, ldsraw + 8192 + (w * 2048 + j * 1024));
        }
    }
    __syncthreads();

    for (int t = 0; t < 32; ++t) {
        if (t < 31) {
            const char* kt = kTile0 + (size_t)(t + 1) * 8192;
            const char* vt = vTile0 + (size_t)(t + 1) * 8192;
            char* dst = ldsraw + ((t + 1) & 1) * 16384;
#pragma unroll
            for (int j = 0; j < 2; ++j) {
                gload16_lds(kt + (w * 2048 + j * 1024) + stOffBase, dst + (w * 2048 + j * 1024));
                gload16_lds(vt + (w * 2048 + j * 1024) + stOffBase, dst + 8192 + (w * 2048 + j * 1024));
            }
        }

        const char* bufp = ldsraw + (t & 1) * 16384;

        f32x4 s[4];
#pragma unroll
        for (int nt = 0; nt < 4; ++nt) {
            f32x4 accS = f32x4{0.f, 0.f, 0.f, 0.f};
#pragma unroll
            for (int ks = 0; ks < 2; ++ks) {
                f16x8 kf = *(const f16x8*)(bufp + nt * 2048 + rdOff[ks]);
                accS = __builtin_amdgcn_mfma_f32_16x16x32_f16(kf, qf[ks], accS, 0, 0, 0);
            }
            s[nt] = accS;
        }
        unsigned long long mks = Mbt[(size_t)t * 2048 + mRowIdx] >> (g * 4);
#pragma unroll
        for (int nt = 0; nt < 4; ++nt) {
            unsigned nib = (unsigned)(mks >> (nt * 16)) & 0xFu;
            if (nib & 1u) s[nt][0] = -1e9f;
            if (nib & 2u) s[nt][1] = -1e9f;
            if (nib & 4u) s[nt][2] = -1e9f;
            if (nib & 8u) s[nt][3] = -1e9f;
        }
        float t0 = fmaxf(fmaxf(s[0][0], s[0][1]), fmaxf(s[0][2], s[0][3]));
        float t1 = fmaxf(fmaxf(s[1][0], s[1][1]), fmaxf(s[1][2], s[1][3]));
        float t2 = fmaxf(fmaxf(s[2][0], s[2][1]), fmaxf(s[2][2], s[2][3]));
        float t3 = fmaxf(fmaxf(s[3][0], s[3][1]), fmaxf(s[3][2], s[3][3]));
        float tmax = fmaxf(fmaxf(t0, t1), fmaxf(t2, t3));
        tmax = fmaxf(tmax, __shfl_xor(tmax, 16, 64));
        tmax = fmaxf(tmax, __shfl_xor(tmax, 32, 64));
        float mn = fmaxf(m, tmax);
        float scl = exp2f(m - mn);
        m = mn;
        float ts = 0.f;
#pragma unroll
        for (int nt = 0; nt < 4; ++nt) {
            float p0 = exp2f(s[nt][0] - m);
            float p1 = exp2f(s[nt][1] - m);
            float p2 = exp2f(s[nt][2] - m);
            float p3 = exp2f(s[nt][3] - m);
            s[nt][0] = p0; s[nt][1] = p1; s[nt][2] = p2; s[nt][3] = p3;
            ts += (p0 + p1) + (p2 + p3);
        }
        ts += __shfl_xor(ts, 16, 64);
        ts += __shfl_xor(ts, 32, 64);
        lsum = lsum * scl + ts;
#pragma unroll
        for (int dt = 0; dt < 4; dt++)
#pragma unroll
            for (int r = 0; r < 4; r++) o[dt][r] *= scl;
        int pk[4][2];
#pragma unroll
        for (int nt = 0; nt < 4; ++nt) {
            pk[nt][0] = __builtin_bit_cast(int, __builtin_amdgcn_cvt_pkrtz(s[nt][0], s[nt][1]));
            pk[nt][1] = __builtin_bit_cast(int, __builtin_amdgcn_cvt_pkrtz(s[nt][2], s[nt][3]));
        }
#pragma unroll
        for (int ks = 0; ks < 2; ++ks) {
            const int ntL = 2 * ks, ntH = 2 * ks + 1;
            int aL0 = __builtin_amdgcn_ds_bpermute(srcLo, pk[ntL][0]);
            int aL1 = __builtin_amdgcn_ds_bpermute(srcLo, pk[ntL][1]);
            int aH0 = __builtin_amdgcn_ds_bpermute(srcHi, pk[ntL][0]);
            int aH1 = __builtin_amdgcn_ds_bpermute(srcHi, pk[ntL][1]);
            int bL0 = __builtin_amdgcn_ds_bpermute(srcLo, pk[ntH][0]);
            int bL1 = __builtin_amdgcn_ds_bpermute(srcLo, pk[ntH][1]);
            int bH0 = __builtin_amdgcn_ds_bpermute(srcHi, pk[ntH][0]);
            int bH1 = __builtin_amdgcn_ds_bpermute(srcHi, pk[ntH][1]);
            int u[4];
            u[0] = hiSel ? bL0 : aL0;
            u[1] = hiSel ? bL1 : aL1;
            u[2] = hiSel ? bH0 : aH0;
            u[3] = hiSel ? bH1 : aH1;
            f16x8 pf;
            {
                union { int i[4]; f16x8 v; } cvt;
                cvt.i[0] = u[0]; cvt.i[1] = u[1]; cvt.i[2] = u[2]; cvt.i[3] = u[3];
                pf = cvt.v;
            }
#pragma unroll
            for (int dt = 0; dt < 4; ++dt) {
                f16x8 vf = *(const f16x8*)(bufp + 8192 + dt * 2048 + rdOff[ks]);
                o[dt] = __builtin_amdgcn_mfma_f32_16x16x32_f16(vf, pf, o[dt], 0, 0, 0);
            }
        }
        __syncthreads();
    }

    float inv = 1.0f / lsum;
    float* OfP = (float*)ldsraw;
#pragma unroll
    for (int dt = 0; dt < 4; ++dt)
#pragma unroll
        for (int r = 0; r < 4; r++)
            OfP[(w * 16 + c) * 68 + dt * 16 + 4 * g + r] = o[dt][r] * inv;
    __syncthreads();

    {
        int row = tid >> 2, seg = tid & 3;
        const float* src = &OfP[row * 68 + seg * 16];
        f16x8 lo, hi;
#pragma unroll
        for (int i = 0; i < 8; ++i) { lo[i] = (_Float16)src[i]; hi[i] = (_Float16)src[8 + i]; }
        _Float16* dst = &O[((size_t)b * LQ_ + qt * 64 + row) * E_ + h * 64 + seg * 16];
        *(f16x8*)dst = lo;
        *(f16x8*)(dst + 8) = hi;
    }
}

extern "C" void kernel_launch(void* const* d_in, const int* in_sizes, int n_in,
                              void* d_out, int out_size, void* d_ws, size_t ws_size,
                              hipStream_t stream)
{
    const float* x   = (const float*)d_in[0];
    const float* ctx = (const float*)d_in[1];
    const void*  msk = d_in[2];
    const float* Wq  = (const float*)d_in[3];
    const float* Wk  = (const float*)d_in[4];
    const float* Wv  = (const float*)d_in[5];
    const float* fcw = (const float*)d_in[6];
    const float* fcb = (const float*)d_in[7];
    float* out = (float*)d_out;

    char* ws = (char*)d_ws;
    size_t off = 0;
    auto alloc = [&](size_t bytes) { char* p = ws + off; off += (bytes + 255) & ~255ull; return p; };

    int* modep = (int*)alloc(256);
    unsigned long long* Mbt = (unsigned long long*)alloc((size_t)B_ * LQ_ * (LKV_ / 64) * 8);
    _Float16* xh   = (_Float16*)alloc((size_t)B_ * LQ_ * E_ * 2);
    _Float16* ch   = (_Float16*)alloc((size_t)B_ * LKV_ * E_ * 2);
    _Float16* wqh  = (_Float16*)alloc((size_t)E_ * E_ * 2);
    _Float16* wkvh = (_Float16*)alloc((size_t)2 * E_ * E_ * 2);
    _Float16* fwh  = (_Float16*)alloc((size_t)E_ * E_ * 2);
    float*    fbf  = (float*)alloc((size_t)E_ * 4);
    _Float16* Qh   = (_Float16*)alloc((size_t)B_ * H_ * LQ_ * D_ * 2);
    _Float16* Kh   = (_Float16*)alloc((size_t)B_ * H_ * LKV_ * D_ * 2);
    _Float16* Vt   = (_Float16*)alloc((size_t)B_ * H_ * LKV_ * D_ * 2);
    _Float16* Ob   = xh;  // safe alias: gemm14_qkv (last reader of xh) finishes before attn writes Ob
    (void)ws_size; (void)in_sizes; (void)n_in; (void)out_size;

    probe14<<<1, 64, 0, stream>>>(msk, modep);

    canon14_all<<<2048, 256, 0, stream>>>(x, ctx, Wq, Wk, Wv, fcw, fcb, msk,
                                          xh, ch, wqh, wkvh, fwh, fbf, Mbt, modep);

    gemm14_qkv<<<640, 256, 0, stream>>>(xh, ch, wqh, wkvh, Qh, Kh, Vt);

    attn14_kernel<<<512, 256, 0, stream>>>(Qh, Kh, Vt, Mbt, Ob);

    gemm14_fc<<<128, 256, 0, stream>>>(Ob, fwh, fbf, out);
}

// Round 15
// 143.405 us; speedup vs baseline: 3.4843x; 1.0531x over previous
//
#include <hip/hip_runtime.h>
#include <hip/hip_bf16.h>

#define B_   2
#define H_   16
#define LQ_  1024
#define LKV_ 2048
#define D_   64
#define E_   1024

typedef __attribute__((ext_vector_type(8))) _Float16 f16x8;
typedef __attribute__((ext_vector_type(4))) float   f32x4;

__device__ __forceinline__ void gload16_lds(const void* g, void* l) {
    __builtin_amdgcn_global_load_lds(
        (const __attribute__((address_space(1))) unsigned int*)g,
        (__attribute__((address_space(3))) unsigned int*)l, 16, 0, 0);
}

// ---------------- one-wave mask-dtype probe ----------------
__global__ void probe15(const void* __restrict__ msk, int* __restrict__ modep) {
    int lane = threadIdx.x;
    int notInt = 0, notF32 = 0, notBF = 0;
    for (int i = lane; i < 256; i += 64) {
        unsigned v = ((const unsigned*)msk)[i * 997];
        if (v > 1u) notInt = 1;
        if (v != 0u && v != 0x3F800000u) notF32 = 1;
        if (v != 0u && v != 0x3F80u && v != 0x3F800000u && v != 0x3F803F80u) notBF = 1;
    }
    notInt = __any(notInt); notF32 = __any(notF32); notBF = __any(notBF);
    if (lane == 0) *modep = !notInt ? 0 : (!notF32 ? 1 : (!notBF ? 2 : 3));
}

// ---------------- streaming canonicalization (mask -> TRANSPOSED bits [t][row]) --------
__global__ void canon15_all(
    const float* __restrict__ x,  const float* __restrict__ ctx,
    const float* __restrict__ wq, const float* __restrict__ wk,
    const float* __restrict__ wv, const float* __restrict__ fw,
    const float* __restrict__ fb, const void* __restrict__ msk,
    _Float16* __restrict__ xh,  _Float16* __restrict__ ch,
    _Float16* __restrict__ wqh, _Float16* __restrict__ wkvh,
    _Float16* __restrict__ fwh, float* __restrict__ fbf,
    unsigned long long* __restrict__ Mbt, const int* __restrict__ modep)
{
    const int mmode = *modep;
    const int total = 1376384;
    const int stride = gridDim.x * blockDim.x;
    for (int idx = blockIdx.x * blockDim.x + threadIdx.x; idx < total; idx += stride) {
        if (idx < 1310720) {
            const float* src; _Float16* dst; int rel;
            if (idx < 262144)       { src = x;   dst = xh;   rel = idx; }
            else if (idx < 786432)  { src = ctx; dst = ch;   rel = idx - 262144; }
            else if (idx < 917504)  { src = wq;  dst = wqh;  rel = idx - 786432; }
            else if (idx < 1048576) { src = wk;  dst = wkvh; rel = idx - 917504; }
            else if (idx < 1179648) { src = wv;  dst = wkvh + (size_t)E_ * E_; rel = idx - 1048576; }
            else                    { src = fw;  dst = fwh;  rel = idx - 1179648; }
            f32x4 a = ((const f32x4*)src)[2 * rel], b = ((const f32x4*)src)[2 * rel + 1];
            f16x8 o;
            o[0] = (_Float16)a.x; o[1] = (_Float16)a.y; o[2] = (_Float16)a.z; o[3] = (_Float16)a.w;
            o[4] = (_Float16)b.x; o[5] = (_Float16)b.y; o[6] = (_Float16)b.z; o[7] = (_Float16)b.w;
            ((f16x8*)dst)[rel] = o;
        } else if (idx < 1310848) {
            int rel = idx - 1310720;
#pragma unroll
            for (int j = 0; j < 8; ++j) fbf[rel * 8 + j] = fb[rel * 8 + j];
        } else {
            int rel = idx - 1310848;           // rel = row*32 + t
            const size_t base = (size_t)rel * 64;
            unsigned long long v = 0;
            if (mmode == 0) {
                const int* p = (const int*)msk + base;
#pragma unroll
                for (int j = 0; j < 64; ++j) if (p[j] != 0) v |= 1ull << j;
            } else if (mmode == 1) {
                const float* p = (const float*)msk + base;
#pragma unroll
                for (int j = 0; j < 64; ++j) if (p[j] != 0.0f) v |= 1ull << j;
            } else if (mmode == 2) {
                const unsigned short* p = (const unsigned short*)msk + base;
#pragma unroll
                for (int j = 0; j < 64; ++j) if (p[j] != 0) v |= 1ull << j;
            } else {
                const unsigned char* p = (const unsigned char*)msk + base;
#pragma unroll
                for (int j = 0; j < 64; ++j) if (p[j] != 0) v |= 1ull << j;
            }
            Mbt[(rel & 31) * 2048 + (rel >> 5)] = v;   // transposed: [t][b*LQ+q]
        }
    }
}

// ---------------- fused Q + K|V projection GEMM: BK=64, swizzled LDS ----------------
__global__ __launch_bounds__(256) void gemm15_qkv(
    const _Float16* __restrict__ xh, const _Float16* __restrict__ ch,
    const _Float16* __restrict__ wqh, const _Float16* __restrict__ wkvh,
    _Float16* __restrict__ Qh, _Float16* __restrict__ Kh, _Float16* __restrict__ Vt)
{
    __shared__ __align__(16) _Float16 As[128 * 64];
    __shared__ __align__(16) _Float16 Bs[128 * 64];

    const int bid = blockIdx.x;
    const bool isQ = bid < 128;
    const _Float16* A; const _Float16* W; int tm, tn;
    if (isQ) { A = xh; W = wqh; tm = bid >> 3; tn = bid & 7; }
    else     { int b2 = bid - 128; A = ch; W = wkvh; tm = b2 >> 4; tn = b2 & 15; }

    const int tid = threadIdx.x;
    const int w = tid >> 6, lane = tid & 63;
    const int g = lane >> 4, c = lane & 15;
    const int wr = w >> 1, wc = w & 1;
    const int rowS = lane >> 3, slot = lane & 7;
    const int stSwz = ((slot ^ (rowS & 7)) << 4);
    const int swz0 = ((g ^ (c & 7)) << 4);
    const int swz1 = (((4 + g) ^ (c & 7)) << 4);

    f32x4 acc[4][4];
#pragma unroll
    for (int i = 0; i < 4; i++)
#pragma unroll
        for (int j = 0; j < 4; j++) acc[i][j] = f32x4{0.f, 0.f, 0.f, 0.f};

    const size_t rowB = (size_t)E_ * 2;
    const char* gAbase = (const char*)A + (size_t)(tm * 128) * rowB;
    const char* gBbase = (const char*)W + (size_t)(tn * 128) * rowB;

    for (int kt = 0; kt < 16; ++kt) {
#pragma unroll
        for (int j = 0; j < 4; ++j) {
            int rloc = w * 32 + j * 8 + rowS;
            gload16_lds(gAbase + (size_t)rloc * rowB + kt * 128 + stSwz,
                        (char*)As + (w * 32 + j * 8) * 128 + lane * 16);
            gload16_lds(gBbase + (size_t)rloc * rowB + kt * 128 + stSwz,
                        (char*)Bs + (w * 32 + j * 8) * 128 + lane * 16);
        }
        __syncthreads();

        f16x8 bF[4][2];
#pragma unroll
        for (int ni = 0; ni < 4; ni++) {
            const char* bp = (const char*)Bs + (wc * 64 + ni * 16 + c) * 128;
            bF[ni][0] = *(const f16x8*)(bp + swz0);
            bF[ni][1] = *(const f16x8*)(bp + swz1);
        }
#pragma unroll
        for (int mi = 0; mi < 4; mi++) {
            const char* ap = (const char*)As + (wr * 64 + mi * 16 + c) * 128;
            f16x8 a0 = *(const f16x8*)(ap + swz0);
            f16x8 a1 = *(const f16x8*)(ap + swz1);
#pragma unroll
            for (int ni = 0; ni < 4; ni++) {
                acc[mi][ni] = __builtin_amdgcn_mfma_f32_16x16x32_f16(a0, bF[ni][0], acc[mi][ni], 0, 0, 0);
                acc[mi][ni] = __builtin_amdgcn_mfma_f32_16x16x32_f16(a1, bF[ni][1], acc[mi][ni], 0, 0, 0);
            }
        }
        __syncthreads();
    }

#pragma unroll
    for (int mi = 0; mi < 4; mi++) {
#pragma unroll
        for (int ni = 0; ni < 4; ni++) {
#pragma unroll
            for (int r = 0; r < 4; r++) {
                int R  = tm * 128 + wr * 64 + mi * 16 + g * 4 + r;
                int Cc = tn * 128 + wc * 64 + ni * 16 + c;
                float v = acc[mi][ni][r];
                if (isQ) {
                    int b = R >> 10, q = R & 1023;
                    int h = Cc >> 6, d = Cc & 63;
                    // 0.125 * log2(e): attention works in exp2 domain
                    Qh[((size_t)(b * H_ + h) * LQ_ + q) * D_ + d] = (_Float16)(v * 0.18033688011112042f);
                } else {
                    int b = R >> 11, k = R & 2047;
                    int isV = Cc >> 10, cc2 = Cc & 1023;
                    int h = cc2 >> 6, d = cc2 & 63;
                    if (!isV)
                        Kh[((size_t)(b * H_ + h) * LKV_ + k) * D_ + d] = (_Float16)v;
                    else {
                        size_t bh = (size_t)(b * H_ + h);
                        Vt[((bh * (LKV_ / 64) + (k >> 6)) * D_ + d) * 64 + (k & 63)] = (_Float16)v;
                    }
                }
            }
        }
    }
}

// ---------------- FC GEMM: BK=64, swizzled LDS ----------------
__global__ __launch_bounds__(256) void gemm15_fc(
    const _Float16* __restrict__ A, const _Float16* __restrict__ W,
    const float* __restrict__ bias, float* __restrict__ Cout)
{
    __shared__ __align__(16) _Float16 As[128 * 64];
    __shared__ __align__(16) _Float16 Bs[128 * 64];

    const int tm = blockIdx.x >> 3, tn = blockIdx.x & 7;
    const int tid = threadIdx.x;
    const int w = tid >> 6, lane = tid & 63;
    const int g = lane >> 4, c = lane & 15;
    const int wr = w >> 1, wc = w & 1;
    const int rowS = lane >> 3, slot = lane & 7;
    const int stSwz = ((slot ^ (rowS & 7)) << 4);
    const int swz0 = ((g ^ (c & 7)) << 4);
    const int swz1 = (((4 + g) ^ (c & 7)) << 4);

    f32x4 acc[4][4];
#pragma unroll
    for (int i = 0; i < 4; i++)
#pragma unroll
        for (int j = 0; j < 4; j++) acc[i][j] = f32x4{0.f, 0.f, 0.f, 0.f};

    const size_t rowB = (size_t)E_ * 2;
    const char* gAbase = (const char*)A + (size_t)(tm * 128) * rowB;
    const char* gBbase = (const char*)W + (size_t)(tn * 128) * rowB;

    for (int kt = 0; kt < 16; ++kt) {
#pragma unroll
        for (int j = 0; j < 4; ++j) {
            int rloc = w * 32 + j * 8 + rowS;
            gload16_lds(gAbase + (size_t)rloc * rowB + kt * 128 + stSwz,
                        (char*)As + (w * 32 + j * 8) * 128 + lane * 16);
            gload16_lds(gBbase + (size_t)rloc * rowB + kt * 128 + stSwz,
                        (char*)Bs + (w * 32 + j * 8) * 128 + lane * 16);
        }
        __syncthreads();

        f16x8 bF[4][2];
#pragma unroll
        for (int ni = 0; ni < 4; ni++) {
            const char* bp = (const char*)Bs + (wc * 64 + ni * 16 + c) * 128;
            bF[ni][0] = *(const f16x8*)(bp + swz0);
            bF[ni][1] = *(const f16x8*)(bp + swz1);
        }
#pragma unroll
        for (int mi = 0; mi < 4; mi++) {
            const char* ap = (const char*)As + (wr * 64 + mi * 16 + c) * 128;
            f16x8 a0 = *(const f16x8*)(ap + swz0);
            f16x8 a1 = *(const f16x8*)(ap + swz1);
#pragma unroll
            for (int ni = 0; ni < 4; ni++) {
                acc[mi][ni] = __builtin_amdgcn_mfma_f32_16x16x32_f16(a0, bF[ni][0], acc[mi][ni], 0, 0, 0);
                acc[mi][ni] = __builtin_amdgcn_mfma_f32_16x16x32_f16(a1, bF[ni][1], acc[mi][ni], 0, 0, 0);
            }
        }
        __syncthreads();
    }

#pragma unroll
    for (int mi = 0; mi < 4; mi++)
#pragma unroll
        for (int ni = 0; ni < 4; ni++)
#pragma unroll
            for (int r = 0; r < 4; r++) {
                int R  = tm * 128 + wr * 64 + mi * 16 + g * 4 + r;
                int Cc = tn * 128 + wc * 64 + ni * 16 + c;
                Cout[(size_t)R * E_ + Cc] = acc[mi][ni][r] + bias[Cc];
            }
}

// ---------------- flash attention: 2-way in-block kv split, LDS-staged, defer-max ----
// Grid 512 (8 xcd x 4 bh x 16 q-tiles of 64). Block 512 = 8 waves:
// ws = w>>2 (kv half, 16 tiles each), wq = w&3 (16-q subtile).
// LDS 64KB: [half][dbuf][K 8KB | V 8KB]. 2 blocks/CU -> 16 waves/CU.
__global__ __launch_bounds__(512) void attn15_kernel(
    const _Float16* __restrict__ Qh,   // [B,H,LQ,D] pre-scaled by 0.125*log2e
    const _Float16* __restrict__ Kh,   // [B,H,LKV,D]
    const _Float16* __restrict__ Vt,   // [B*H][LKV/64][D][64] tiled
    const unsigned long long* __restrict__ Mbt,  // [32][B*LQ] transposed bitmask
    _Float16* __restrict__ O)          // [B,LQ,E] f16
{
    __shared__ __align__(16) char ldsraw[65536];

    const int bid0 = blockIdx.x;
    const int xcd = bid0 & 7, jj = bid0 >> 3;
    const int bh = xcd * 4 + (jj >> 4);
    const int qt = jj & 15;
    const int b = bh >> 4, h = bh & 15;
    const int tid = threadIdx.x;
    const int w = tid >> 6, lane = tid & 63;
    const int g = lane >> 4, c = lane & 15;
    const int ws = w >> 2, wq = w & 3;
    const int q0 = qt * 64 + wq * 16;

    char* half = ldsraw + ws * 32768;

    f16x8 qf[2];
#pragma unroll
    for (int ks = 0; ks < 2; ++ks)
        qf[ks] = *(const f16x8*)&Qh[((size_t)bh * LQ_ + q0 + c) * D_ + ks * 32 + g * 8];

    f32x4 o[4];
#pragma unroll
    for (int dt = 0; dt < 4; dt++) o[dt] = f32x4{0.f, 0.f, 0.f, 0.f};
    float m = -1e30f, lsum = 0.f;

    const int rowS = (lane >> 3);
    const int stOffBase = (rowS * 128) + (((lane & 7) ^ (rowS & 7)) * 16);
    const char* kTileB = (const char*)Kh + (size_t)bh * (LKV_ * D_ * 2) + (size_t)ws * 16 * 8192;
    const char* vTileB = (const char*)Vt + (size_t)bh * (LKV_ * D_ * 2) + (size_t)ws * 16 * 8192;

    int rdOff[2];
#pragma unroll
    for (int ks = 0; ks < 2; ++ks)
        rdOff[ks] = c * 128 + (((ks * 4 + g) ^ (c & 7)) * 16);

    const int srcLo = (((g & 1) << 1) * 16 + c) << 2;
    const int srcHi = ((((g & 1) << 1) + 1) * 16 + c) << 2;
    const bool hiSel = (g >= 2);

    const int mRowIdx = b * LQ_ + q0 + c;
    const size_t mTile0 = (size_t)(ws * 16) * 2048 + mRowIdx;

    // prologue: stage tile 0 of this half into buffer 0
    {
#pragma unroll
        for (int j = 0; j < 2; ++j) {
            gload16_lds(kTileB + (wq * 2048 + j * 1024) + stOffBase, half + (wq * 2048 + j * 1024));
            gload16_lds(vTileB + (wq * 2048 + j * 1024) + stOffBase, half + 8192 + (wq * 2048 + j * 1024));
        }
    }
    __syncthreads();

    for (int t = 0; t < 16; ++t) {
        if (t < 15) {
            const char* kt = kTileB + (size_t)(t + 1) * 8192;
            const char* vt = vTileB + (size_t)(t + 1) * 8192;
            char* dst = half + ((t + 1) & 1) * 16384;
#pragma unroll
            for (int j = 0; j < 2; ++j) {
                gload16_lds(kt + (wq * 2048 + j * 1024) + stOffBase, dst + (wq * 2048 + j * 1024));
                gload16_lds(vt + (wq * 2048 + j * 1024) + stOffBase, dst + 8192 + (wq * 2048 + j * 1024));
            }
        }

        const char* bufp = half + (t & 1) * 16384;

        // ---- swapped QK^T from LDS ----
        f32x4 s[4];
#pragma unroll
        for (int nt = 0; nt < 4; ++nt) {
            f32x4 accS = f32x4{0.f, 0.f, 0.f, 0.f};
#pragma unroll
            for (int ks = 0; ks < 2; ++ks) {
                f16x8 kf = *(const f16x8*)(bufp + nt * 2048 + rdOff[ks]);
                accS = __builtin_amdgcn_mfma_f32_16x16x32_f16(kf, qf[ks], accS, 0, 0, 0);
            }
            s[nt] = accS;
        }
        // ---- mask ----
        unsigned long long mks = Mbt[mTile0 + (size_t)t * 2048] >> (g * 4);
#pragma unroll
        for (int nt = 0; nt < 4; ++nt) {
            unsigned nib = (unsigned)(mks >> (nt * 16)) & 0xFu;
            if (nib & 1u) s[nt][0] = -1e9f;
            if (nib & 2u) s[nt][1] = -1e9f;
            if (nib & 4u) s[nt][2] = -1e9f;
            if (nib & 8u) s[nt][3] = -1e9f;
        }
        // ---- online softmax with defer-max (T13, THR=8 in exp2 domain) ----
        float t0 = fmaxf(fmaxf(s[0][0], s[0][1]), fmaxf(s[0][2], s[0][3]));
        float t1 = fmaxf(fmaxf(s[1][0], s[1][1]), fmaxf(s[1][2], s[1][3]));
        float t2 = fmaxf(fmaxf(s[2][0], s[2][1]), fmaxf(s[2][2], s[2][3]));
        float t3 = fmaxf(fmaxf(s[3][0], s[3][1]), fmaxf(s[3][2], s[3][3]));
        float tmax = fmaxf(fmaxf(t0, t1), fmaxf(t2, t3));
        tmax = fmaxf(tmax, __shfl_xor(tmax, 16, 64));
        tmax = fmaxf(tmax, __shfl_xor(tmax, 32, 64));
        if (!__all(tmax - m <= 8.0f)) {
            float mn = fmaxf(m, tmax);
            float scl = exp2f(m - mn);
            m = mn;
            lsum *= scl;
#pragma unroll
            for (int dt = 0; dt < 4; dt++)
#pragma unroll
                for (int r = 0; r < 4; r++) o[dt][r] *= scl;
        }
        float ts = 0.f;
#pragma unroll
        for (int nt = 0; nt < 4; ++nt) {
            float p0 = exp2f(s[nt][0] - m);
            float p1 = exp2f(s[nt][1] - m);
            float p2 = exp2f(s[nt][2] - m);
            float p3 = exp2f(s[nt][3] - m);
            s[nt][0] = p0; s[nt][1] = p1; s[nt][2] = p2; s[nt][3] = p3;
            ts += (p0 + p1) + (p2 + p3);
        }
        ts += __shfl_xor(ts, 16, 64);
        ts += __shfl_xor(ts, 32, 64);
        lsum += ts;
        // ---- pack P to f16 pairs ----
        int pk[4][2];
#pragma unroll
        for (int nt = 0; nt < 4; ++nt) {
            pk[nt][0] = __builtin_bit_cast(int, __builtin_amdgcn_cvt_pkrtz(s[nt][0], s[nt][1]));
            pk[nt][1] = __builtin_bit_cast(int, __builtin_amdgcn_cvt_pkrtz(s[nt][2], s[nt][3]));
        }
        // ---- PV from LDS V ----
#pragma unroll
        for (int ks = 0; ks < 2; ++ks) {
            const int ntL = 2 * ks, ntH = 2 * ks + 1;
            int aL0 = __builtin_amdgcn_ds_bpermute(srcLo, pk[ntL][0]);
            int aL1 = __builtin_amdgcn_ds_bpermute(srcLo, pk[ntL][1]);
            int aH0 = __builtin_amdgcn_ds_bpermute(srcHi, pk[ntL][0]);
            int aH1 = __builtin_amdgcn_ds_bpermute(srcHi, pk[ntL][1]);
            int bL0 = __builtin_amdgcn_ds_bpermute(srcLo, pk[ntH][0]);
            int bL1 = __builtin_amdgcn_ds_bpermute(srcLo, pk[ntH][1]);
            int bH0 = __builtin_amdgcn_ds_bpermute(srcHi, pk[ntH][0]);
            int bH1 = __builtin_amdgcn_ds_bpermute(srcHi, pk[ntH][1]);
            int u[4];
            u[0] = hiSel ? bL0 : aL0;
            u[1] = hiSel ? bL1 : aL1;
            u[2] = hiSel ? bH0 : aH0;
            u[3] = hiSel ? bH1 : aH1;
            f16x8 pf;
            {
                union { int i[4]; f16x8 v; } cvt;
                cvt.i[0] = u[0]; cvt.i[1] = u[1]; cvt.i[2] = u[2]; cvt.i[3] = u[3];
                pf = cvt.v;
            }
#pragma unroll
            for (int dt = 0; dt < 4; ++dt) {
                f16x8 vf = *(const f16x8*)(bufp + 8192 + dt * 2048 + rdOff[ks]);
                o[dt] = __builtin_amdgcn_mfma_f32_16x16x32_f16(vf, pf, o[dt], 0, 0, 0);
            }
        }
        __syncthreads();
    }

    // ---- publish partials: partial row = ws*64 + ql  (ql = wq*16 + c) ----
    float* OfP = (float*)ldsraw;                  // [128][68] f32 = 34816B
    float* Ml  = (float*)(ldsraw + 34816);        // [128][2]
#pragma unroll
    for (int dt = 0; dt < 4; ++dt)
#pragma unroll
        for (int r = 0; r < 4; r++)
            OfP[(w * 16 + c) * 68 + dt * 16 + 4 * g + r] = o[dt][r];
    if (lane < 16) {
        Ml[(w * 16 + lane) * 2 + 0] = m;
        Ml[(w * 16 + lane) * 2 + 1] = lsum;
    }
    __syncthreads();

    // ---- combine 2 kv-partials per q-row (s0 = ql, s1 = 64+ql) ----
    const int d = tid & 63;
    const int qlBase = tid >> 6;
#pragma unroll
    for (int pass = 0; pass < 8; ++pass) {
        int ql = pass * 8 + qlBase;          // 0..63
        float m0 = Ml[ql * 2], l0 = Ml[ql * 2 + 1];
        float m1 = Ml[(64 + ql) * 2], l1 = Ml[(64 + ql) * 2 + 1];
        float M  = fmaxf(m0, m1);
        float e0 = exp2f(m0 - M), e1 = exp2f(m1 - M);
        float L  = l0 * e0 + l1 * e1;
        float acc = OfP[ql * 68 + d] * e0 + OfP[(64 + ql) * 68 + d] * e1;
        O[((size_t)b * LQ_ + qt * 64 + ql) * E_ + h * 64 + d] = (_Float16)(acc / L);
    }
}

extern "C" void kernel_launch(void* const* d_in, const int* in_sizes, int n_in,
                              void* d_out, int out_size, void* d_ws, size_t ws_size,
                              hipStream_t stream)
{
    const float* x   = (const float*)d_in[0];
    const float* ctx = (const float*)d_in[1];
    const void*  msk = d_in[2];
    const float* Wq  = (const float*)d_in[3];
    const float* Wk  = (const float*)d_in[4];
    const float* Wv  = (const float*)d_in[5];
    const float* fcw = (const float*)d_in[6];
    const float* fcb = (const float*)d_in[7];
    float* out = (float*)d_out;

    char* ws = (char*)d_ws;
    size_t off = 0;
    auto alloc = [&](size_t bytes) { char* p = ws + off; off += (bytes + 255) & ~255ull; return p; };

    int* modep = (int*)alloc(256);
    unsigned long long* Mbt = (unsigned long long*)alloc((size_t)B_ * LQ_ * (LKV_ / 64) * 8);
    _Float16* xh   = (_Float16*)alloc((size_t)B_ * LQ_ * E_ * 2);
    _Float16* ch   = (_Float16*)alloc((size_t)B_ * LKV_ * E_ * 2);
    _Float16* wqh  = (_Float16*)alloc((size_t)E_ * E_ * 2);
    _Float16* wkvh = (_Float16*)alloc((size_t)2 * E_ * E_ * 2);
    _Float16* fwh  = (_Float16*)alloc((size_t)E_ * E_ * 2);
    float*    fbf  = (float*)alloc((size_t)E_ * 4);
    _Float16* Qh   = (_Float16*)alloc((size_t)B_ * H_ * LQ_ * D_ * 2);
    _Float16* Kh   = (_Float16*)alloc((size_t)B_ * H_ * LKV_ * D_ * 2);
    _Float16* Vt   = (_Float16*)alloc((size_t)B_ * H_ * LKV_ * D_ * 2);
    _Float16* Ob   = xh;  // safe alias: gemm15_qkv (last reader of xh) finishes before attn writes Ob
    (void)ws_size; (void)in_sizes; (void)n_in; (void)out_size;

    probe15<<<1, 64, 0, stream>>>(msk, modep);

    canon15_all<<<2048, 256, 0, stream>>>(x, ctx, Wq, Wk, Wv, fcw, fcb, msk,
                                          xh, ch, wqh, wkvh, fwh, fbf, Mbt, modep);

    gemm15_qkv<<<640, 256, 0, stream>>>(xh, ch, wqh, wkvh, Qh, Kh, Vt);

    attn15_kernel<<<512, 512, 0, stream>>>(Qh, Kh, Vt, Mbt, Ob);

    gemm15_fc<<<128, 256, 0, stream>>>(Ob, fwh, fbf, out);
}

// Round 16
// 143.059 us; speedup vs baseline: 3.4927x; 1.0024x over previous
//
#include <hip/hip_runtime.h>
#include <hip/hip_bf16.h>

#define B_   2
#define H_   16
#define LQ_  1024
#define LKV_ 2048
#define D_   64
#define E_   1024

typedef __attribute__((ext_vector_type(8))) _Float16 f16x8;
typedef __attribute__((ext_vector_type(4))) float   f32x4;

__device__ __forceinline__ void gload16_lds(const void* g, void* l) {
    __builtin_amdgcn_global_load_lds(
        (const __attribute__((address_space(1))) unsigned int*)g,
        (__attribute__((address_space(3))) unsigned int*)l, 16, 0, 0);
}

// ---------------- one-wave mask-dtype probe ----------------
__global__ void probe16(const void* __restrict__ msk, int* __restrict__ modep) {
    int lane = threadIdx.x;
    int notInt = 0, notF32 = 0, notBF = 0;
    for (int i = lane; i < 256; i += 64) {
        unsigned v = ((const unsigned*)msk)[i * 997];
        if (v > 1u) notInt = 1;
        if (v != 0u && v != 0x3F800000u) notF32 = 1;
        if (v != 0u && v != 0x3F80u && v != 0x3F800000u && v != 0x3F803F80u) notBF = 1;
    }
    notInt = __any(notInt); notF32 = __any(notF32); notBF = __any(notBF);
    if (lane == 0) *modep = !notInt ? 0 : (!notF32 ? 1 : (!notBF ? 2 : 3));
}

// ---------------- streaming canonicalization (mask -> TRANSPOSED bits [t][row]) --------
__global__ void canon16_all(
    const float* __restrict__ x,  const float* __restrict__ ctx,
    const float* __restrict__ wq, const float* __restrict__ wk,
    const float* __restrict__ wv, const float* __restrict__ fw,
    const float* __restrict__ fb, const void* __restrict__ msk,
    _Float16* __restrict__ xh,  _Float16* __restrict__ ch,
    _Float16* __restrict__ wqh, _Float16* __restrict__ wkvh,
    _Float16* __restrict__ fwh, float* __restrict__ fbf,
    unsigned long long* __restrict__ Mbt, const int* __restrict__ modep)
{
    const int mmode = *modep;
    const int total = 1376384;
    const int stride = gridDim.x * blockDim.x;
    for (int idx = blockIdx.x * blockDim.x + threadIdx.x; idx < total; idx += stride) {
        if (idx < 1310720) {
            const float* src; _Float16* dst; int rel;
            if (idx < 262144)       { src = x;   dst = xh;   rel = idx; }
            else if (idx < 786432)  { src = ctx; dst = ch;   rel = idx - 262144; }
            else if (idx < 917504)  { src = wq;  dst = wqh;  rel = idx - 786432; }
            else if (idx < 1048576) { src = wk;  dst = wkvh; rel = idx - 917504; }
            else if (idx < 1179648) { src = wv;  dst = wkvh + (size_t)E_ * E_; rel = idx - 1048576; }
            else                    { src = fw;  dst = fwh;  rel = idx - 1179648; }
            f32x4 a = ((const f32x4*)src)[2 * rel], b = ((const f32x4*)src)[2 * rel + 1];
            f16x8 o;
            o[0] = (_Float16)a.x; o[1] = (_Float16)a.y; o[2] = (_Float16)a.z; o[3] = (_Float16)a.w;
            o[4] = (_Float16)b.x; o[5] = (_Float16)b.y; o[6] = (_Float16)b.z; o[7] = (_Float16)b.w;
            ((f16x8*)dst)[rel] = o;
        } else if (idx < 1310848) {
            int rel = idx - 1310720;
#pragma unroll
            for (int j = 0; j < 8; ++j) fbf[rel * 8 + j] = fb[rel * 8 + j];
        } else {
            int rel = idx - 1310848;           // rel = row*32 + t
            const size_t base = (size_t)rel * 64;
            unsigned long long v = 0;
            if (mmode == 0) {
                const int* p = (const int*)msk + base;
#pragma unroll
                for (int j = 0; j < 64; ++j) if (p[j] != 0) v |= 1ull << j;
            } else if (mmode == 1) {
                const float* p = (const float*)msk + base;
#pragma unroll
                for (int j = 0; j < 64; ++j) if (p[j] != 0.0f) v |= 1ull << j;
            } else if (mmode == 2) {
                const unsigned short* p = (const unsigned short*)msk + base;
#pragma unroll
                for (int j = 0; j < 64; ++j) if (p[j] != 0) v |= 1ull << j;
            } else {
                const unsigned char* p = (const unsigned char*)msk + base;
#pragma unroll
                for (int j = 0; j < 64; ++j) if (p[j] != 0) v |= 1ull << j;
            }
            Mbt[(rel & 31) * 2048 + (rel >> 5)] = v;   // transposed: [t][b*LQ+q]
        }
    }
}

// ---------------- fused Q + K|V projection GEMM: BK=64, swizzled, DOUBLE-BUFFERED ----
__global__ __launch_bounds__(256) void gemm16_qkv(
    const _Float16* __restrict__ xh, const _Float16* __restrict__ ch,
    const _Float16* __restrict__ wqh, const _Float16* __restrict__ wkvh,
    _Float16* __restrict__ Qh, _Float16* __restrict__ Kh, _Float16* __restrict__ Vt)
{
    __shared__ __align__(16) _Float16 As[2][128 * 64];   // 2 x 16KB
    __shared__ __align__(16) _Float16 Bs[2][128 * 64];

    const int bid = blockIdx.x;
    const bool isQ = bid < 128;
    const _Float16* A; const _Float16* W; int tm, tn;
    if (isQ) { A = xh; W = wqh; tm = bid >> 3; tn = bid & 7; }
    else     { int b2 = bid - 128; A = ch; W = wkvh; tm = b2 >> 4; tn = b2 & 15; }

    const int tid = threadIdx.x;
    const int w = tid >> 6, lane = tid & 63;
    const int g = lane >> 4, c = lane & 15;
    const int wr = w >> 1, wc = w & 1;
    const int rowS = lane >> 3, slot = lane & 7;
    const int stSwz = ((slot ^ (rowS & 7)) << 4);
    const int swz0 = ((g ^ (c & 7)) << 4);
    const int swz1 = (((4 + g) ^ (c & 7)) << 4);

    f32x4 acc[4][4];
#pragma unroll
    for (int i = 0; i < 4; i++)
#pragma unroll
        for (int j = 0; j < 4; j++) acc[i][j] = f32x4{0.f, 0.f, 0.f, 0.f};

    const size_t rowB = (size_t)E_ * 2;
    const char* gAbase = (const char*)A + (size_t)(tm * 128) * rowB;
    const char* gBbase = (const char*)W + (size_t)(tn * 128) * rowB;

    // prologue: stage tile 0 -> buffer 0
#pragma unroll
    for (int j = 0; j < 4; ++j) {
        int rloc = w * 32 + j * 8 + rowS;
        gload16_lds(gAbase + (size_t)rloc * rowB + stSwz,
                    (char*)As[0] + (w * 32 + j * 8) * 128 + lane * 16);
        gload16_lds(gBbase + (size_t)rloc * rowB + stSwz,
                    (char*)Bs[0] + (w * 32 + j * 8) * 128 + lane * 16);
    }
    __syncthreads();

    for (int kt = 0; kt < 16; ++kt) {
        // issue next-tile stage BEFORE compute (loads fly under MFMA)
        if (kt < 15) {
            const int nb = (kt + 1) & 1;
#pragma unroll
            for (int j = 0; j < 4; ++j) {
                int rloc = w * 32 + j * 8 + rowS;
                gload16_lds(gAbase + (size_t)rloc * rowB + (kt + 1) * 128 + stSwz,
                            (char*)As[nb] + (w * 32 + j * 8) * 128 + lane * 16);
                gload16_lds(gBbase + (size_t)rloc * rowB + (kt + 1) * 128 + stSwz,
                            (char*)Bs[nb] + (w * 32 + j * 8) * 128 + lane * 16);
            }
        }
        const int cb = kt & 1;

        f16x8 bF[4][2];
#pragma unroll
        for (int ni = 0; ni < 4; ni++) {
            const char* bp = (const char*)Bs[cb] + (wc * 64 + ni * 16 + c) * 128;
            bF[ni][0] = *(const f16x8*)(bp + swz0);
            bF[ni][1] = *(const f16x8*)(bp + swz1);
        }
#pragma unroll
        for (int mi = 0; mi < 4; mi++) {
            const char* ap = (const char*)As[cb] + (wr * 64 + mi * 16 + c) * 128;
            f16x8 a0 = *(const f16x8*)(ap + swz0);
            f16x8 a1 = *(const f16x8*)(ap + swz1);
#pragma unroll
            for (int ni = 0; ni < 4; ni++) {
                acc[mi][ni] = __builtin_amdgcn_mfma_f32_16x16x32_f16(a0, bF[ni][0], acc[mi][ni], 0, 0, 0);
                acc[mi][ni] = __builtin_amdgcn_mfma_f32_16x16x32_f16(a1, bF[ni][1], acc[mi][ni], 0, 0, 0);
            }
        }
        __syncthreads();   // drains stage(kt+1) + protects buffer reuse
    }

#pragma unroll
    for (int mi = 0; mi < 4; mi++) {
#pragma unroll
        for (int ni = 0; ni < 4; ni++) {
#pragma unroll
            for (int r = 0; r < 4; r++) {
                int R  = tm * 128 + wr * 64 + mi * 16 + g * 4 + r;
                int Cc = tn * 128 + wc * 64 + ni * 16 + c;
                float v = acc[mi][ni][r];
                if (isQ) {
                    int b = R >> 10, q = R & 1023;
                    int h = Cc >> 6, d = Cc & 63;
                    // 0.125 * log2(e): attention works in exp2 domain
                    Qh[((size_t)(b * H_ + h) * LQ_ + q) * D_ + d] = (_Float16)(v * 0.18033688011112042f);
                } else {
                    int b = R >> 11, k = R & 2047;
                    int isV = Cc >> 10, cc2 = Cc & 1023;
                    int h = cc2 >> 6, d = cc2 & 63;
                    if (!isV)
                        Kh[((size_t)(b * H_ + h) * LKV_ + k) * D_ + d] = (_Float16)v;
                    else {
                        size_t bh = (size_t)(b * H_ + h);
                        Vt[((bh * (LKV_ / 64) + (k >> 6)) * D_ + d) * 64 + (k & 63)] = (_Float16)v;
                    }
                }
            }
        }
    }
}

// ---------------- FC GEMM: BK=64, swizzled, DOUBLE-BUFFERED ----------------
__global__ __launch_bounds__(256) void gemm16_fc(
    const _Float16* __restrict__ A, const _Float16* __restrict__ W,
    const float* __restrict__ bias, float* __restrict__ Cout)
{
    __shared__ __align__(16) _Float16 As[2][128 * 64];
    __shared__ __align__(16) _Float16 Bs[2][128 * 64];

    const int tm = blockIdx.x >> 3, tn = blockIdx.x & 7;
    const int tid = threadIdx.x;
    const int w = tid >> 6, lane = tid & 63;
    const int g = lane >> 4, c = lane & 15;
    const int wr = w >> 1, wc = w & 1;
    const int rowS = lane >> 3, slot = lane & 7;
    const int stSwz = ((slot ^ (rowS & 7)) << 4);
    const int swz0 = ((g ^ (c & 7)) << 4);
    const int swz1 = (((4 + g) ^ (c & 7)) << 4);

    f32x4 acc[4][4];
#pragma unroll
    for (int i = 0; i < 4; i++)
#pragma unroll
        for (int j = 0; j < 4; j++) acc[i][j] = f32x4{0.f, 0.f, 0.f, 0.f};

    const size_t rowB = (size_t)E_ * 2;
    const char* gAbase = (const char*)A + (size_t)(tm * 128) * rowB;
    const char* gBbase = (const char*)W + (size_t)(tn * 128) * rowB;

#pragma unroll
    for (int j = 0; j < 4; ++j) {
        int rloc = w * 32 + j * 8 + rowS;
        gload16_lds(gAbase + (size_t)rloc * rowB + stSwz,
                    (char*)As[0] + (w * 32 + j * 8) * 128 + lane * 16);
        gload16_lds(gBbase + (size_t)rloc * rowB + stSwz,
                    (char*)Bs[0] + (w * 32 + j * 8) * 128 + lane * 16);
    }
    __syncthreads();

    for (int kt = 0; kt < 16; ++kt) {
        if (kt < 15) {
            const int nb = (kt + 1) & 1;
#pragma unroll
            for (int j = 0; j < 4; ++j) {
                int rloc = w * 32 + j * 8 + rowS;
                gload16_lds(gAbase + (size_t)rloc * rowB + (kt + 1) * 128 + stSwz,
                            (char*)As[nb] + (w * 32 + j * 8) * 128 + lane * 16);
                gload16_lds(gBbase + (size_t)rloc * rowB + (kt + 1) * 128 + stSwz,
                            (char*)Bs[nb] + (w * 32 + j * 8) * 128 + lane * 16);
            }
        }
        const int cb = kt & 1;

        f16x8 bF[4][2];
#pragma unroll
        for (int ni = 0; ni < 4; ni++) {
            const char* bp = (const char*)Bs[cb] + (wc * 64 + ni * 16 + c) * 128;
            bF[ni][0] = *(const f16x8*)(bp + swz0);
            bF[ni][1] = *(const f16x8*)(bp + swz1);
        }
#pragma unroll
        for (int mi = 0; mi < 4; mi++) {
            const char* ap = (const char*)As[cb] + (wr * 64 + mi * 16 + c) * 128;
            f16x8 a0 = *(const f16x8*)(ap + swz0);
            f16x8 a1 = *(const f16x8*)(ap + swz1);
#pragma unroll
            for (int ni = 0; ni < 4; ni++) {
                acc[mi][ni] = __builtin_amdgcn_mfma_f32_16x16x32_f16(a0, bF[ni][0], acc[mi][ni], 0, 0, 0);
                acc[mi][ni] = __builtin_amdgcn_mfma_f32_16x16x32_f16(a1, bF[ni][1], acc[mi][ni], 0, 0, 0);
            }
        }
        __syncthreads();
    }

#pragma unroll
    for (int mi = 0; mi < 4; mi++)
#pragma unroll
        for (int ni = 0; ni < 4; ni++)
#pragma unroll
            for (int r = 0; r < 4; r++) {
                int R  = tm * 128 + wr * 64 + mi * 16 + g * 4 + r;
                int Cc = tn * 128 + wc * 64 + ni * 16 + c;
                Cout[(size_t)R * E_ + Cc] = acc[mi][ni][r] + bias[Cc];
            }
}

// ---------------- flash attention: 2-way in-block kv split, LDS-staged, defer-max ----
// (unchanged from round 15)
__global__ __launch_bounds__(512) void attn16_kernel(
    const _Float16* __restrict__ Qh,   // [B,H,LQ,D] pre-scaled by 0.125*log2e
    const _Float16* __restrict__ Kh,   // [B,H,LKV,D]
    const _Float16* __restrict__ Vt,   // [B*H][LKV/64][D][64] tiled
    const unsigned long long* __restrict__ Mbt,  // [32][B*LQ] transposed bitmask
    _Float16* __restrict__ O)          // [B,LQ,E] f16
{
    __shared__ __align__(16) char ldsraw[65536];

    const int bid0 = blockIdx.x;
    const int xcd = bid0 & 7, jj = bid0 >> 3;
    const int bh = xcd * 4 + (jj >> 4);
    const int qt = jj & 15;
    const int b = bh >> 4, h = bh & 15;
    const int tid = threadIdx.x;
    const int w = tid >> 6, lane = tid & 63;
    const int g = lane >> 4, c = lane & 15;
    const int ws = w >> 2, wq = w & 3;
    const int q0 = qt * 64 + wq * 16;

    char* half = ldsraw + ws * 32768;

    f16x8 qf[2];
#pragma unroll
    for (int ks = 0; ks < 2; ++ks)
        qf[ks] = *(const f16x8*)&Qh[((size_t)bh * LQ_ + q0 + c) * D_ + ks * 32 + g * 8];

    f32x4 o[4];
#pragma unroll
    for (int dt = 0; dt < 4; dt++) o[dt] = f32x4{0.f, 0.f, 0.f, 0.f};
    float m = -1e30f, lsum = 0.f;

    const int rowS = (lane >> 3);
    const int stOffBase = (rowS * 128) + (((lane & 7) ^ (rowS & 7)) * 16);
    const char* kTileB = (const char*)Kh + (size_t)bh * (LKV_ * D_ * 2) + (size_t)ws * 16 * 8192;
    const char* vTileB = (const char*)Vt + (size_t)bh * (LKV_ * D_ * 2) + (size_t)ws * 16 * 8192;

    int rdOff[2];
#pragma unroll
    for (int ks = 0; ks < 2; ++ks)
        rdOff[ks] = c * 128 + (((ks * 4 + g) ^ (c & 7)) * 16);

    const int srcLo = (((g & 1) << 1) * 16 + c) << 2;
    const int srcHi = ((((g & 1) << 1) + 1) * 16 + c) << 2;
    const bool hiSel = (g >= 2);

    const int mRowIdx = b * LQ_ + q0 + c;
    const size_t mTile0 = (size_t)(ws * 16) * 2048 + mRowIdx;

    {
#pragma unroll
        for (int j = 0; j < 2; ++j) {
            gload16_lds(kTileB + (wq * 2048 + j * 1024) + stOffBase, half + (wq * 2048 + j * 1024));
            gload16_lds(vTileB + (wq * 2048 + j * 1024) + stOffBase, half + 8192 + (wq * 2048 + j * 1024));
        }
    }
    __syncthreads();

    for (int t = 0; t < 16; ++t) {
        if (t < 15) {
            const char* kt = kTileB + (size_t)(t + 1) * 8192;
            const char* vt = vTileB + (size_t)(t + 1) * 8192;
            char* dst = half + ((t + 1) & 1) * 16384;
#pragma unroll
            for (int j = 0; j < 2; ++j) {
                gload16_lds(kt + (wq * 2048 + j * 1024) + stOffBase, dst + (wq * 2048 + j * 1024));
                gload16_lds(vt + (wq * 2048 + j * 1024) + stOffBase, dst + 8192 + (wq * 2048 + j * 1024));
            }
        }

        const char* bufp = half + (t & 1) * 16384;

        f32x4 s[4];
#pragma unroll
        for (int nt = 0; nt < 4; ++nt) {
            f32x4 accS = f32x4{0.f, 0.f, 0.f, 0.f};
#pragma unroll
            for (int ks = 0; ks < 2; ++ks) {
                f16x8 kf = *(const f16x8*)(bufp + nt * 2048 + rdOff[ks]);
                accS = __builtin_amdgcn_mfma_f32_16x16x32_f16(kf, qf[ks], accS, 0, 0, 0);
            }
            s[nt] = accS;
        }
        unsigned long long mks = Mbt[mTile0 + (size_t)t * 2048] >> (g * 4);
#pragma unroll
        for (int nt = 0; nt < 4; ++nt) {
            unsigned nib = (unsigned)(mks >> (nt * 16)) & 0xFu;
            if (nib & 1u) s[nt][0] = -1e9f;
            if (nib & 2u) s[nt][1] = -1e9f;
            if (nib & 4u) s[nt][2] = -1e9f;
            if (nib & 8u) s[nt][3] = -1e9f;
        }
        float t0 = fmaxf(fmaxf(s[0][0], s[0][1]), fmaxf(s[0][2], s[0][3]));
        float t1 = fmaxf(fmaxf(s[1][0], s[1][1]), fmaxf(s[1][2], s[1][3]));
        float t2 = fmaxf(fmaxf(s[2][0], s[2][1]), fmaxf(s[2][2], s[2][3]));
        float t3 = fmaxf(fmaxf(s[3][0], s[3][1]), fmaxf(s[3][2], s[3][3]));
        float tmax = fmaxf(fmaxf(t0, t1), fmaxf(t2, t3));
        tmax = fmaxf(tmax, __shfl_xor(tmax, 16, 64));
        tmax = fmaxf(tmax, __shfl_xor(tmax, 32, 64));
        if (!__all(tmax - m <= 8.0f)) {
            float mn = fmaxf(m, tmax);
            float scl = exp2f(m - mn);
            m = mn;
            lsum *= scl;
#pragma unroll
            for (int dt = 0; dt < 4; dt++)
#pragma unroll
                for (int r = 0; r < 4; r++) o[dt][r] *= scl;
        }
        float ts = 0.f;
#pragma unroll
        for (int nt = 0; nt < 4; ++nt) {
            float p0 = exp2f(s[nt][0] - m);
            float p1 = exp2f(s[nt][1] - m);
            float p2 = exp2f(s[nt][2] - m);
            float p3 = exp2f(s[nt][3] - m);
            s[nt][0] = p0; s[nt][1] = p1; s[nt][2] = p2; s[nt][3] = p3;
            ts += (p0 + p1) + (p2 + p3);
        }
        ts += __shfl_xor(ts, 16, 64);
        ts += __shfl_xor(ts, 32, 64);
        lsum += ts;
        int pk[4][2];
#pragma unroll
        for (int nt = 0; nt < 4; ++nt) {
            pk[nt][0] = __builtin_bit_cast(int, __builtin_amdgcn_cvt_pkrtz(s[nt][0], s[nt][1]));
            pk[nt][1] = __builtin_bit_cast(int, __builtin_amdgcn_cvt_pkrtz(s[nt][2], s[nt][3]));
        }
#pragma unroll
        for (int ks = 0; ks < 2; ++ks) {
            const int ntL = 2 * ks, ntH = 2 * ks + 1;
            int aL0 = __builtin_amdgcn_ds_bpermute(srcLo, pk[ntL][0]);
            int aL1 = __builtin_amdgcn_ds_bpermute(srcLo, pk[ntL][1]);
            int aH0 = __builtin_amdgcn_ds_bpermute(srcHi, pk[ntL][0]);
            int aH1 = __builtin_amdgcn_ds_bpermute(srcHi, pk[ntL][1]);
            int bL0 = __builtin_amdgcn_ds_bpermute(srcLo, pk[ntH][0]);
            int bL1 = __builtin_amdgcn_ds_bpermute(srcLo, pk[ntH][1]);
            int bH0 = __builtin_amdgcn_ds_bpermute(srcHi, pk[ntH][0]);
            int bH1 = __builtin_amdgcn_ds_bpermute(srcHi, pk[ntH][1]);
            int u[4];
            u[0] = hiSel ? bL0 : aL0;
            u[1] = hiSel ? bL1 : aL1;
            u[2] = hiSel ? bH0 : aH0;
            u[3] = hiSel ? bH1 : aH1;
            f16x8 pf;
            {
                union { int i[4]; f16x8 v; } cvt;
                cvt.i[0] = u[0]; cvt.i[1] = u[1]; cvt.i[2] = u[2]; cvt.i[3] = u[3];
                pf = cvt.v;
            }
#pragma unroll
            for (int dt = 0; dt < 4; ++dt) {
                f16x8 vf = *(const f16x8*)(bufp + 8192 + dt * 2048 + rdOff[ks]);
                o[dt] = __builtin_amdgcn_mfma_f32_16x16x32_f16(vf, pf, o[dt], 0, 0, 0);
            }
        }
        __syncthreads();
    }

    float* OfP = (float*)ldsraw;                  // [128][68]
    float* Ml  = (float*)(ldsraw + 34816);        // [128][2]
#pragma unroll
    for (int dt = 0; dt < 4; ++dt)
#pragma unroll
        for (int r = 0; r < 4; r++)
            OfP[(w * 16 + c) * 68 + dt * 16 + 4 * g + r] = o[dt][r];
    if (lane < 16) {
        Ml[(w * 16 + lane) * 2 + 0] = m;
        Ml[(w * 16 + lane) * 2 + 1] = lsum;
    }
    __syncthreads();

    const int d = tid & 63;
    const int qlBase = tid >> 6;
#pragma unroll
    for (int pass = 0; pass < 8; ++pass) {
        int ql = pass * 8 + qlBase;          // 0..63
        float m0 = Ml[ql * 2], l0 = Ml[ql * 2 + 1];
        float m1 = Ml[(64 + ql) * 2], l1 = Ml[(64 + ql) * 2 + 1];
        float M  = fmaxf(m0, m1);
        float e0 = exp2f(m0 - M), e1 = exp2f(m1 - M);
        float L  = l0 * e0 + l1 * e1;
        float acc = OfP[ql * 68 + d] * e0 + OfP[(64 + ql) * 68 + d] * e1;
        O[((size_t)b * LQ_ + qt * 64 + ql) * E_ + h * 64 + d] = (_Float16)(acc / L);
    }
}

extern "C" void kernel_launch(void* const* d_in, const int* in_sizes, int n_in,
                              void* d_out, int out_size, void* d_ws, size_t ws_size,
                              hipStream_t stream)
{
    const float* x   = (const float*)d_in[0];
    const float* ctx = (const float*)d_in[1];
    const void*  msk = d_in[2];
    const float* Wq  = (const float*)d_in[3];
    const float* Wk  = (const float*)d_in[4];
    const float* Wv  = (const float*)d_in[5];
    const float* fcw = (const float*)d_in[6];
    const float* fcb = (const float*)d_in[7];
    float* out = (float*)d_out;

    char* ws = (char*)d_ws;
    size_t off = 0;
    auto alloc = [&](size_t bytes) { char* p = ws + off; off += (bytes + 255) & ~255ull; return p; };

    int* modep = (int*)alloc(256);
    unsigned long long* Mbt = (unsigned long long*)alloc((size_t)B_ * LQ_ * (LKV_ / 64) * 8);
    _Float16* xh   = (_Float16*)alloc((size_t)B_ * LQ_ * E_ * 2);
    _Float16* ch   = (_Float16*)alloc((size_t)B_ * LKV_ * E_ * 2);
    _Float16* wqh  = (_Float16*)alloc((size_t)E_ * E_ * 2);
    _Float16* wkvh = (_Float16*)alloc((size_t)2 * E_ * E_ * 2);
    _Float16* fwh  = (_Float16*)alloc((size_t)E_ * E_ * 2);
    float*    fbf  = (float*)alloc((size_t)E_ * 4);
    _Float16* Qh   = (_Float16*)alloc((size_t)B_ * H_ * LQ_ * D_ * 2);
    _Float16* Kh   = (_Float16*)alloc((size_t)B_ * H_ * LKV_ * D_ * 2);
    _Float16* Vt   = (_Float16*)alloc((size_t)B_ * H_ * LKV_ * D_ * 2);
    _Float16* Ob   = xh;  // safe alias: gemm16_qkv (last reader of xh) finishes before attn writes Ob
    (void)ws_size; (void)in_sizes; (void)n_in; (void)out_size;

    probe16<<<1, 64, 0, stream>>>(msk, modep);

    canon16_all<<<2048, 256, 0, stream>>>(x, ctx, Wq, Wk, Wv, fcw, fcb, msk,
                                          xh, ch, wqh, wkvh, fwh, fbf, Mbt, modep);

    gemm16_qkv<<<640, 256, 0, stream>>>(xh, ch, wqh, wkvh, Qh, Kh, Vt);

    attn16_kernel<<<512, 512, 0, stream>>>(Qh, Kh, Vt, Mbt, Ob);

    gemm16_fc<<<128, 256, 0, stream>>>(Ob, fwh, fbf, out);
}